// Round 4
// baseline (1203.475 us; speedup 1.0000x reference)
//
#include <hip/hip_runtime.h>
#include <math.h>

#define IN_DIM 20
#define DIM 128
#define HH 8
#define LL 3
#define BB 2
#define NP 192
#define DHH 16
#define C2 256
#define NN (NP*NP)
#define EPS 1e-5f

typedef __bf16 bf16x8 __attribute__((ext_vector_type(8)));
typedef float  f32x16 __attribute__((ext_vector_type(16)));

union Pack8 { __bf16 h[8]; uint4 u; };

// ---------------- init: conv1d over seq for both x and c ----------------
__global__ void k_conv_init(const float* __restrict__ seq, const float* __restrict__ w1,
                            const float* __restrict__ w2, float* __restrict__ X,
                            float* __restrict__ Cc) {
  int t = blockIdx.x, b = blockIdx.y, oc = threadIdx.x;
  __shared__ float ss[3][IN_DIM];
  if (threadIdx.x < 3*IN_DIM) {
    int k = threadIdx.x / IN_DIM, ic = threadIdx.x % IN_DIM;
    int tt = t + k - 1;
    ss[k][ic] = (tt >= 0 && tt < NP) ? seq[(b*NP + tt)*IN_DIM + ic] : 0.f;
  }
  __syncthreads();
  float a1 = 0.f, a2 = 0.f;
  #pragma unroll
  for (int ic = 0; ic < IN_DIM; ic++) {
    #pragma unroll
    for (int k = 0; k < 3; k++) {
      float sv = ss[k][ic];
      a1 = fmaf(w1[(oc*IN_DIM + ic)*3 + k], sv, a1);
      a2 = fmaf(w2[(oc*IN_DIM + ic)*3 + k], sv, a2);
    }
  }
  X[(b*NP + t)*DIM + oc] = a1;
  Cc[(b*DIM + oc)*NP + t] = a2;
}

// ---------------- conv1d + BN(train stats) + relu, fused ----------------
__global__ void k_conv1d_bn_relu(const float* __restrict__ cin, const float* __restrict__ w,
                                 const float* __restrict__ g, const float* __restrict__ bb,
                                 float* __restrict__ cout) {
  int oc = blockIdx.x;
  int t = threadIdx.x;
  float raw[BB];
  for (int b = 0; b < BB; b++) {
    float acc = 0.f;
    for (int ic = 0; ic < DIM; ic++) {
      const float* cr = cin + (b*DIM + ic)*NP;
      const float* wr = w + (oc*DIM + ic)*3;
      float lf = (t > 0)      ? cr[t-1] : 0.f;
      float mf = cr[t];
      float rf = (t < NP-1)   ? cr[t+1] : 0.f;
      acc = fmaf(lf, wr[0], acc);
      acc = fmaf(mf, wr[1], acc);
      acc = fmaf(rf, wr[2], acc);
    }
    raw[b] = acc;
  }
  __shared__ float sb[NP];
  sb[t] = raw[0] + raw[1];
  __syncthreads();
  for (int s = 128; s > 0; s >>= 1) {
    if (t < s && t + s < NP) sb[t] += sb[t + s];
    __syncthreads();
  }
  float mean = sb[0] / (float)(BB*NP);
  __syncthreads();
  sb[t] = raw[0]*raw[0] + raw[1]*raw[1];
  __syncthreads();
  for (int s = 128; s > 0; s >>= 1) {
    if (t < s && t + s < NP) sb[t] += sb[t + s];
    __syncthreads();
  }
  float var = sb[0] / (float)(BB*NP) - mean*mean;
  float rstd = rsqrtf(var + EPS);
  float gg = g[oc], bo = bb[oc];
  for (int b = 0; b < BB; b++)
    cout[(b*DIM + oc)*NP + t] = fmaxf((raw[b] - mean)*rstd*gg + bo, 0.f);
}

// ---------------- fused: x = LN(x + c^T), then q,k,v = heads(relu(x@w^T+b)) ----------------
__global__ void k_lnqkv(float* __restrict__ X, const float* __restrict__ cc,
                        const float* __restrict__ g, const float* __restrict__ bb,
                        const float* __restrict__ wq, const float* __restrict__ bq,
                        const float* __restrict__ wk, const float* __restrict__ bk,
                        const float* __restrict__ wv, const float* __restrict__ bv,
                        float* __restrict__ Q, float* __restrict__ K, float* __restrict__ V) {
  int t = blockIdx.x, b = blockIdx.y, d = threadIdx.x;
  __shared__ float sb[DIM];
  __shared__ float sy[DIM];
  float v = X[(b*NP + t)*DIM + d] + cc[(b*DIM + d)*NP + t];
  sb[d] = v; __syncthreads();
  for (int s = 64; s > 0; s >>= 1) { if (d < s) sb[d] += sb[d+s]; __syncthreads(); }
  float mean = sb[0] / (float)DIM;
  __syncthreads();
  float dv = v - mean;
  sb[d] = dv*dv; __syncthreads();
  for (int s = 64; s > 0; s >>= 1) { if (d < s) sb[d] += sb[d+s]; __syncthreads(); }
  float var = sb[0] / (float)DIM;
  float rstd = rsqrtf(var + EPS);
  float xn = dv * rstd * g[d] + bb[d];
  X[(b*NP + t)*DIM + d] = xn;
  sy[d] = xn;
  __syncthreads();
  float aq = bq[d], ak = bk[d], av = bv[d];
  for (int e = 0; e < DIM; e++) {
    float xv = sy[e];
    aq = fmaf(wq[d*DIM + e], xv, aq);
    ak = fmaf(wk[d*DIM + e], xv, ak);
    av = fmaf(wv[d*DIM + e], xv, av);
  }
  int h = d >> 4, dh = d & 15;
  size_t o = ((size_t)(b*HH + h)*NP + t)*DHH + dh;
  Q[o] = fmaxf(aq, 0.f); K[o] = fmaxf(ak, 0.f); V[o] = fmaxf(av, 0.f);
}

// ---------------- conv2d weight prep: fp32 [L][oc][ic][3][3] -> bf16 [L][chunk16][kk9][kh2][oc256][8] ----------------
__global__ void k_wprep(const float* __restrict__ w, __bf16* __restrict__ wtb) {
  int blk = blockIdx.x;            // 3*16*9
  int kk = blk % 9;
  int chunk = (blk / 9) % 16;
  int l = blk / (9*16);
  int kh = threadIdx.x >> 8;
  int oc = threadIdx.x & 255;
  Pack8 p;
  #pragma unroll
  for (int e = 0; e < 8; e++) {
    int ic = chunk*16 + kh*8 + e;
    p.h[e] = (__bf16)w[(((size_t)(l*C2 + oc))*C2 + ic)*9 + kk];
  }
  size_t unit = ((((size_t)(l*16 + chunk)*9 + kk)*2 + kh)*256 + oc);
  ((uint4*)wtb)[unit] = p.u;
}

// ---------------- layer-0 conv input build: bf16(seq2pair(Cc) + seq2pair(CL0)); zeroes STAT2 ----------------
__global__ void k_make_convin(const float* __restrict__ Cc, const float* __restrict__ CL0,
                              __bf16* __restrict__ inb, float* __restrict__ STAT2) {
  int idx = blockIdx.x*256 + threadIdx.x;   // (b,chunk,i,kh,j) units
  if (blockIdx.x == 0 && threadIdx.x < 256) {
    STAT2[threadIdx.x] = 0.f; STAT2[256 + threadIdx.x] = 0.f;
  }
  int j = idx % 192;
  int r1 = idx / 192;
  int kh = r1 & 1;
  int r2 = r1 >> 1;
  int i = r2 % 192;
  int r3 = r2 / 192;
  int chunk = r3 % 16;
  int b = r3 / 16;
  Pack8 p;
  #pragma unroll
  for (int e = 0; e < 8; e++) {
    int c = chunk*16 + kh*8 + e;
    float v;
    if (c < DIM) v = Cc[(b*DIM + c)*NP + i] + CL0[(b*DIM + c)*NP + i];
    else { int cc = c - DIM; v = Cc[(b*DIM + cc)*NP + j] + CL0[(b*DIM + cc)*NP + j]; }
    p.h[e] = (__bf16)v;
  }
  ((uint4*)inb)[idx] = p.u;
}

// ---------------- the heavy kernel: implicit-GEMM bf16 MFMA 3x3 conv ----------------
// A (weights) read directly from global (L2-resident); B (input) via double-buffered LDS.
// Fused BN2 partial stats (fp32 acc) via atomics. Output packed bf16 [b][G][i][j][8c].
// grid (3 jt, 48 it, 4 = b*2+oct), block 256 (4 waves)
__global__ __launch_bounds__(256, 2)
void k_conv2d_mfma(const __bf16* __restrict__ inb,   // [b][16][192][2][192][8]
                   const __bf16* __restrict__ wtb,   // [16][9][2][256][8] (layer slice)
                   __bf16* __restrict__ rawb,        // [b][32][192][192][8]
                   float* __restrict__ STAT2) {
  __shared__ __align__(16) char smem[30720];         // 2x960 uint4 input dbuf; epilogue overlay
  uint4* lI = (uint4*)smem;
  float* sTall = (float*)smem;
  int tid = threadIdx.x;
  int jt = blockIdx.x, it = blockIdx.y, zz = blockIdx.z;
  int b = zz >> 1, oct = zz & 1;
  int i0 = it*4, j0 = jt*64, oc0 = oct*128;
  int lane = tid & 63, wv = tid >> 6;
  int wm = wv & 1, wn = wv >> 1;
  int ln31 = lane & 31, kh = lane >> 5;

  const uint4* gW = (const uint4*)wtb;
  const uint4* gI = (const uint4*)inb;

  f32x16 acc[2][4];
  #pragma unroll
  for (int m = 0; m < 2; m++)
    #pragma unroll
    for (int n = 0; n < 4; n++)
      #pragma unroll
      for (int q = 0; q < 16; q++) acc[m][n][q] = 0.f;

  uint4 ireg[4];

  auto load_i = [&](int chunk) {
    #pragma unroll
    for (int t = 0; t < 4; t++) {
      int u = t*256 + tid;
      uint4 v; v.x = v.y = v.z = v.w = 0u;
      if (u < 960) {
        int r = u / 160, rem = u % 160;
        int khu = rem / 80, cc = rem % 80;
        int row = i0 - 1 + r;
        int cj = j0 - 8 + cc;
        if ((unsigned)row < 192u && (unsigned)cj < 192u)
          v = gI[(((size_t)(b*16 + chunk)*192 + row)*2 + khu)*192 + cj];
      }
      ireg[t] = v;
    }
  };
  auto store_i = [&](int buf) {
    #pragma unroll
    for (int t = 0; t < 4; t++) {
      int u = t*256 + tid;
      if (u < 960) lI[buf*960 + u] = ireg[t];
    }
  };

  load_i(0);
  store_i(0);
  __syncthreads();

  for (int chunk = 0; chunk < 16; ++chunk) {
    int cur = chunk & 1;
    if (chunk < 15) load_i(chunk + 1);      // global prefetch, no barrier dependency
    const uint4* bufp = lI + cur*960;
    #pragma unroll
    for (int kj = 0; kj < 3; kj++) {
      bf16x8 breg[4][2];                    // rows wn*2+rr, col-halves; reused across ki
      #pragma unroll
      for (int rr = 0; rr < 4; rr++)
        #pragma unroll
        for (int ch = 0; ch < 2; ch++) {
          int r = wn*2 + rr;
          int cc = ch*32 + ln31 + kj + 7;
          breg[rr][ch] = *(const bf16x8*)((const __bf16*)(bufp + (r*2 + kh)*80 + cc));
        }
      #pragma unroll
      for (int ki = 0; ki < 3; ki++) {
        int kk = ki*3 + kj;
        size_t wbase = ((size_t)chunk*18 + kk*2 + kh)*256 + oc0 + wm*64;
        bf16x8 a0 = *(const bf16x8*)((const __bf16*)(gW + wbase + ln31));
        bf16x8 a1 = *(const bf16x8*)((const __bf16*)(gW + wbase + 32 + ln31));
        #pragma unroll
        for (int nt = 0; nt < 4; nt++) {
          int rr = (nt >> 1) + ki;
          acc[0][nt] = __builtin_amdgcn_mfma_f32_32x32x16_bf16(a0, breg[rr][nt&1], acc[0][nt], 0, 0, 0);
          acc[1][nt] = __builtin_amdgcn_mfma_f32_32x32x16_bf16(a1, breg[rr][nt&1], acc[1][nt], 0, 0, 0);
        }
      }
    }
    if (chunk < 15) {
      store_i(cur ^ 1);
      __syncthreads();
    }
  }

  // fused BN2 partial stats from fp32 accumulators
  #pragma unroll
  for (int mt = 0; mt < 2; mt++) {
    #pragma unroll
    for (int reg = 0; reg < 16; reg++) {
      float s  = acc[mt][0][reg] + acc[mt][1][reg] + acc[mt][2][reg] + acc[mt][3][reg];
      float s2 = acc[mt][0][reg]*acc[mt][0][reg] + acc[mt][1][reg]*acc[mt][1][reg]
               + acc[mt][2][reg]*acc[mt][2][reg] + acc[mt][3][reg]*acc[mt][3][reg];
      #pragma unroll
      for (int m = 1; m <= 16; m <<= 1) { s += __shfl_xor(s, m); s2 += __shfl_xor(s2, m); }
      if (ln31 == 0) {
        int c = oc0 + wm*64 + mt*32 + (reg & 3) + 8*(reg >> 2) + 4*kh;
        atomicAdd(&STAT2[c], s);
        atomicAdd(&STAT2[C2 + c], s2);
      }
    }
  }

  // epilogue: per-wave LDS transpose (overlay) -> packed bf16 16B stores
  float* tr = sTall + wv*(32*33);
  uint4* RAWu = (uint4*)rawb;
  #pragma unroll
  for (int mt = 0; mt < 2; mt++) {
    int cbase = oc0 + wm*64 + mt*32;
    int Gb = cbase >> 3;
    #pragma unroll
    for (int nt = 0; nt < 4; nt++) {
      int ii = i0 + wn*2 + (nt>>1);
      int jb = j0 + (nt&1)*32;
      __syncthreads();
      #pragma unroll
      for (int reg = 0; reg < 16; reg++) {
        int row = (reg & 3) + 8*(reg >> 2) + 4*kh;
        tr[row*33 + ln31] = acc[mt][nt][reg];
      }
      __syncthreads();
      #pragma unroll
      for (int gs = 0; gs < 2; gs++) {
        int g = kh + gs*2;
        Pack8 p;
        #pragma unroll
        for (int e = 0; e < 8; e++) p.h[e] = (__bf16)tr[(g*8 + e)*33 + ln31];
        RAWu[(((size_t)(b*32 + Gb + g)*192) + ii)*192 + jb + ln31] = p.u;
      }
    }
  }
}

// ---------------- fused: BN2 norm+relu, gate projection, next conv input bf16 ----------------
template<int WRITE_NEXT>
__global__ void k_bn2_norm_gate(const __bf16* __restrict__ rawb, const float* __restrict__ STAT2,
                                const float* __restrict__ g, const float* __restrict__ bb,
                                const float* __restrict__ wd, const float* __restrict__ CLn,
                                __bf16* __restrict__ inb_next, float* __restrict__ tg) {
  int i = blockIdx.x, b = blockIdx.y, j = threadIdx.x;
  __shared__ float sscale[C2], sshift[C2], swd[HH*C2];
  const float inv = 1.f / (float)(BB*NN);
  for (int c = j; c < C2; c += 192) {
    float mean = STAT2[c] * inv;
    float var  = STAT2[C2 + c] * inv - mean*mean;
    float rstd = rsqrtf(var + EPS);
    float sc = rstd * g[c];
    sscale[c] = sc;
    sshift[c] = bb[c] - mean*sc;
  }
  for (int idx = j; idx < HH*C2; idx += 192) swd[idx] = wd[idx];
  __syncthreads();
  float gacc[HH] = {};
  const uint4* RAWu = (const uint4*)rawb;
  for (int cu = 0; cu < 32; cu++) {
    Pack8 pr; pr.u = RAWu[((size_t)(b*32 + cu)*NP + i)*NP + j];
    Pack8 p;
    #pragma unroll
    for (int e = 0; e < 8; e++) {
      int c = cu*8 + e;
      float v = (float)pr.h[e];
      v = fmaxf(fmaf(v, sscale[c], sshift[c]), 0.f);
      if (WRITE_NEXT) {
        float nv = v + ((c < DIM) ? CLn[(b*DIM + c)*NP + i] : CLn[(b*DIM + c - DIM)*NP + j]);
        p.h[e] = (__bf16)nv;
      }
      #pragma unroll
      for (int h = 0; h < HH; h++) gacc[h] = fmaf(v, swd[h*C2 + c], gacc[h]);
    }
    if (WRITE_NEXT) {
      size_t unit = (((size_t)(b*16 + (cu>>1))*192 + i)*2 + (cu&1))*192 + j;
      ((uint4*)inb_next)[unit] = p.u;
    }
  }
  for (int h = 0; h < HH; h++)
    tg[((size_t)(b*HH + h)*NP + i)*NP + j] = gacc[h];
}

// ---------------- attention row with inline gate=sigmoid(t+t^T+bias); zeroes STAT2 ----------------
__global__ void k_attn(const float* __restrict__ Q, const float* __restrict__ K,
                       const float* __restrict__ V, const float* __restrict__ tg,
                       const float* __restrict__ wdb, const float* __restrict__ mask,
                       float* __restrict__ upd, float* __restrict__ STAT2) {
  int i = blockIdx.x, h = blockIdx.y, b = blockIdx.z, j = threadIdx.x;
  if (i == 0 && h == 0 && b == 0)
    for (int s = j; s < 2*C2; s += 192) STAT2[s] = 0.f;
  size_t bh = (size_t)(b*HH + h);
  __shared__ float sq[DHH];
  __shared__ float sb[NP];
  __shared__ float sattn[NP];
  if (j < DHH) sq[j] = Q[(bh*NP + i)*DHH + j];
  __syncthreads();
  const float* kr = K + (bh*NP + j)*DHH;
  float a = 0.f;
  #pragma unroll
  for (int d = 0; d < DHH; d++) a = fmaf(sq[d], kr[d], a);
  a *= 0.25f;
  sb[j] = a; __syncthreads();
  for (int s = 128; s > 0; s >>= 1) {
    if (j < s && j + s < NP) sb[j] = fmaxf(sb[j], sb[j+s]);
    __syncthreads();
  }
  float amax = sb[0];
  __syncthreads();
  float e = expf(a - amax) * mask[b*NP + j];
  sb[j] = e; __syncthreads();
  for (int s = 128; s > 0; s >>= 1) {
    if (j < s && j + s < NP) sb[j] += sb[j+s];
    __syncthreads();
  }
  float denom = sb[0] + 1e-6f;
  float gv = tg[(bh*NP + i)*NP + j] + tg[(bh*NP + j)*NP + i] + wdb[h];
  float gate = 1.f / (1.f + expf(-gv));
  float attn = (e / denom) * gate;
  sattn[j] = attn;
  __syncthreads();
  if (j < DHH) {
    float acc = 0.f;
    for (int jj = 0; jj < NP; jj++)
      acc = fmaf(sattn[jj], V[(bh*NP + jj)*DHH + j], acc);
    upd[((size_t)(b*NP) + i)*DIM + h*DHH + j] = acc;
  }
}

// ---------------- x = relu((x + upd) @ wl^T + bl) ----------------
__global__ void k_xup(float* __restrict__ X, const float* __restrict__ upd,
                      const float* __restrict__ wl, const float* __restrict__ bl) {
  int t = blockIdx.x, b = blockIdx.y, d = threadIdx.x;
  __shared__ float sy[DIM];
  size_t o = (size_t)(b*NP + t)*DIM;
  sy[d] = X[o + d] + upd[o + d];
  __syncthreads();
  float acc = bl[d];
  for (int e = 0; e < DIM; e++) acc = fmaf(wl[d*DIM + e], sy[e], acc);
  X[o + d] = fmaxf(acc, 0.f);
}

// ---------------- out = relu(x @ fc^T + fb) ----------------
__global__ void k_final(const float* __restrict__ X, const float* __restrict__ fc,
                        const float* __restrict__ fb, float* __restrict__ out) {
  int t = blockIdx.x, b = blockIdx.y, d = threadIdx.x;
  __shared__ float sy[DIM];
  size_t o = (size_t)(b*NP + t)*DIM;
  sy[d] = X[o + d];
  __syncthreads();
  float acc = fb[d];
  for (int e = 0; e < DIM; e++) acc = fmaf(fc[d*DIM + e], sy[e], acc);
  out[o + d] = fmaxf(acc, 0.f);
}

extern "C" void kernel_launch(void* const* d_in, const int* in_sizes, int n_in,
                              void* d_out, int out_size, void* d_ws, size_t ws_size,
                              hipStream_t stream) {
  const float* seq     = (const float*)d_in[0];
  const float* mask    = (const float*)d_in[1];
  const float* conv1_w = (const float*)d_in[2];
  const float* conv2_w = (const float*)d_in[3];
  const float* ln_g    = (const float*)d_in[4];
  const float* ln_b    = (const float*)d_in[5];
  const float* c1d_w   = (const float*)d_in[6];
  const float* bn1_g   = (const float*)d_in[7];
  const float* bn1_b   = (const float*)d_in[8];
  const float* c2d_w   = (const float*)d_in[9];
  const float* bn2_g   = (const float*)d_in[10];
  const float* bn2_b   = (const float*)d_in[11];
  const float* wq_w    = (const float*)d_in[12];
  const float* wq_b    = (const float*)d_in[13];
  const float* wk_w    = (const float*)d_in[14];
  const float* wk_b    = (const float*)d_in[15];
  const float* wv_w    = (const float*)d_in[16];
  const float* wv_b    = (const float*)d_in[17];
  const float* wd_w    = (const float*)d_in[18];
  const float* wd_b    = (const float*)d_in[19];
  const float* wl_w    = (const float*)d_in[20];
  const float* wl_b    = (const float*)d_in[21];
  const float* fc_w    = (const float*)d_in[22];
  const float* fc_b    = (const float*)d_in[23];
  float* out = (float*)d_out;

  float* ws = (float*)d_ws;
  float* X    = ws; ws += BB*NP*DIM;
  float* Cc   = ws; ws += BB*DIM*NP;
  float* CL0  = ws; ws += BB*DIM*NP;
  float* CL1  = ws; ws += BB*DIM*NP;
  float* CL2  = ws; ws += BB*DIM*NP;
  float* Q    = ws; ws += BB*NP*DIM;
  float* K    = ws; ws += BB*NP*DIM;
  float* V    = ws; ws += BB*NP*DIM;
  float* UPD  = ws; ws += BB*NP*DIM;
  float* TG   = ws; ws += (size_t)BB*HH*NN;
  float* STAT2= ws; ws += 2*C2;
  __bf16* RAW = (__bf16*)ws; ws += (size_t)BB*C2*NN/2;  // raw conv output, packed bf16
  __bf16* INB = (__bf16*)ws; ws += (size_t)BB*C2*NN/2;  // conv input bf16
  __bf16* WTB = (__bf16*)ws; ws += (size_t)LL*C2*C2*9/2;

  const float* CL[3] = {CL0, CL1, CL2};

  k_wprep<<<LL*16*9, 512, 0, stream>>>(c2d_w, WTB);
  k_conv_init<<<dim3(NP, BB), DIM, 0, stream>>>(seq, conv1_w, conv2_w, X, Cc);
  k_conv1d_bn_relu<<<DIM, NP, 0, stream>>>(Cc,  c1d_w + 0*(size_t)DIM*DIM*3, bn1_g + 0*DIM, bn1_b + 0*DIM, CL0);
  k_conv1d_bn_relu<<<DIM, NP, 0, stream>>>(CL0, c1d_w + 1*(size_t)DIM*DIM*3, bn1_g + 1*DIM, bn1_b + 1*DIM, CL1);
  k_conv1d_bn_relu<<<DIM, NP, 0, stream>>>(CL1, c1d_w + 2*(size_t)DIM*DIM*3, bn1_g + 2*DIM, bn1_b + 2*DIM, CL2);
  k_make_convin<<<(BB*16*NP*2*NP)/256, 256, 0, stream>>>(Cc, CL0, INB, STAT2);

  for (int l = 0; l < LL; l++) {
    k_lnqkv<<<dim3(NP, BB), DIM, 0, stream>>>(X, CL[l], ln_g + l*DIM, ln_b + l*DIM,
                                              wq_w + (size_t)l*DIM*DIM, wq_b + l*DIM,
                                              wk_w + (size_t)l*DIM*DIM, wk_b + l*DIM,
                                              wv_w + (size_t)l*DIM*DIM, wv_b + l*DIM, Q, K, V);
    k_conv2d_mfma<<<dim3(3, 48, 4), 256, 0, stream>>>(INB, WTB + (size_t)l*16*9*2*256*8, RAW, STAT2);
    if (l < LL-1)
      k_bn2_norm_gate<1><<<dim3(NP, BB), NP, 0, stream>>>(RAW, STAT2, bn2_g + l*C2, bn2_b + l*C2,
                                                          wd_w + (size_t)l*HH*C2, CL[l+1], INB, TG);
    else
      k_bn2_norm_gate<0><<<dim3(NP, BB), NP, 0, stream>>>(RAW, STAT2, bn2_g + l*C2, bn2_b + l*C2,
                                                          wd_w + (size_t)l*HH*C2, nullptr, nullptr, TG);
    k_attn<<<dim3(NP, HH, BB), NP, 0, stream>>>(Q, K, V, TG, wd_b + l*HH, mask, UPD, STAT2);
    k_xup<<<dim3(NP, BB), DIM, 0, stream>>>(X, UPD, wl_w + (size_t)l*DIM*DIM, wl_b + l*DIM);
  }
  k_final<<<dim3(NP, BB), DIM, 0, stream>>>(X, fc_w, fc_b, out);
}

// Round 5
// 731.803 us; speedup vs baseline: 1.6445x; 1.6445x over previous
//
#include <hip/hip_runtime.h>
#include <math.h>

#define IN_DIM 20
#define DIM 128
#define HH 8
#define LL 3
#define BB 2
#define NP 192
#define DHH 16
#define C2 256
#define NN (NP*NP)
#define EPS 1e-5f

// padded conv-input geometry
#define PR 200   // padded rows (grow = i+1, 0..196 used)
#define PC 224   // padded cols (gcol = j+8, 0..199 used, stage window needs j0..j0+95 <= 223)

typedef __bf16 bf16x8 __attribute__((ext_vector_type(8)));
typedef float  f32x16 __attribute__((ext_vector_type(16)));

union Pack8 { __bf16 h[8]; uint4 u; };

#define GLOAD16(gp, lp) \
  __builtin_amdgcn_global_load_lds((const __attribute__((address_space(1))) uint4*)(gp), \
                                   (__attribute__((address_space(3))) uint4*)(lp), 16, 0, 0)

// ---------------- init: conv1d over seq for both x and c ----------------
__global__ void k_conv_init(const float* __restrict__ seq, const float* __restrict__ w1,
                            const float* __restrict__ w2, float* __restrict__ X,
                            float* __restrict__ Cc) {
  int t = blockIdx.x, b = blockIdx.y, oc = threadIdx.x;
  __shared__ float ss[3][IN_DIM];
  if (threadIdx.x < 3*IN_DIM) {
    int k = threadIdx.x / IN_DIM, ic = threadIdx.x % IN_DIM;
    int tt = t + k - 1;
    ss[k][ic] = (tt >= 0 && tt < NP) ? seq[(b*NP + tt)*IN_DIM + ic] : 0.f;
  }
  __syncthreads();
  float a1 = 0.f, a2 = 0.f;
  #pragma unroll
  for (int ic = 0; ic < IN_DIM; ic++) {
    #pragma unroll
    for (int k = 0; k < 3; k++) {
      float sv = ss[k][ic];
      a1 = fmaf(w1[(oc*IN_DIM + ic)*3 + k], sv, a1);
      a2 = fmaf(w2[(oc*IN_DIM + ic)*3 + k], sv, a2);
    }
  }
  X[(b*NP + t)*DIM + oc] = a1;
  Cc[(b*DIM + oc)*NP + t] = a2;
}

// ---------------- conv1d + BN(train stats) + relu, fused ----------------
__global__ void k_conv1d_bn_relu(const float* __restrict__ cin, const float* __restrict__ w,
                                 const float* __restrict__ g, const float* __restrict__ bb,
                                 float* __restrict__ cout) {
  int oc = blockIdx.x;
  int t = threadIdx.x;
  float raw[BB];
  for (int b = 0; b < BB; b++) {
    float acc = 0.f;
    for (int ic = 0; ic < DIM; ic++) {
      const float* cr = cin + (b*DIM + ic)*NP;
      const float* wr = w + (oc*DIM + ic)*3;
      float lf = (t > 0)      ? cr[t-1] : 0.f;
      float mf = cr[t];
      float rf = (t < NP-1)   ? cr[t+1] : 0.f;
      acc = fmaf(lf, wr[0], acc);
      acc = fmaf(mf, wr[1], acc);
      acc = fmaf(rf, wr[2], acc);
    }
    raw[b] = acc;
  }
  __shared__ float sb[NP];
  sb[t] = raw[0] + raw[1];
  __syncthreads();
  for (int s = 128; s > 0; s >>= 1) {
    if (t < s && t + s < NP) sb[t] += sb[t + s];
    __syncthreads();
  }
  float mean = sb[0] / (float)(BB*NP);
  __syncthreads();
  sb[t] = raw[0]*raw[0] + raw[1]*raw[1];
  __syncthreads();
  for (int s = 128; s > 0; s >>= 1) {
    if (t < s && t + s < NP) sb[t] += sb[t + s];
    __syncthreads();
  }
  float var = sb[0] / (float)(BB*NP) - mean*mean;
  float rstd = rsqrtf(var + EPS);
  float gg = g[oc], bo = bb[oc];
  for (int b = 0; b < BB; b++)
    cout[(b*DIM + oc)*NP + t] = fmaxf((raw[b] - mean)*rstd*gg + bo, 0.f);
}

// ---------------- fused: x = LN(x + c^T), then q,k,v = heads(relu(x@w^T+b)) ----------------
__global__ void k_lnqkv(float* __restrict__ X, const float* __restrict__ cc,
                        const float* __restrict__ g, const float* __restrict__ bb,
                        const float* __restrict__ wq, const float* __restrict__ bq,
                        const float* __restrict__ wk, const float* __restrict__ bk,
                        const float* __restrict__ wv, const float* __restrict__ bv,
                        float* __restrict__ Q, float* __restrict__ K, float* __restrict__ V) {
  int t = blockIdx.x, b = blockIdx.y, d = threadIdx.x;
  __shared__ float sb[DIM];
  __shared__ float sy[DIM];
  float v = X[(b*NP + t)*DIM + d] + cc[(b*DIM + d)*NP + t];
  sb[d] = v; __syncthreads();
  for (int s = 64; s > 0; s >>= 1) { if (d < s) sb[d] += sb[d+s]; __syncthreads(); }
  float mean = sb[0] / (float)DIM;
  __syncthreads();
  float dv = v - mean;
  sb[d] = dv*dv; __syncthreads();
  for (int s = 64; s > 0; s >>= 1) { if (d < s) sb[d] += sb[d+s]; __syncthreads(); }
  float var = sb[0] / (float)DIM;
  float rstd = rsqrtf(var + EPS);
  float xn = dv * rstd * g[d] + bb[d];
  X[(b*NP + t)*DIM + d] = xn;
  sy[d] = xn;
  __syncthreads();
  float aq = bq[d], ak = bk[d], av = bv[d];
  for (int e = 0; e < DIM; e++) {
    float xv = sy[e];
    aq = fmaf(wq[d*DIM + e], xv, aq);
    ak = fmaf(wk[d*DIM + e], xv, ak);
    av = fmaf(wv[d*DIM + e], xv, av);
  }
  int h = d >> 4, dh = d & 15;
  size_t o = ((size_t)(b*HH + h)*NP + t)*DHH + dh;
  Q[o] = fmaxf(aq, 0.f); K[o] = fmaxf(ak, 0.f); V[o] = fmaxf(av, 0.f);
}

// ---------------- conv2d weight prep: fp32 [L][oc][ic][3][3] -> bf16 [L][chunk16][kk9][kh2][oc256][8] ----------------
__global__ void k_wprep(const float* __restrict__ w, __bf16* __restrict__ wtb) {
  int blk = blockIdx.x;            // 3*16*9
  int kk = blk % 9;
  int chunk = (blk / 9) % 16;
  int l = blk / (9*16);
  int kh = threadIdx.x >> 8;
  int oc = threadIdx.x & 255;
  Pack8 p;
  #pragma unroll
  for (int e = 0; e < 8; e++) {
    int ic = chunk*16 + kh*8 + e;
    p.h[e] = (__bf16)w[(((size_t)(l*C2 + oc))*C2 + ic)*9 + kk];
  }
  size_t unit = ((((size_t)(l*16 + chunk)*9 + kk)*2 + kh)*256 + oc);
  ((uint4*)wtb)[unit] = p.u;
}

// ---------------- layer-0 conv input build into PADDED layout; zeroes STAT2 ----------------
// INB unit (16B): idx = ((((b*16 + chunk)*PR + grow)*PC + gcol)*2 + kh); i = grow-1, j = gcol-8
__global__ void k_make_convin(const float* __restrict__ Cc, const float* __restrict__ CL0,
                              __bf16* __restrict__ inb, float* __restrict__ STAT2) {
  int idx = blockIdx.x*256 + threadIdx.x;   // total BB*16*PR*PC*2
  if (blockIdx.x == 0 && threadIdx.x < 256) {
    STAT2[threadIdx.x] = 0.f; STAT2[256 + threadIdx.x] = 0.f;
  }
  int kh = idx & 1;
  int t = idx >> 1;
  int gcol = t % PC; int t2 = t / PC;
  int grow = t2 % PR; int t3 = t2 / PR;
  int chunk = t3 & 15; int b = t3 >> 4;
  int i = grow - 1, j = gcol - 8;
  Pack8 p;
  if ((unsigned)i < 192u && (unsigned)j < 192u) {
    #pragma unroll
    for (int e = 0; e < 8; e++) {
      int c = chunk*16 + kh*8 + e;
      float v;
      if (c < DIM) v = Cc[(b*DIM + c)*NP + i] + CL0[(b*DIM + c)*NP + i];
      else { int cc = c - DIM; v = Cc[(b*DIM + cc)*NP + j] + CL0[(b*DIM + cc)*NP + j]; }
      p.h[e] = (__bf16)v;
    }
  } else {
    #pragma unroll
    for (int e = 0; e < 8; e++) p.h[e] = (__bf16)0.f;
  }
  ((uint4*)inb)[idx] = p.u;
}

// ---------------- the heavy kernel: implicit-GEMM bf16 MFMA 3x3 conv ----------------
// grid (3 jt, 48 it, 8 = b*4+oct), block 256 (4 waves). Block tile: 64 oc x (4 rows x 64 cols).
// K: 16 chunks of 16 ic; per chunk stage W (1152 u16B) + I (1152 u16B) via global_load_lds
// into LDS double buffer; ONE barrier per chunk (issue-after-barrier makes WAR safe).
__global__ __launch_bounds__(256, 2)
void k_conv2d_mfma(const __bf16* __restrict__ inb,   // padded [b][16][PR][PC][2][8]
                   const __bf16* __restrict__ wtb,   // [16][9][2][256][8] (layer slice)
                   __bf16* __restrict__ rawb,        // [b][32][192][192][8]
                   float* __restrict__ STAT2) {
  __shared__ __align__(16) uint4 sbuf[2*2304];       // 73728 B: [buf][W 1152 | I 1152]
  int tid = threadIdx.x;
  int jt = blockIdx.x, it = blockIdx.y, zz = blockIdx.z;
  int b = zz >> 2, oct = zz & 3;
  int i0 = it*4, j0 = jt*64, oc0 = oct*64;
  int lane = tid & 63, wv = tid >> 6;
  int wn = wv;                      // wave's row within tile
  int ln31 = lane & 31, khl = lane >> 5;

  const uint4* gW = (const uint4*)wtb;
  const uint4* gI = (const uint4*)inb;

  f32x16 acc[2][2];
  #pragma unroll
  for (int m = 0; m < 2; m++)
    #pragma unroll
    for (int n = 0; n < 2; n++)
      #pragma unroll
      for (int q = 0; q < 16; q++) acc[m][n][q] = 0.f;

  // issue this wave's 9 async staging loads for `chunk` into buffer `buf`
  auto issue = [&](int chunk, int buf) {
    uint4* lbase = sbuf + buf*2304;
    const uint4* gWc = gW + (size_t)chunk*4608 + oc0;                 // + kkh*256 + lane
    const uint4* gIc = gI + (((size_t)(b*16 + chunk)*PR + i0)*PC + j0)*2;
    #pragma unroll
    for (int t = 0; t < 9; t++) {
      int L = wv*9 + t;
      if (L < 18) {
        GLOAD16(gWc + L*256 + lane, lbase + L*64);
      } else {
        int Lp = L - 18;
        int r = Lp / 3, s = Lp - r*3;
        int local = s*64 + lane;            // 0..191
        int kh = local >= 96;
        int c = local - (kh ? 96 : 0);      // 0..95
        GLOAD16(gIc + ((size_t)r*PC + c)*2 + kh, lbase + 1152 + Lp*64);
      }
    }
  };

  issue(0, 0);

  for (int chunk = 0; chunk < 16; ++chunk) {
    int buf = chunk & 1;
    __syncthreads();                        // drains vmcnt: staged data visible; WAR-safe
    if (chunk < 15) issue(chunk + 1, buf ^ 1);
    const __bf16* Wl = (const __bf16*)(sbuf + buf*2304);
    const __bf16* Il = (const __bf16*)(sbuf + buf*2304 + 1152);
    #pragma unroll
    for (int kj = 0; kj < 3; kj++) {
      bf16x8 bfr[3][2];
      #pragma unroll
      for (int ki = 0; ki < 3; ki++) {
        int r = wn + ki;
        #pragma unroll
        for (int ch = 0; ch < 2; ch++) {
          int c = ch*32 + ln31 + kj + 7;
          bfr[ki][ch] = *(const bf16x8*)(Il + (r*192 + khl*96 + c)*8);
        }
      }
      #pragma unroll
      for (int ki = 0; ki < 3; ki++) {
        int kk = ki*3 + kj;
        bf16x8 a0 = *(const bf16x8*)(Wl + ((kk*2 + khl)*64 +      ln31)*8);
        bf16x8 a1 = *(const bf16x8*)(Wl + ((kk*2 + khl)*64 + 32 + ln31)*8);
        #pragma unroll
        for (int ch = 0; ch < 2; ch++) {
          acc[0][ch] = __builtin_amdgcn_mfma_f32_32x32x16_bf16(a0, bfr[ki][ch], acc[0][ch], 0, 0, 0);
          acc[1][ch] = __builtin_amdgcn_mfma_f32_32x32x16_bf16(a1, bfr[ki][ch], acc[1][ch], 0, 0, 0);
        }
      }
    }
  }

  __syncthreads();                          // all ds_reads done; overlay LDS for epilogue
  float* trAll = (float*)sbuf;
  float* tr = trAll + wv*(32*33);
  float* sstat = trAll + 4*32*33;           // 128 floats
  if (tid < 128) sstat[tid] = 0.f;
  __syncthreads();

  // fused BN2 partial stats (per-block LDS reduce, then 64 global atomics)
  #pragma unroll
  for (int m = 0; m < 2; m++) {
    #pragma unroll
    for (int reg = 0; reg < 16; reg++) {
      float v0 = acc[m][0][reg], v1 = acc[m][1][reg];
      float s = v0 + v1, s2 = v0*v0 + v1*v1;
      #pragma unroll
      for (int msk = 1; msk <= 16; msk <<= 1) { s += __shfl_xor(s, msk); s2 += __shfl_xor(s2, msk); }
      if (ln31 == 0) {
        int oc_l = m*32 + (reg & 3) + 8*(reg >> 2) + 4*khl;
        atomicAdd(&sstat[oc_l], s);
        atomicAdd(&sstat[64 + oc_l], s2);
      }
    }
  }

  // packed bf16 output via wave-local LDS transpose (no block barriers)
  int i = i0 + wn;
  uint4* RAWu = (uint4*)rawb;
  #pragma unroll
  for (int m = 0; m < 2; m++) {
    int Gb = (oc0 + m*32) >> 3;
    #pragma unroll
    for (int ch = 0; ch < 2; ch++) {
      #pragma unroll
      for (int reg = 0; reg < 16; reg++) {
        int row = (reg & 3) + 8*(reg >> 2) + 4*khl;
        tr[row*33 + ln31] = acc[m][ch][reg];
      }
      __builtin_amdgcn_s_waitcnt(0);        // wave-local LDS ordering
      #pragma unroll
      for (int gs = 0; gs < 2; gs++) {
        int g = khl + gs*2;
        Pack8 p;
        #pragma unroll
        for (int e = 0; e < 8; e++) p.h[e] = (__bf16)tr[(g*8 + e)*33 + ln31];
        RAWu[((size_t)(b*32 + Gb + g)*192 + i)*192 + j0 + ch*32 + ln31] = p.u;
      }
      __builtin_amdgcn_s_waitcnt(0);
    }
  }

  __syncthreads();
  if (tid < 64) {
    atomicAdd(&STAT2[oc0 + tid], sstat[tid]);
    atomicAdd(&STAT2[C2 + oc0 + tid], sstat[64 + tid]);
  }
}

// ---------------- fused: BN2 norm+relu, gate projection, next conv input (padded) ----------------
template<int WRITE_NEXT>
__global__ void k_bn2_norm_gate(const __bf16* __restrict__ rawb, const float* __restrict__ STAT2,
                                const float* __restrict__ g, const float* __restrict__ bb,
                                const float* __restrict__ wd, const float* __restrict__ CLn,
                                __bf16* __restrict__ inb_next, float* __restrict__ tg) {
  int i = blockIdx.x, b = blockIdx.y, j = threadIdx.x;
  __shared__ float sscale[C2], sshift[C2], swd[HH*C2];
  const float inv = 1.f / (float)(BB*NN);
  for (int c = j; c < C2; c += 192) {
    float mean = STAT2[c] * inv;
    float var  = STAT2[C2 + c] * inv - mean*mean;
    float rstd = rsqrtf(var + EPS);
    float sc = rstd * g[c];
    sscale[c] = sc;
    sshift[c] = bb[c] - mean*sc;
  }
  for (int idx = j; idx < HH*C2; idx += 192) swd[idx] = wd[idx];
  __syncthreads();
  float gacc[HH] = {};
  const uint4* RAWu = (const uint4*)rawb;
  for (int cu = 0; cu < 32; cu++) {
    Pack8 pr; pr.u = RAWu[((size_t)(b*32 + cu)*NP + i)*NP + j];
    Pack8 p;
    #pragma unroll
    for (int e = 0; e < 8; e++) {
      int c = cu*8 + e;
      float v = (float)pr.h[e];
      v = fmaxf(fmaf(v, sscale[c], sshift[c]), 0.f);
      if (WRITE_NEXT) {
        float nv = v + ((c < DIM) ? CLn[(b*DIM + c)*NP + i] : CLn[(b*DIM + c - DIM)*NP + j]);
        p.h[e] = (__bf16)nv;
      }
      #pragma unroll
      for (int h = 0; h < HH; h++) gacc[h] = fmaf(v, swd[h*C2 + c], gacc[h]);
    }
    if (WRITE_NEXT) {
      size_t unit = ((((size_t)(b*16 + (cu>>1))*PR + (i+1))*PC + (j+8))*2 + (cu&1));
      ((uint4*)inb_next)[unit] = p.u;
    }
  }
  for (int h = 0; h < HH; h++)
    tg[((size_t)(b*HH + h)*NP + i)*NP + j] = gacc[h];
}

// ---------------- attention row with inline gate=sigmoid(t+t^T+bias); zeroes STAT2 ----------------
__global__ void k_attn(const float* __restrict__ Q, const float* __restrict__ K,
                       const float* __restrict__ V, const float* __restrict__ tg,
                       const float* __restrict__ wdb, const float* __restrict__ mask,
                       float* __restrict__ upd, float* __restrict__ STAT2) {
  int i = blockIdx.x, h = blockIdx.y, b = blockIdx.z, j = threadIdx.x;
  if (i == 0 && h == 0 && b == 0)
    for (int s = j; s < 2*C2; s += 192) STAT2[s] = 0.f;
  size_t bh = (size_t)(b*HH + h);
  __shared__ float sq[DHH];
  __shared__ float sb[NP];
  __shared__ float sattn[NP];
  if (j < DHH) sq[j] = Q[(bh*NP + i)*DHH + j];
  __syncthreads();
  const float* kr = K + (bh*NP + j)*DHH;
  float a = 0.f;
  #pragma unroll
  for (int d = 0; d < DHH; d++) a = fmaf(sq[d], kr[d], a);
  a *= 0.25f;
  sb[j] = a; __syncthreads();
  for (int s = 128; s > 0; s >>= 1) {
    if (j < s && j + s < NP) sb[j] = fmaxf(sb[j], sb[j+s]);
    __syncthreads();
  }
  float amax = sb[0];
  __syncthreads();
  float e = expf(a - amax) * mask[b*NP + j];
  sb[j] = e; __syncthreads();
  for (int s = 128; s > 0; s >>= 1) {
    if (j < s && j + s < NP) sb[j] += sb[j+s];
    __syncthreads();
  }
  float denom = sb[0] + 1e-6f;
  float gv = tg[(bh*NP + i)*NP + j] + tg[(bh*NP + j)*NP + i] + wdb[h];
  float gate = 1.f / (1.f + expf(-gv));
  float attn = (e / denom) * gate;
  sattn[j] = attn;
  __syncthreads();
  if (j < DHH) {
    float acc = 0.f;
    for (int jj = 0; jj < NP; jj++)
      acc = fmaf(sattn[jj], V[(bh*NP + jj)*DHH + j], acc);
    upd[((size_t)(b*NP) + i)*DIM + h*DHH + j] = acc;
  }
}

// ---------------- x = relu((x + upd) @ wl^T + bl) ----------------
__global__ void k_xup(float* __restrict__ X, const float* __restrict__ upd,
                      const float* __restrict__ wl, const float* __restrict__ bl) {
  int t = blockIdx.x, b = blockIdx.y, d = threadIdx.x;
  __shared__ float sy[DIM];
  size_t o = (size_t)(b*NP + t)*DIM;
  sy[d] = X[o + d] + upd[o + d];
  __syncthreads();
  float acc = bl[d];
  for (int e = 0; e < DIM; e++) acc = fmaf(wl[d*DIM + e], sy[e], acc);
  X[o + d] = fmaxf(acc, 0.f);
}

// ---------------- out = relu(x @ fc^T + fb) ----------------
__global__ void k_final(const float* __restrict__ X, const float* __restrict__ fc,
                        const float* __restrict__ fb, float* __restrict__ out) {
  int t = blockIdx.x, b = blockIdx.y, d = threadIdx.x;
  __shared__ float sy[DIM];
  size_t o = (size_t)(b*NP + t)*DIM;
  sy[d] = X[o + d];
  __syncthreads();
  float acc = fb[d];
  for (int e = 0; e < DIM; e++) acc = fmaf(fc[d*DIM + e], sy[e], acc);
  out[o + d] = fmaxf(acc, 0.f);
}

extern "C" void kernel_launch(void* const* d_in, const int* in_sizes, int n_in,
                              void* d_out, int out_size, void* d_ws, size_t ws_size,
                              hipStream_t stream) {
  const float* seq     = (const float*)d_in[0];
  const float* mask    = (const float*)d_in[1];
  const float* conv1_w = (const float*)d_in[2];
  const float* conv2_w = (const float*)d_in[3];
  const float* ln_g    = (const float*)d_in[4];
  const float* ln_b    = (const float*)d_in[5];
  const float* c1d_w   = (const float*)d_in[6];
  const float* bn1_g   = (const float*)d_in[7];
  const float* bn1_b   = (const float*)d_in[8];
  const float* c2d_w   = (const float*)d_in[9];
  const float* bn2_g   = (const float*)d_in[10];
  const float* bn2_b   = (const float*)d_in[11];
  const float* wq_w    = (const float*)d_in[12];
  const float* wq_b    = (const float*)d_in[13];
  const float* wk_w    = (const float*)d_in[14];
  const float* wk_b    = (const float*)d_in[15];
  const float* wv_w    = (const float*)d_in[16];
  const float* wv_b    = (const float*)d_in[17];
  const float* wd_w    = (const float*)d_in[18];
  const float* wd_b    = (const float*)d_in[19];
  const float* wl_w    = (const float*)d_in[20];
  const float* wl_b    = (const float*)d_in[21];
  const float* fc_w    = (const float*)d_in[22];
  const float* fc_b    = (const float*)d_in[23];
  float* out = (float*)d_out;

  float* ws = (float*)d_ws;
  float* X    = ws; ws += BB*NP*DIM;
  float* Cc   = ws; ws += BB*DIM*NP;
  float* CL0  = ws; ws += BB*DIM*NP;
  float* CL1  = ws; ws += BB*DIM*NP;
  float* CL2  = ws; ws += BB*DIM*NP;
  float* Q    = ws; ws += BB*NP*DIM;
  float* K    = ws; ws += BB*NP*DIM;
  float* V    = ws; ws += BB*NP*DIM;
  float* UPD  = ws; ws += BB*NP*DIM;
  float* TG   = ws; ws += (size_t)BB*HH*NN;
  float* STAT2= ws; ws += 2*C2;
  __bf16* RAW = (__bf16*)ws; ws += (size_t)BB*C2*NN/2;        // packed bf16 conv output
  __bf16* INB = (__bf16*)ws; ws += (size_t)BB*16*PR*PC*2*16/4; // padded bf16 conv input
  __bf16* WTB = (__bf16*)ws; ws += (size_t)LL*C2*C2*9/2;

  const float* CL[3] = {CL0, CL1, CL2};

  k_wprep<<<LL*16*9, 512, 0, stream>>>(c2d_w, WTB);
  k_conv_init<<<dim3(NP, BB), DIM, 0, stream>>>(seq, conv1_w, conv2_w, X, Cc);
  k_conv1d_bn_relu<<<DIM, NP, 0, stream>>>(Cc,  c1d_w + 0*(size_t)DIM*DIM*3, bn1_g + 0*DIM, bn1_b + 0*DIM, CL0);
  k_conv1d_bn_relu<<<DIM, NP, 0, stream>>>(CL0, c1d_w + 1*(size_t)DIM*DIM*3, bn1_g + 1*DIM, bn1_b + 1*DIM, CL1);
  k_conv1d_bn_relu<<<DIM, NP, 0, stream>>>(CL1, c1d_w + 2*(size_t)DIM*DIM*3, bn1_g + 2*DIM, bn1_b + 2*DIM, CL2);
  k_make_convin<<<(BB*16*PR*PC*2)/256, 256, 0, stream>>>(Cc, CL0, INB, STAT2);

  for (int l = 0; l < LL; l++) {
    k_lnqkv<<<dim3(NP, BB), DIM, 0, stream>>>(X, CL[l], ln_g + l*DIM, ln_b + l*DIM,
                                              wq_w + (size_t)l*DIM*DIM, wq_b + l*DIM,
                                              wk_w + (size_t)l*DIM*DIM, wk_b + l*DIM,
                                              wv_w + (size_t)l*DIM*DIM, wv_b + l*DIM, Q, K, V);
    k_conv2d_mfma<<<dim3(3, 48, 8), 256, 0, stream>>>(INB, WTB + (size_t)l*16*9*2*256*8, RAW, STAT2);
    if (l < LL-1)
      k_bn2_norm_gate<1><<<dim3(NP, BB), NP, 0, stream>>>(RAW, STAT2, bn2_g + l*C2, bn2_b + l*C2,
                                                          wd_w + (size_t)l*HH*C2, CL[l+1], INB, TG);
    else
      k_bn2_norm_gate<0><<<dim3(NP, BB), NP, 0, stream>>>(RAW, STAT2, bn2_g + l*C2, bn2_b + l*C2,
                                                          wd_w + (size_t)l*HH*C2, nullptr, nullptr, TG);
    k_attn<<<dim3(NP, HH, BB), NP, 0, stream>>>(Q, K, V, TG, wd_b + l*HH, mask, UPD, STAT2);
    k_xup<<<dim3(NP, BB), DIM, 0, stream>>>(X, UPD, wl_w + (size_t)l*DIM*DIM, wl_b + l*DIM);
  }
  k_final<<<dim3(NP, BB), DIM, 0, stream>>>(X, fc_w, fc_b, out);
}

// Round 6
// 730.805 us; speedup vs baseline: 1.6468x; 1.0014x over previous
//
#include <hip/hip_runtime.h>
#include <math.h>

#define IN_DIM 20
#define DIM 128
#define HH 8
#define LL 3
#define BB 2
#define NP 192
#define DHH 16
#define C2 256
#define NN (NP*NP)
#define EPS 1e-5f

// padded conv-input geometry
#define PR 200
#define PC 224

typedef __bf16 bf16x8 __attribute__((ext_vector_type(8)));
typedef float  f32x16 __attribute__((ext_vector_type(16)));

union Pack8 { __bf16 h[8]; uint4 u; };

#define GLOAD16(gp, lp) \
  __builtin_amdgcn_global_load_lds((const __attribute__((address_space(1))) uint4*)(gp), \
                                   (__attribute__((address_space(3))) uint4*)(lp), 16, 0, 0)

// ---------------- init: conv1d over seq for both x and c ----------------
__global__ void k_conv_init(const float* __restrict__ seq, const float* __restrict__ w1,
                            const float* __restrict__ w2, float* __restrict__ X,
                            float* __restrict__ Cc) {
  int t = blockIdx.x, b = blockIdx.y, oc = threadIdx.x;
  __shared__ float ss[3][IN_DIM];
  if (threadIdx.x < 3*IN_DIM) {
    int k = threadIdx.x / IN_DIM, ic = threadIdx.x % IN_DIM;
    int tt = t + k - 1;
    ss[k][ic] = (tt >= 0 && tt < NP) ? seq[(b*NP + tt)*IN_DIM + ic] : 0.f;
  }
  __syncthreads();
  float a1 = 0.f, a2 = 0.f;
  #pragma unroll
  for (int ic = 0; ic < IN_DIM; ic++) {
    #pragma unroll
    for (int k = 0; k < 3; k++) {
      float sv = ss[k][ic];
      a1 = fmaf(w1[(oc*IN_DIM + ic)*3 + k], sv, a1);
      a2 = fmaf(w2[(oc*IN_DIM + ic)*3 + k], sv, a2);
    }
  }
  X[(b*NP + t)*DIM + oc] = a1;
  Cc[(b*DIM + oc)*NP + t] = a2;
}

// ---------------- conv1d + BN(train stats) + relu, fused ----------------
__global__ void k_conv1d_bn_relu(const float* __restrict__ cin, const float* __restrict__ w,
                                 const float* __restrict__ g, const float* __restrict__ bb,
                                 float* __restrict__ cout) {
  int oc = blockIdx.x;
  int t = threadIdx.x;
  float raw[BB];
  for (int b = 0; b < BB; b++) {
    float acc = 0.f;
    for (int ic = 0; ic < DIM; ic++) {
      const float* cr = cin + (b*DIM + ic)*NP;
      const float* wr = w + (oc*DIM + ic)*3;
      float lf = (t > 0)      ? cr[t-1] : 0.f;
      float mf = cr[t];
      float rf = (t < NP-1)   ? cr[t+1] : 0.f;
      acc = fmaf(lf, wr[0], acc);
      acc = fmaf(mf, wr[1], acc);
      acc = fmaf(rf, wr[2], acc);
    }
    raw[b] = acc;
  }
  __shared__ float sb[NP];
  sb[t] = raw[0] + raw[1];
  __syncthreads();
  for (int s = 128; s > 0; s >>= 1) {
    if (t < s && t + s < NP) sb[t] += sb[t + s];
    __syncthreads();
  }
  float mean = sb[0] / (float)(BB*NP);
  __syncthreads();
  sb[t] = raw[0]*raw[0] + raw[1]*raw[1];
  __syncthreads();
  for (int s = 128; s > 0; s >>= 1) {
    if (t < s && t + s < NP) sb[t] += sb[t + s];
    __syncthreads();
  }
  float var = sb[0] / (float)(BB*NP) - mean*mean;
  float rstd = rsqrtf(var + EPS);
  float gg = g[oc], bo = bb[oc];
  for (int b = 0; b < BB; b++)
    cout[(b*DIM + oc)*NP + t] = fmaxf((raw[b] - mean)*rstd*gg + bo, 0.f);
}

// ---------------- layer-0 only: x = LN(x + c^T), q,k,v ----------------
__global__ void k_lnqkv(float* __restrict__ X, const float* __restrict__ cc,
                        const float* __restrict__ g, const float* __restrict__ bb,
                        const float* __restrict__ wq, const float* __restrict__ bq,
                        const float* __restrict__ wk, const float* __restrict__ bk,
                        const float* __restrict__ wv, const float* __restrict__ bv,
                        float* __restrict__ Q, float* __restrict__ K, float* __restrict__ V) {
  int t = blockIdx.x, b = blockIdx.y, d = threadIdx.x;
  __shared__ float sb[DIM];
  __shared__ float sy[DIM];
  float v = X[(b*NP + t)*DIM + d] + cc[(b*DIM + d)*NP + t];
  sb[d] = v; __syncthreads();
  for (int s = 64; s > 0; s >>= 1) { if (d < s) sb[d] += sb[d+s]; __syncthreads(); }
  float mean = sb[0] / (float)DIM;
  __syncthreads();
  float dv = v - mean;
  sb[d] = dv*dv; __syncthreads();
  for (int s = 64; s > 0; s >>= 1) { if (d < s) sb[d] += sb[d+s]; __syncthreads(); }
  float var = sb[0] / (float)DIM;
  float rstd = rsqrtf(var + EPS);
  float xn = dv * rstd * g[d] + bb[d];
  X[(b*NP + t)*DIM + d] = xn;
  sy[d] = xn;
  __syncthreads();
  float aq = bq[d], ak = bk[d], av = bv[d];
  for (int e = 0; e < DIM; e++) {
    float xv = sy[e];
    aq = fmaf(wq[d*DIM + e], xv, aq);
    ak = fmaf(wk[d*DIM + e], xv, ak);
    av = fmaf(wv[d*DIM + e], xv, av);
  }
  int h = d >> 4, dh = d & 15;
  size_t o = ((size_t)(b*HH + h)*NP + t)*DHH + dh;
  Q[o] = fmaxf(aq, 0.f); K[o] = fmaxf(ak, 0.f); V[o] = fmaxf(av, 0.f);
}

// ---------------- conv2d weight prep ----------------
__global__ void k_wprep(const float* __restrict__ w, __bf16* __restrict__ wtb) {
  int blk = blockIdx.x;            // 3*16*9
  int kk = blk % 9;
  int chunk = (blk / 9) % 16;
  int l = blk / (9*16);
  int kh = threadIdx.x >> 8;
  int oc = threadIdx.x & 255;
  Pack8 p;
  #pragma unroll
  for (int e = 0; e < 8; e++) {
    int ic = chunk*16 + kh*8 + e;
    p.h[e] = (__bf16)w[(((size_t)(l*C2 + oc))*C2 + ic)*9 + kk];
  }
  size_t unit = ((((size_t)(l*16 + chunk)*9 + kk)*2 + kh)*256 + oc);
  ((uint4*)wtb)[unit] = p.u;
}

// ---------------- layer-0 conv input build (padded); zeroes 3x STAT2 ----------------
__global__ void k_make_convin(const float* __restrict__ Cc, const float* __restrict__ CL0,
                              __bf16* __restrict__ inb, float* __restrict__ STATALL) {
  int idx = blockIdx.x*256 + threadIdx.x;
  if (blockIdx.x == 0) {
    for (int z = threadIdx.x; z < 3*2*C2; z += 256) STATALL[z] = 0.f;
  }
  int kh = idx & 1;
  int t = idx >> 1;
  int gcol = t % PC; int t2 = t / PC;
  int grow = t2 % PR; int t3 = t2 / PR;
  int chunk = t3 & 15; int b = t3 >> 4;
  int i = grow - 1, j = gcol - 8;
  Pack8 p;
  if ((unsigned)i < 192u && (unsigned)j < 192u) {
    #pragma unroll
    for (int e = 0; e < 8; e++) {
      int c = chunk*16 + kh*8 + e;
      float v;
      if (c < DIM) v = Cc[(b*DIM + c)*NP + i] + CL0[(b*DIM + c)*NP + i];
      else { int cc = c - DIM; v = Cc[(b*DIM + cc)*NP + j] + CL0[(b*DIM + cc)*NP + j]; }
      p.h[e] = (__bf16)v;
    }
  } else {
    #pragma unroll
    for (int e = 0; e < 8; e++) p.h[e] = (__bf16)0.f;
  }
  ((uint4*)inb)[idx] = p.u;
}

// ---------------- heavy kernel: implicit-GEMM bf16 MFMA 3x3 conv (UNCHANGED from R5) ----------------
__global__ __launch_bounds__(256, 2)
void k_conv2d_mfma(const __bf16* __restrict__ inb,
                   const __bf16* __restrict__ wtb,
                   __bf16* __restrict__ rawb,
                   float* __restrict__ STAT2) {
  __shared__ __align__(16) uint4 sbuf[2*2304];
  int tid = threadIdx.x;
  int jt = blockIdx.x, it = blockIdx.y, zz = blockIdx.z;
  int b = zz >> 2, oct = zz & 3;
  int i0 = it*4, j0 = jt*64, oc0 = oct*64;
  int lane = tid & 63, wv = tid >> 6;
  int wn = wv;
  int ln31 = lane & 31, khl = lane >> 5;

  const uint4* gW = (const uint4*)wtb;
  const uint4* gI = (const uint4*)inb;

  f32x16 acc[2][2];
  #pragma unroll
  for (int m = 0; m < 2; m++)
    #pragma unroll
    for (int n = 0; n < 2; n++)
      #pragma unroll
      for (int q = 0; q < 16; q++) acc[m][n][q] = 0.f;

  auto issue = [&](int chunk, int buf) {
    uint4* lbase = sbuf + buf*2304;
    const uint4* gWc = gW + (size_t)chunk*4608 + oc0;
    const uint4* gIc = gI + (((size_t)(b*16 + chunk)*PR + i0)*PC + j0)*2;
    #pragma unroll
    for (int t = 0; t < 9; t++) {
      int L = wv*9 + t;
      if (L < 18) {
        GLOAD16(gWc + L*256 + lane, lbase + L*64);
      } else {
        int Lp = L - 18;
        int r = Lp / 3, s = Lp - r*3;
        int local = s*64 + lane;
        int kh = local >= 96;
        int c = local - (kh ? 96 : 0);
        GLOAD16(gIc + ((size_t)r*PC + c)*2 + kh, lbase + 1152 + Lp*64);
      }
    }
  };

  issue(0, 0);

  for (int chunk = 0; chunk < 16; ++chunk) {
    int buf = chunk & 1;
    __syncthreads();
    if (chunk < 15) issue(chunk + 1, buf ^ 1);
    const __bf16* Wl = (const __bf16*)(sbuf + buf*2304);
    const __bf16* Il = (const __bf16*)(sbuf + buf*2304 + 1152);
    #pragma unroll
    for (int kj = 0; kj < 3; kj++) {
      bf16x8 bfr[3][2];
      #pragma unroll
      for (int ki = 0; ki < 3; ki++) {
        int r = wn + ki;
        #pragma unroll
        for (int ch = 0; ch < 2; ch++) {
          int c = ch*32 + ln31 + kj + 7;
          bfr[ki][ch] = *(const bf16x8*)(Il + (r*192 + khl*96 + c)*8);
        }
      }
      #pragma unroll
      for (int ki = 0; ki < 3; ki++) {
        int kk = ki*3 + kj;
        bf16x8 a0 = *(const bf16x8*)(Wl + ((kk*2 + khl)*64 +      ln31)*8);
        bf16x8 a1 = *(const bf16x8*)(Wl + ((kk*2 + khl)*64 + 32 + ln31)*8);
        #pragma unroll
        for (int ch = 0; ch < 2; ch++) {
          acc[0][ch] = __builtin_amdgcn_mfma_f32_32x32x16_bf16(a0, bfr[ki][ch], acc[0][ch], 0, 0, 0);
          acc[1][ch] = __builtin_amdgcn_mfma_f32_32x32x16_bf16(a1, bfr[ki][ch], acc[1][ch], 0, 0, 0);
        }
      }
    }
  }

  __syncthreads();
  float* trAll = (float*)sbuf;
  float* tr = trAll + wv*(32*33);
  float* sstat = trAll + 4*32*33;
  if (tid < 128) sstat[tid] = 0.f;
  __syncthreads();

  #pragma unroll
  for (int m = 0; m < 2; m++) {
    #pragma unroll
    for (int reg = 0; reg < 16; reg++) {
      float v0 = acc[m][0][reg], v1 = acc[m][1][reg];
      float s = v0 + v1, s2 = v0*v0 + v1*v1;
      #pragma unroll
      for (int msk = 1; msk <= 16; msk <<= 1) { s += __shfl_xor(s, msk); s2 += __shfl_xor(s2, msk); }
      if (ln31 == 0) {
        int oc_l = m*32 + (reg & 3) + 8*(reg >> 2) + 4*khl;
        atomicAdd(&sstat[oc_l], s);
        atomicAdd(&sstat[64 + oc_l], s2);
      }
    }
  }

  int i = i0 + wn;
  uint4* RAWu = (uint4*)rawb;
  #pragma unroll
  for (int m = 0; m < 2; m++) {
    int Gb = (oc0 + m*32) >> 3;
    #pragma unroll
    for (int ch = 0; ch < 2; ch++) {
      #pragma unroll
      for (int reg = 0; reg < 16; reg++) {
        int row = (reg & 3) + 8*(reg >> 2) + 4*khl;
        tr[row*33 + ln31] = acc[m][ch][reg];
      }
      __builtin_amdgcn_s_waitcnt(0);
      #pragma unroll
      for (int gs = 0; gs < 2; gs++) {
        int g = khl + gs*2;
        Pack8 p;
        #pragma unroll
        for (int e = 0; e < 8; e++) p.h[e] = (__bf16)tr[(g*8 + e)*33 + ln31];
        RAWu[((size_t)(b*32 + Gb + g)*192 + i)*192 + j0 + ch*32 + ln31] = p.u;
      }
      __builtin_amdgcn_s_waitcnt(0);
    }
  }

  __syncthreads();
  if (tid < 64) {
    atomicAdd(&STAT2[oc0 + tid], sstat[tid]);
    atomicAdd(&STAT2[C2 + oc0 + tid], sstat[64 + tid]);
  }
}

// ---------------- fused: BN2 norm+relu, gate projection, next conv input (padded) ----------------
template<int WRITE_NEXT>
__global__ void k_bn2_norm_gate(const __bf16* __restrict__ rawb, const float* __restrict__ STAT2,
                                const float* __restrict__ g, const float* __restrict__ bb,
                                const float* __restrict__ wd, const float* __restrict__ CLn,
                                __bf16* __restrict__ inb_next, float* __restrict__ tg) {
  int i = blockIdx.x, b = blockIdx.y, j = threadIdx.x;
  __shared__ float sscale[C2], sshift[C2], swd[HH*C2];
  const float inv = 1.f / (float)(BB*NN);
  for (int c = j; c < C2; c += 192) {
    float mean = STAT2[c] * inv;
    float var  = STAT2[C2 + c] * inv - mean*mean;
    float rstd = rsqrtf(var + EPS);
    float sc = rstd * g[c];
    sscale[c] = sc;
    sshift[c] = bb[c] - mean*sc;
  }
  for (int idx = j; idx < HH*C2; idx += 192) swd[idx] = wd[idx];
  __syncthreads();
  float gacc[HH] = {};
  const uint4* RAWu = (const uint4*)rawb;
  for (int cu = 0; cu < 32; cu++) {
    Pack8 pr; pr.u = RAWu[((size_t)(b*32 + cu)*NP + i)*NP + j];
    Pack8 p;
    #pragma unroll
    for (int e = 0; e < 8; e++) {
      int c = cu*8 + e;
      float v = (float)pr.h[e];
      v = fmaxf(fmaf(v, sscale[c], sshift[c]), 0.f);
      if (WRITE_NEXT) {
        float nv = v + ((c < DIM) ? CLn[(b*DIM + c)*NP + i] : CLn[(b*DIM + c - DIM)*NP + j]);
        p.h[e] = (__bf16)nv;
      }
      #pragma unroll
      for (int h = 0; h < HH; h++) gacc[h] = fmaf(v, swd[h*C2 + c], gacc[h]);
    }
    if (WRITE_NEXT) {
      size_t unit = ((((size_t)(b*16 + (cu>>1))*PR + (i+1))*PC + (j+8))*2 + (cu&1));
      ((uint4*)inb_next)[unit] = p.u;
    }
  }
  for (int h = 0; h < HH; h++)
    tg[((size_t)(b*HH + h)*NP + i)*NP + j] = gacc[h];
}

// ---------------- MEGA-fused: attention(all heads) + xup + [next LN/QKV | final FC] ----------------
// grid (NP, BB), block NP (192 = 3 waves). MODE 0: mid layer; MODE 1: last layer (writes out).
template<int MODE>
__global__ __launch_bounds__(192)
void k_attnx(const float* __restrict__ Q, const float* __restrict__ K,
             const float* __restrict__ V, const float* __restrict__ tg,
             const float* __restrict__ wdb, const float* __restrict__ mask,
             float* __restrict__ X,
             const float* __restrict__ wl, const float* __restrict__ bl,
             const float* __restrict__ ccn,                     // MODE0: CL[l+1]
             const float* __restrict__ lng, const float* __restrict__ lnb,
             const float* __restrict__ wq, const float* __restrict__ bq,
             const float* __restrict__ wk, const float* __restrict__ bk,
             const float* __restrict__ wv, const float* __restrict__ bv,
             float* __restrict__ Qn, float* __restrict__ Kn, float* __restrict__ Vn,
             const float* __restrict__ fc, const float* __restrict__ fb,
             float* __restrict__ out) {
  int i = blockIdx.x, b = blockIdx.y, j = threadIdx.x;
  int lane = j & 63, wvv = j >> 6;
  __shared__ float sattn[HH][NP];
  __shared__ float supd[DIM];
  __shared__ float sy[DIM];
  __shared__ float sred[3];
  float mk = mask[b*NP + j];

  // scores + masked softmax + gate, per head
  for (int h = 0; h < HH; h++) {
    size_t bh = (size_t)(b*HH + h);
    const float4* qr = (const float4*)(Q + (bh*NP + i)*DHH);
    const float4* kr = (const float4*)(K + (bh*NP + j)*DHH);
    float a = 0.f;
    #pragma unroll
    for (int q4 = 0; q4 < 4; q4++) {
      float4 qv = qr[q4], kv = kr[q4];
      a = fmaf(qv.x, kv.x, a); a = fmaf(qv.y, kv.y, a);
      a = fmaf(qv.z, kv.z, a); a = fmaf(qv.w, kv.w, a);
    }
    a *= 0.25f;
    float gv = tg[(bh*NP + i)*NP + j] + tg[(bh*NP + j)*NP + i] + wdb[h];
    float gate = 1.f / (1.f + expf(-gv));
    float m = a;
    #pragma unroll
    for (int s = 32; s > 0; s >>= 1) m = fmaxf(m, __shfl_xor(m, s));
    if (lane == 0) sred[wvv] = m;
    __syncthreads();
    float amax = fmaxf(fmaxf(sred[0], sred[1]), sred[2]);
    float e = expf(a - amax) * mk;
    float ss = e;
    #pragma unroll
    for (int s = 32; s > 0; s >>= 1) ss += __shfl_xor(ss, s);
    __syncthreads();
    if (lane == 0) sred[wvv] = ss;
    __syncthreads();
    float denom = sred[0] + sred[1] + sred[2] + 1e-6f;
    sattn[h][j] = (e / denom) * gate;
    __syncthreads();
  }

  // PV: threads (h,d) for j<128
  if (j < DIM) {
    int h = j >> 4, d = j & 15;
    size_t bh = (size_t)(b*HH + h);
    float acc = 0.f;
    for (int jj = 0; jj < NP; jj++)
      acc = fmaf(sattn[h][jj], V[(bh*NP + jj)*DHH + d], acc);
    supd[h*DHH + d] = acc;
  }
  __syncthreads();

  // xup: X' = relu((X + upd) @ wl^T + bl)
  size_t o = (size_t)(b*NP + i)*DIM;
  if (j < DIM) sy[j] = X[o + j] + supd[j];
  __syncthreads();
  float xr = 0.f;
  if (j < DIM) {
    float acc = bl[j];
    for (int e = 0; e < DIM; e++) acc = fmaf(wl[j*DIM + e], sy[e], acc);
    xr = fmaxf(acc, 0.f);
  }
  __syncthreads();            // sy reuse below

  if (MODE == 0) {
    // next layer: x = LN(xr + cc^T), then QKV
    float v = 0.f;
    if (j < DIM) v = xr + ccn[(b*DIM + j)*NP + i];
    float s = (j < DIM) ? v : 0.f;
    #pragma unroll
    for (int m = 32; m > 0; m >>= 1) s += __shfl_xor(s, m);
    if (lane == 0 && wvv < 2) sred[wvv] = s;
    __syncthreads();
    float mean = (sred[0] + sred[1]) * (1.f/128.f);
    float dv = v - mean;
    float q = (j < DIM) ? dv*dv : 0.f;
    #pragma unroll
    for (int m = 32; m > 0; m >>= 1) q += __shfl_xor(q, m);
    __syncthreads();
    if (lane == 0 && wvv < 2) sred[wvv] = q;
    __syncthreads();
    float var = (sred[0] + sred[1]) * (1.f/128.f);
    float rstd = rsqrtf(var + EPS);
    if (j < DIM) {
      float xn = dv * rstd * lng[j] + lnb[j];
      X[o + j] = xn;
      sy[j] = xn;
    }
    __syncthreads();
    if (j < DIM) {
      float aq = bq[j], ak = bk[j], av = bv[j];
      for (int e = 0; e < DIM; e++) {
        float xv = sy[e];
        aq = fmaf(wq[j*DIM + e], xv, aq);
        ak = fmaf(wk[j*DIM + e], xv, ak);
        av = fmaf(wv[j*DIM + e], xv, av);
      }
      int h = j >> 4, dh = j & 15;
      size_t oo = ((size_t)(b*HH + h)*NP + i)*DHH + dh;
      Qn[oo] = fmaxf(aq, 0.f); Kn[oo] = fmaxf(ak, 0.f); Vn[oo] = fmaxf(av, 0.f);
    }
  } else {
    // final: out = relu(xr @ fc^T + fb)
    if (j < DIM) sy[j] = xr;
    __syncthreads();
    if (j < DIM) {
      float acc = fb[j];
      for (int e = 0; e < DIM; e++) acc = fmaf(fc[j*DIM + e], sy[e], acc);
      out[o + j] = fmaxf(acc, 0.f);
    }
  }
}

extern "C" void kernel_launch(void* const* d_in, const int* in_sizes, int n_in,
                              void* d_out, int out_size, void* d_ws, size_t ws_size,
                              hipStream_t stream) {
  const float* seq     = (const float*)d_in[0];
  const float* mask    = (const float*)d_in[1];
  const float* conv1_w = (const float*)d_in[2];
  const float* conv2_w = (const float*)d_in[3];
  const float* ln_g    = (const float*)d_in[4];
  const float* ln_b    = (const float*)d_in[5];
  const float* c1d_w   = (const float*)d_in[6];
  const float* bn1_g   = (const float*)d_in[7];
  const float* bn1_b   = (const float*)d_in[8];
  const float* c2d_w   = (const float*)d_in[9];
  const float* bn2_g   = (const float*)d_in[10];
  const float* bn2_b   = (const float*)d_in[11];
  const float* wq_w    = (const float*)d_in[12];
  const float* wq_b    = (const float*)d_in[13];
  const float* wk_w    = (const float*)d_in[14];
  const float* wk_b    = (const float*)d_in[15];
  const float* wv_w    = (const float*)d_in[16];
  const float* wv_b    = (const float*)d_in[17];
  const float* wd_w    = (const float*)d_in[18];
  const float* wd_b    = (const float*)d_in[19];
  const float* wl_w    = (const float*)d_in[20];
  const float* wl_b    = (const float*)d_in[21];
  const float* fc_w    = (const float*)d_in[22];
  const float* fc_b    = (const float*)d_in[23];
  float* out = (float*)d_out;

  float* ws = (float*)d_ws;
  float* X    = ws; ws += BB*NP*DIM;
  float* Cc   = ws; ws += BB*DIM*NP;
  float* CL0  = ws; ws += BB*DIM*NP;
  float* CL1  = ws; ws += BB*DIM*NP;
  float* CL2  = ws; ws += BB*DIM*NP;
  float* Q0   = ws; ws += BB*NP*DIM;
  float* K0   = ws; ws += BB*NP*DIM;
  float* V0   = ws; ws += BB*NP*DIM;
  float* Q1   = ws; ws += BB*NP*DIM;
  float* K1   = ws; ws += BB*NP*DIM;
  float* V1   = ws; ws += BB*NP*DIM;
  float* TG0  = ws; ws += (size_t)BB*HH*NN;
  float* TG1  = ws; ws += (size_t)BB*HH*NN;
  float* STATALL = ws; ws += 3*2*C2;
  __bf16* RAW = (__bf16*)ws; ws += (size_t)BB*C2*NN/2;
  __bf16* INB = (__bf16*)ws; ws += (size_t)BB*16*PR*PC*2*16/4;
  __bf16* WTB = (__bf16*)ws; ws += (size_t)LL*C2*C2*9/2;

  k_wprep<<<LL*16*9, 512, 0, stream>>>(c2d_w, WTB);
  k_conv_init<<<dim3(NP, BB), DIM, 0, stream>>>(seq, conv1_w, conv2_w, X, Cc);
  k_conv1d_bn_relu<<<DIM, NP, 0, stream>>>(Cc,  c1d_w + 0*(size_t)DIM*DIM*3, bn1_g + 0*DIM, bn1_b + 0*DIM, CL0);
  k_conv1d_bn_relu<<<DIM, NP, 0, stream>>>(CL0, c1d_w + 1*(size_t)DIM*DIM*3, bn1_g + 1*DIM, bn1_b + 1*DIM, CL1);
  k_conv1d_bn_relu<<<DIM, NP, 0, stream>>>(CL1, c1d_w + 2*(size_t)DIM*DIM*3, bn1_g + 2*DIM, bn1_b + 2*DIM, CL2);
  k_make_convin<<<(BB*16*PR*PC*2)/256, 256, 0, stream>>>(Cc, CL0, INB, STATALL);
  k_lnqkv<<<dim3(NP, BB), DIM, 0, stream>>>(X, CL0, ln_g, ln_b,
                                            wq_w, wq_b, wk_w, wk_b, wv_w, wv_b, Q0, K0, V0);

  // ---- layer 0 ----
  k_conv2d_mfma<<<dim3(3, 48, 8), 256, 0, stream>>>(INB, WTB + 0*(size_t)16*9*2*256*8, RAW, STATALL + 0*2*C2);
  k_bn2_norm_gate<1><<<dim3(NP, BB), NP, 0, stream>>>(RAW, STATALL + 0*2*C2, bn2_g + 0*C2, bn2_b + 0*C2,
                                                      wd_w + 0*(size_t)HH*C2, CL1, INB, TG0);
  k_attnx<0><<<dim3(NP, BB), NP, 0, stream>>>(Q0, K0, V0, TG0, wd_b + 0*HH, mask, X,
                                              wl_w + 0*(size_t)DIM*DIM, wl_b + 0*DIM,
                                              CL1, ln_g + 1*DIM, ln_b + 1*DIM,
                                              wq_w + 1*(size_t)DIM*DIM, wq_b + 1*DIM,
                                              wk_w + 1*(size_t)DIM*DIM, wk_b + 1*DIM,
                                              wv_w + 1*(size_t)DIM*DIM, wv_b + 1*DIM,
                                              Q1, K1, V1, nullptr, nullptr, nullptr);
  // ---- layer 1 ----
  k_conv2d_mfma<<<dim3(3, 48, 8), 256, 0, stream>>>(INB, WTB + 1*(size_t)16*9*2*256*8, RAW, STATALL + 1*2*C2);
  k_bn2_norm_gate<1><<<dim3(NP, BB), NP, 0, stream>>>(RAW, STATALL + 1*2*C2, bn2_g + 1*C2, bn2_b + 1*C2,
                                                      wd_w + 1*(size_t)HH*C2, CL2, INB, TG1);
  k_attnx<0><<<dim3(NP, BB), NP, 0, stream>>>(Q1, K1, V1, TG1, wd_b + 1*HH, mask, X,
                                              wl_w + 1*(size_t)DIM*DIM, wl_b + 1*DIM,
                                              CL2, ln_g + 2*DIM, ln_b + 2*DIM,
                                              wq_w + 2*(size_t)DIM*DIM, wq_b + 2*DIM,
                                              wk_w + 2*(size_t)DIM*DIM, wk_b + 2*DIM,
                                              wv_w + 2*(size_t)DIM*DIM, wv_b + 2*DIM,
                                              Q0, K0, V0, nullptr, nullptr, nullptr);
  // ---- layer 2 ----
  k_conv2d_mfma<<<dim3(3, 48, 8), 256, 0, stream>>>(INB, WTB + 2*(size_t)16*9*2*256*8, RAW, STATALL + 2*2*C2);
  k_bn2_norm_gate<0><<<dim3(NP, BB), NP, 0, stream>>>(RAW, STATALL + 2*2*C2, bn2_g + 2*C2, bn2_b + 2*C2,
                                                      wd_w + 2*(size_t)HH*C2, nullptr, nullptr, TG0);
  k_attnx<1><<<dim3(NP, BB), NP, 0, stream>>>(Q0, K0, V0, TG0, wd_b + 2*HH, mask, X,
                                              wl_w + 2*(size_t)DIM*DIM, wl_b + 2*DIM,
                                              nullptr, nullptr, nullptr,
                                              nullptr, nullptr, nullptr, nullptr, nullptr, nullptr,
                                              nullptr, nullptr, nullptr,
                                              fc_w, fc_b, out);
}

// Round 7
// 699.903 us; speedup vs baseline: 1.7195x; 1.0442x over previous
//
#include <hip/hip_runtime.h>
#include <math.h>

#define IN_DIM 20
#define DIM 128
#define HH 8
#define LL 3
#define BB 2
#define NP 192
#define DHH 16
#define C2 256
#define NN (NP*NP)
#define EPS 1e-5f

// padded conv-input geometry
#define PR 200
#define PC 224

typedef __bf16 bf16x8 __attribute__((ext_vector_type(8)));
typedef float  f32x16 __attribute__((ext_vector_type(16)));

union Pack8 { __bf16 h[8]; uint4 u; };

#define GLOAD16(gp, lp) \
  __builtin_amdgcn_global_load_lds((const __attribute__((address_space(1))) uint4*)(gp), \
                                   (__attribute__((address_space(3))) uint4*)(lp), 16, 0, 0)

// ---------------- init: conv1d over seq for both x and c ----------------
__global__ void k_conv_init(const float* __restrict__ seq, const float* __restrict__ w1,
                            const float* __restrict__ w2, float* __restrict__ X,
                            float* __restrict__ Cc) {
  int t = blockIdx.x, b = blockIdx.y, oc = threadIdx.x;
  __shared__ float ss[3][IN_DIM];
  if (threadIdx.x < 3*IN_DIM) {
    int k = threadIdx.x / IN_DIM, ic = threadIdx.x % IN_DIM;
    int tt = t + k - 1;
    ss[k][ic] = (tt >= 0 && tt < NP) ? seq[(b*NP + tt)*IN_DIM + ic] : 0.f;
  }
  __syncthreads();
  float a1 = 0.f, a2 = 0.f;
  #pragma unroll
  for (int ic = 0; ic < IN_DIM; ic++) {
    #pragma unroll
    for (int k = 0; k < 3; k++) {
      float sv = ss[k][ic];
      a1 = fmaf(w1[(oc*IN_DIM + ic)*3 + k], sv, a1);
      a2 = fmaf(w2[(oc*IN_DIM + ic)*3 + k], sv, a2);
    }
  }
  X[(b*NP + t)*DIM + oc] = a1;
  Cc[(b*DIM + oc)*NP + t] = a2;
}

// ---------------- conv1d + BN(train stats) + relu, fused ----------------
__global__ void k_conv1d_bn_relu(const float* __restrict__ cin, const float* __restrict__ w,
                                 const float* __restrict__ g, const float* __restrict__ bb,
                                 float* __restrict__ cout) {
  int oc = blockIdx.x;
  int t = threadIdx.x;
  float raw[BB];
  for (int b = 0; b < BB; b++) {
    float acc = 0.f;
    for (int ic = 0; ic < DIM; ic++) {
      const float* cr = cin + (b*DIM + ic)*NP;
      const float* wr = w + (oc*DIM + ic)*3;
      float lf = (t > 0)      ? cr[t-1] : 0.f;
      float mf = cr[t];
      float rf = (t < NP-1)   ? cr[t+1] : 0.f;
      acc = fmaf(lf, wr[0], acc);
      acc = fmaf(mf, wr[1], acc);
      acc = fmaf(rf, wr[2], acc);
    }
    raw[b] = acc;
  }
  __shared__ float sb[NP];
  sb[t] = raw[0] + raw[1];
  __syncthreads();
  for (int s = 128; s > 0; s >>= 1) {
    if (t < s && t + s < NP) sb[t] += sb[t + s];
    __syncthreads();
  }
  float mean = sb[0] / (float)(BB*NP);
  __syncthreads();
  sb[t] = raw[0]*raw[0] + raw[1]*raw[1];
  __syncthreads();
  for (int s = 128; s > 0; s >>= 1) {
    if (t < s && t + s < NP) sb[t] += sb[t + s];
    __syncthreads();
  }
  float var = sb[0] / (float)(BB*NP) - mean*mean;
  float rstd = rsqrtf(var + EPS);
  float gg = g[oc], bo = bb[oc];
  for (int b = 0; b < BB; b++)
    cout[(b*DIM + oc)*NP + t] = fmaxf((raw[b] - mean)*rstd*gg + bo, 0.f);
}

// ---------------- layer-0 only: x = LN(x + c^T), q,k,v ----------------
__global__ void k_lnqkv(float* __restrict__ X, const float* __restrict__ cc,
                        const float* __restrict__ g, const float* __restrict__ bb,
                        const float* __restrict__ wq, const float* __restrict__ bq,
                        const float* __restrict__ wk, const float* __restrict__ bk,
                        const float* __restrict__ wv, const float* __restrict__ bv,
                        float* __restrict__ Q, float* __restrict__ K, float* __restrict__ V) {
  int t = blockIdx.x, b = blockIdx.y, d = threadIdx.x;
  __shared__ float sb[DIM];
  __shared__ float sy[DIM];
  float v = X[(b*NP + t)*DIM + d] + cc[(b*DIM + d)*NP + t];
  sb[d] = v; __syncthreads();
  for (int s = 64; s > 0; s >>= 1) { if (d < s) sb[d] += sb[d+s]; __syncthreads(); }
  float mean = sb[0] / (float)DIM;
  __syncthreads();
  float dv = v - mean;
  sb[d] = dv*dv; __syncthreads();
  for (int s = 64; s > 0; s >>= 1) { if (d < s) sb[d] += sb[d+s]; __syncthreads(); }
  float var = sb[0] / (float)DIM;
  float rstd = rsqrtf(var + EPS);
  float xn = dv * rstd * g[d] + bb[d];
  X[(b*NP + t)*DIM + d] = xn;
  sy[d] = xn;
  __syncthreads();
  float aq = bq[d], ak = bk[d], av = bv[d];
  for (int e = 0; e < DIM; e++) {
    float xv = sy[e];
    aq = fmaf(wq[d*DIM + e], xv, aq);
    ak = fmaf(wk[d*DIM + e], xv, ak);
    av = fmaf(wv[d*DIM + e], xv, av);
  }
  int h = d >> 4, dh = d & 15;
  size_t o = ((size_t)(b*HH + h)*NP + t)*DHH + dh;
  Q[o] = fmaxf(aq, 0.f); K[o] = fmaxf(ak, 0.f); V[o] = fmaxf(av, 0.f);
}

// ---------------- conv2d weight prep (coalesced reads via LDS) ----------------
// grid LL*C2 blocks = one (l, oc) row per block; 256 threads
__global__ void k_wprep(const float* __restrict__ w, __bf16* __restrict__ wtb) {
  int l = blockIdx.x / C2, oc = blockIdx.x % C2;
  int tid = threadIdx.x;
  __shared__ float swt[C2*9];   // 2304 floats = this oc's [ic][3][3]
  const float4* wsrc = (const float4*)(w + ((size_t)(l*C2 + oc))*C2*9);
  for (int idx = tid; idx < 576; idx += 256) ((float4*)swt)[idx] = wsrc[idx];
  __syncthreads();
  for (int v = tid; v < 288; v += 256) {
    int chunk = v / 18, rem = v % 18;
    int kk = rem >> 1, kh = rem & 1;
    Pack8 p;
    #pragma unroll
    for (int e = 0; e < 8; e++)
      p.h[e] = (__bf16)swt[(chunk*16 + kh*8 + e)*9 + kk];
    size_t unit = ((((size_t)(l*16 + chunk)*9 + kk)*2 + kh)*256 + oc);
    ((uint4*)wtb)[unit] = p.u;
  }
}

// ---------------- layer-0 conv input build (padded); zeroes 3x STAT2 ----------------
__global__ void k_make_convin(const float* __restrict__ Cc, const float* __restrict__ CL0,
                              __bf16* __restrict__ inb, float* __restrict__ STATALL) {
  int idx = blockIdx.x*256 + threadIdx.x;
  if (blockIdx.x == 0) {
    for (int z = threadIdx.x; z < 3*2*C2; z += 256) STATALL[z] = 0.f;
  }
  int kh = idx & 1;
  int t = idx >> 1;
  int gcol = t % PC; int t2 = t / PC;
  int grow = t2 % PR; int t3 = t2 / PR;
  int chunk = t3 & 15; int b = t3 >> 4;
  int i = grow - 1, j = gcol - 8;
  Pack8 p;
  if ((unsigned)i < 192u && (unsigned)j < 192u) {
    #pragma unroll
    for (int e = 0; e < 8; e++) {
      int c = chunk*16 + kh*8 + e;
      float v;
      if (c < DIM) v = Cc[(b*DIM + c)*NP + i] + CL0[(b*DIM + c)*NP + i];
      else { int cc = c - DIM; v = Cc[(b*DIM + cc)*NP + j] + CL0[(b*DIM + cc)*NP + j]; }
      p.h[e] = (__bf16)v;
    }
  } else {
    #pragma unroll
    for (int e = 0; e < 8; e++) p.h[e] = (__bf16)0.f;
  }
  ((uint4*)inb)[idx] = p.u;
}

// ---------------- heavy kernel: implicit-GEMM bf16 MFMA 3x3 conv, 3 blocks/CU ----------------
// grid (3 jt, 48 it, 16 = b*8+oct), block 256 (4 waves). Block tile: 32 oc x (4 rows x 64 cols).
// K: 16 chunks of 16 ic; per chunk stage W (576 u4 = 9KB) + I (1024 u4 = 16KB, 80-col padded
// window) via global_load_lds into a 2x1600-u4 LDS double buffer (50 KB total -> 3 blocks/CU).
__global__ __launch_bounds__(256, 3)
void k_conv2d_mfma(const __bf16* __restrict__ inb,   // padded [b][16][PR][PC][2][8]
                   const __bf16* __restrict__ wtb,   // [16][9][2][256][8] (layer slice)
                   __bf16* __restrict__ rawb,        // [b][32][192][192][8]
                   float* __restrict__ STAT2) {
  __shared__ __align__(16) uint4 sbuf[2*1600];       // 51200 B
  int tid = threadIdx.x;
  int jt = blockIdx.x, it = blockIdx.y, zz = blockIdx.z;
  int b = zz >> 3, oct = zz & 7;
  int i0 = it*4, j0 = jt*64, oc0 = oct*32;
  int lane = tid & 63, wv = tid >> 6;
  int wn = wv;                                       // output row i0+wn
  int ln31 = lane & 31, khl = lane >> 5;

  const uint4* gW = (const uint4*)wtb;
  const uint4* gI = (const uint4*)inb;

  f32x16 acc[2];
  #pragma unroll
  for (int n = 0; n < 2; n++)
    #pragma unroll
    for (int q = 0; q < 16; q++) acc[n][q] = 0.f;

  // precompute this wave's staging slots (7 per wave, last valid only for wave 0)
  const uint4* gp[7];
  int lofs[7];
  int gstride[7];
  bool gvalid[7];
  #pragma unroll
  for (int t = 0; t < 7; t++) {
    int L = t*4 + wv;                                // 0..27
    gvalid[t] = (L < 25);
    if (L < 9) {                                     // W: lds [kk*2+kh][oc32] = L*64+lane
      int kkh = L*2 + (lane >> 5);
      gp[t] = gW + (size_t)kkh*256 + oc0 + (lane & 31);
      lofs[t] = L*64 + lane;
      gstride[t] = 4608;
    } else {                                         // I: u in [0,1024), layout (r*2+kh)*80+c
      int u = (L - 9)*64 + lane;
      int r = u / 160;
      int kh = (u % 160) / 80;
      int c = u % 80;
      gp[t] = gI + ((size_t)(b*16)*PR + i0 + r)*PC*2 + (size_t)(j0 + c)*2 + kh;
      lofs[t] = 576 + u;
      gstride[t] = PR*PC*2;
    }
  }

  auto issue = [&](int buf) {
    uint4* lbase = sbuf + buf*1600;
    #pragma unroll
    for (int t = 0; t < 7; t++) {
      if (gvalid[t]) {
        GLOAD16(gp[t], lbase + lofs[t]);
        gp[t] += gstride[t];
      }
    }
  };

  issue(0);

  for (int chunk = 0; chunk < 16; ++chunk) {
    int buf = chunk & 1;
    __syncthreads();                   // staged data visible; prev buf's ds_reads done
    if (chunk < 15) issue(buf ^ 1);
    const __bf16* Wl = (const __bf16*)(sbuf + buf*1600);
    const __bf16* Il = (const __bf16*)(sbuf + buf*1600 + 576);
    #pragma unroll
    for (int kj = 0; kj < 3; kj++) {
      bf16x8 bfr[3][2];
      #pragma unroll
      for (int ki = 0; ki < 3; ki++) {
        int r = wn + ki;
        #pragma unroll
        for (int ch = 0; ch < 2; ch++) {
          int c = ch*32 + ln31 + kj + 7;
          bfr[ki][ch] = *(const bf16x8*)(Il + ((r*2 + khl)*80 + c)*8);
        }
      }
      #pragma unroll
      for (int ki = 0; ki < 3; ki++) {
        int kk = ki*3 + kj;
        bf16x8 a = *(const bf16x8*)(Wl + ((kk*2 + khl)*32 + ln31)*8);
        #pragma unroll
        for (int ch = 0; ch < 2; ch++)
          acc[ch] = __builtin_amdgcn_mfma_f32_32x32x16_bf16(a, bfr[ki][ch], acc[ch], 0, 0, 0);
      }
    }
  }

  __syncthreads();                     // all ds_reads done; overlay LDS for epilogue
  float* trAll = (float*)sbuf;
  float* tr = trAll + wv*(32*33);
  float* sstat = trAll + 4*32*33;      // 64 floats: [32 sum][32 sumsq]
  if (tid < 64) sstat[tid] = 0.f;
  __syncthreads();

  // fused BN2 partial stats
  #pragma unroll
  for (int reg = 0; reg < 16; reg++) {
    float v0 = acc[0][reg], v1 = acc[1][reg];
    float s = v0 + v1, s2 = v0*v0 + v1*v1;
    #pragma unroll
    for (int msk = 1; msk <= 16; msk <<= 1) { s += __shfl_xor(s, msk); s2 += __shfl_xor(s2, msk); }
    if (ln31 == 0) {
      int oc_l = (reg & 3) + 8*(reg >> 2) + 4*khl;
      atomicAdd(&sstat[oc_l], s);
      atomicAdd(&sstat[32 + oc_l], s2);
    }
  }

  // packed bf16 output via wave-local LDS transpose
  int i = i0 + wn;
  int Gb = oc0 >> 3;
  uint4* RAWu = (uint4*)rawb;
  #pragma unroll
  for (int ch = 0; ch < 2; ch++) {
    #pragma unroll
    for (int reg = 0; reg < 16; reg++) {
      int row = (reg & 3) + 8*(reg >> 2) + 4*khl;
      tr[row*33 + ln31] = acc[ch][reg];
    }
    __builtin_amdgcn_s_waitcnt(0);
    #pragma unroll
    for (int gs = 0; gs < 2; gs++) {
      int g = khl + gs*2;
      Pack8 p;
      #pragma unroll
      for (int e = 0; e < 8; e++) p.h[e] = (__bf16)tr[(g*8 + e)*33 + ln31];
      RAWu[((size_t)(b*32 + Gb + g)*192 + i)*192 + j0 + ch*32 + ln31] = p.u;
    }
    __builtin_amdgcn_s_waitcnt(0);
  }

  __syncthreads();
  if (tid < 32) {
    atomicAdd(&STAT2[oc0 + tid], sstat[tid]);
    atomicAdd(&STAT2[C2 + oc0 + tid], sstat[32 + tid]);
  }
}

// ---------------- fused: BN2 norm+relu, gate projection, next conv input (padded) ----------------
template<int WRITE_NEXT>
__global__ void k_bn2_norm_gate(const __bf16* __restrict__ rawb, const float* __restrict__ STAT2,
                                const float* __restrict__ g, const float* __restrict__ bb,
                                const float* __restrict__ wd, const float* __restrict__ CLn,
                                __bf16* __restrict__ inb_next, float* __restrict__ tg) {
  int i = blockIdx.x, b = blockIdx.y, j = threadIdx.x;
  __shared__ float sscale[C2], sshift[C2], swd[HH*C2];
  const float inv = 1.f / (float)(BB*NN);
  for (int c = j; c < C2; c += 192) {
    float mean = STAT2[c] * inv;
    float var  = STAT2[C2 + c] * inv - mean*mean;
    float rstd = rsqrtf(var + EPS);
    float sc = rstd * g[c];
    sscale[c] = sc;
    sshift[c] = bb[c] - mean*sc;
  }
  for (int idx = j; idx < HH*C2; idx += 192) swd[idx] = wd[idx];
  __syncthreads();
  float gacc[HH] = {};
  const uint4* RAWu = (const uint4*)rawb;
  for (int cu = 0; cu < 32; cu++) {
    Pack8 pr; pr.u = RAWu[((size_t)(b*32 + cu)*NP + i)*NP + j];
    Pack8 p;
    #pragma unroll
    for (int e = 0; e < 8; e++) {
      int c = cu*8 + e;
      float v = (float)pr.h[e];
      v = fmaxf(fmaf(v, sscale[c], sshift[c]), 0.f);
      if (WRITE_NEXT) {
        float nv = v + ((c < DIM) ? CLn[(b*DIM + c)*NP + i] : CLn[(b*DIM + c - DIM)*NP + j]);
        p.h[e] = (__bf16)nv;
      }
      #pragma unroll
      for (int h = 0; h < HH; h++) gacc[h] = fmaf(v, swd[h*C2 + c], gacc[h]);
    }
    if (WRITE_NEXT) {
      size_t unit = ((((size_t)(b*16 + (cu>>1))*PR + (i+1))*PC + (j+8))*2 + (cu&1));
      ((uint4*)inb_next)[unit] = p.u;
    }
  }
  for (int h = 0; h < HH; h++)
    tg[((size_t)(b*HH + h)*NP + i)*NP + j] = gacc[h];
}

// ---------------- MEGA-fused: attention(all heads) + xup + [next LN/QKV | final FC] ----------------
template<int MODE>
__global__ __launch_bounds__(192)
void k_attnx(const float* __restrict__ Q, const float* __restrict__ K,
             const float* __restrict__ V, const float* __restrict__ tg,
             const float* __restrict__ wdb, const float* __restrict__ mask,
             float* __restrict__ X,
             const float* __restrict__ wl, const float* __restrict__ bl,
             const float* __restrict__ ccn,
             const float* __restrict__ lng, const float* __restrict__ lnb,
             const float* __restrict__ wq, const float* __restrict__ bq,
             const float* __restrict__ wk, const float* __restrict__ bk,
             const float* __restrict__ wv, const float* __restrict__ bv,
             float* __restrict__ Qn, float* __restrict__ Kn, float* __restrict__ Vn,
             const float* __restrict__ fc, const float* __restrict__ fb,
             float* __restrict__ out) {
  int i = blockIdx.x, b = blockIdx.y, j = threadIdx.x;
  int lane = j & 63, wvv = j >> 6;
  __shared__ float sattn[HH][NP];
  __shared__ float supd[DIM];
  __shared__ float sy[DIM];
  __shared__ float sred[3];
  float mk = mask[b*NP + j];

  for (int h = 0; h < HH; h++) {
    size_t bh = (size_t)(b*HH + h);
    const float4* qr = (const float4*)(Q + (bh*NP + i)*DHH);
    const float4* kr = (const float4*)(K + (bh*NP + j)*DHH);
    float a = 0.f;
    #pragma unroll
    for (int q4 = 0; q4 < 4; q4++) {
      float4 qv = qr[q4], kv = kr[q4];
      a = fmaf(qv.x, kv.x, a); a = fmaf(qv.y, kv.y, a);
      a = fmaf(qv.z, kv.z, a); a = fmaf(qv.w, kv.w, a);
    }
    a *= 0.25f;
    float gv = tg[(bh*NP + i)*NP + j] + tg[(bh*NP + j)*NP + i] + wdb[h];
    float gate = 1.f / (1.f + expf(-gv));
    float m = a;
    #pragma unroll
    for (int s = 32; s > 0; s >>= 1) m = fmaxf(m, __shfl_xor(m, s));
    if (lane == 0) sred[wvv] = m;
    __syncthreads();
    float amax = fmaxf(fmaxf(sred[0], sred[1]), sred[2]);
    float e = expf(a - amax) * mk;
    float ss = e;
    #pragma unroll
    for (int s = 32; s > 0; s >>= 1) ss += __shfl_xor(ss, s);
    __syncthreads();
    if (lane == 0) sred[wvv] = ss;
    __syncthreads();
    float denom = sred[0] + sred[1] + sred[2] + 1e-6f;
    sattn[h][j] = (e / denom) * gate;
    __syncthreads();
  }

  if (j < DIM) {
    int h = j >> 4, d = j & 15;
    size_t bh = (size_t)(b*HH + h);
    float acc = 0.f;
    for (int jj = 0; jj < NP; jj++)
      acc = fmaf(sattn[h][jj], V[(bh*NP + jj)*DHH + d], acc);
    supd[h*DHH + d] = acc;
  }
  __syncthreads();

  size_t o = (size_t)(b*NP + i)*DIM;
  if (j < DIM) sy[j] = X[o + j] + supd[j];
  __syncthreads();
  float xr = 0.f;
  if (j < DIM) {
    float acc = bl[j];
    for (int e = 0; e < DIM; e++) acc = fmaf(wl[j*DIM + e], sy[e], acc);
    xr = fmaxf(acc, 0.f);
  }
  __syncthreads();

  if (MODE == 0) {
    float v = 0.f;
    if (j < DIM) v = xr + ccn[(b*DIM + j)*NP + i];
    float s = (j < DIM) ? v : 0.f;
    #pragma unroll
    for (int m = 32; m > 0; m >>= 1) s += __shfl_xor(s, m);
    if (lane == 0 && wvv < 2) sred[wvv] = s;
    __syncthreads();
    float mean = (sred[0] + sred[1]) * (1.f/128.f);
    float dv = v - mean;
    float q = (j < DIM) ? dv*dv : 0.f;
    #pragma unroll
    for (int m = 32; m > 0; m >>= 1) q += __shfl_xor(q, m);
    __syncthreads();
    if (lane == 0 && wvv < 2) sred[wvv] = q;
    __syncthreads();
    float var = (sred[0] + sred[1]) * (1.f/128.f);
    float rstd = rsqrtf(var + EPS);
    if (j < DIM) {
      float xn = dv * rstd * lng[j] + lnb[j];
      X[o + j] = xn;
      sy[j] = xn;
    }
    __syncthreads();
    if (j < DIM) {
      float aq = bq[j], ak = bk[j], av = bv[j];
      for (int e = 0; e < DIM; e++) {
        float xv = sy[e];
        aq = fmaf(wq[j*DIM + e], xv, aq);
        ak = fmaf(wk[j*DIM + e], xv, ak);
        av = fmaf(wv[j*DIM + e], xv, av);
      }
      int h = j >> 4, dh = j & 15;
      size_t oo = ((size_t)(b*HH + h)*NP + i)*DHH + dh;
      Qn[oo] = fmaxf(aq, 0.f); Kn[oo] = fmaxf(ak, 0.f); Vn[oo] = fmaxf(av, 0.f);
    }
  } else {
    if (j < DIM) sy[j] = xr;
    __syncthreads();
    if (j < DIM) {
      float acc = fb[j];
      for (int e = 0; e < DIM; e++) acc = fmaf(fc[j*DIM + e], sy[e], acc);
      out[o + j] = fmaxf(acc, 0.f);
    }
  }
}

extern "C" void kernel_launch(void* const* d_in, const int* in_sizes, int n_in,
                              void* d_out, int out_size, void* d_ws, size_t ws_size,
                              hipStream_t stream) {
  const float* seq     = (const float*)d_in[0];
  const float* mask    = (const float*)d_in[1];
  const float* conv1_w = (const float*)d_in[2];
  const float* conv2_w = (const float*)d_in[3];
  const float* ln_g    = (const float*)d_in[4];
  const float* ln_b    = (const float*)d_in[5];
  const float* c1d_w   = (const float*)d_in[6];
  const float* bn1_g   = (const float*)d_in[7];
  const float* bn1_b   = (const float*)d_in[8];
  const float* c2d_w   = (const float*)d_in[9];
  const float* bn2_g   = (const float*)d_in[10];
  const float* bn2_b   = (const float*)d_in[11];
  const float* wq_w    = (const float*)d_in[12];
  const float* wq_b    = (const float*)d_in[13];
  const float* wk_w    = (const float*)d_in[14];
  const float* wk_b    = (const float*)d_in[15];
  const float* wv_w    = (const float*)d_in[16];
  const float* wv_b    = (const float*)d_in[17];
  const float* wd_w    = (const float*)d_in[18];
  const float* wd_b    = (const float*)d_in[19];
  const float* wl_w    = (const float*)d_in[20];
  const float* wl_b    = (const float*)d_in[21];
  const float* fc_w    = (const float*)d_in[22];
  const float* fc_b    = (const float*)d_in[23];
  float* out = (float*)d_out;

  float* ws = (float*)d_ws;
  float* X    = ws; ws += BB*NP*DIM;
  float* Cc   = ws; ws += BB*DIM*NP;
  float* CL0  = ws; ws += BB*DIM*NP;
  float* CL1  = ws; ws += BB*DIM*NP;
  float* CL2  = ws; ws += BB*DIM*NP;
  float* Q0   = ws; ws += BB*NP*DIM;
  float* K0   = ws; ws += BB*NP*DIM;
  float* V0   = ws; ws += BB*NP*DIM;
  float* Q1   = ws; ws += BB*NP*DIM;
  float* K1   = ws; ws += BB*NP*DIM;
  float* V1   = ws; ws += BB*NP*DIM;
  float* TG0  = ws; ws += (size_t)BB*HH*NN;
  float* TG1  = ws; ws += (size_t)BB*HH*NN;
  float* STATALL = ws; ws += 3*2*C2;
  __bf16* RAW = (__bf16*)ws; ws += (size_t)BB*C2*NN/2;
  __bf16* INB = (__bf16*)ws; ws += (size_t)BB*16*PR*PC*2*16/4;
  __bf16* WTB = (__bf16*)ws; ws += (size_t)LL*C2*C2*9/2;

  k_wprep<<<LL*C2, 256, 0, stream>>>(c2d_w, WTB);
  k_conv_init<<<dim3(NP, BB), DIM, 0, stream>>>(seq, conv1_w, conv2_w, X, Cc);
  k_conv1d_bn_relu<<<DIM, NP, 0, stream>>>(Cc,  c1d_w + 0*(size_t)DIM*DIM*3, bn1_g + 0*DIM, bn1_b + 0*DIM, CL0);
  k_conv1d_bn_relu<<<DIM, NP, 0, stream>>>(CL0, c1d_w + 1*(size_t)DIM*DIM*3, bn1_g + 1*DIM, bn1_b + 1*DIM, CL1);
  k_conv1d_bn_relu<<<DIM, NP, 0, stream>>>(CL1, c1d_w + 2*(size_t)DIM*DIM*3, bn1_g + 2*DIM, bn1_b + 2*DIM, CL2);
  k_make_convin<<<(BB*16*PR*PC*2)/256, 256, 0, stream>>>(Cc, CL0, INB, STATALL);
  k_lnqkv<<<dim3(NP, BB), DIM, 0, stream>>>(X, CL0, ln_g, ln_b,
                                            wq_w, wq_b, wk_w, wk_b, wv_w, wv_b, Q0, K0, V0);

  // ---- layer 0 ----
  k_conv2d_mfma<<<dim3(3, 48, 16), 256, 0, stream>>>(INB, WTB + 0*(size_t)16*9*2*256*8, RAW, STATALL + 0*2*C2);
  k_bn2_norm_gate<1><<<dim3(NP, BB), NP, 0, stream>>>(RAW, STATALL + 0*2*C2, bn2_g + 0*C2, bn2_b + 0*C2,
                                                      wd_w + 0*(size_t)HH*C2, CL1, INB, TG0);
  k_attnx<0><<<dim3(NP, BB), NP, 0, stream>>>(Q0, K0, V0, TG0, wd_b + 0*HH, mask, X,
                                              wl_w + 0*(size_t)DIM*DIM, wl_b + 0*DIM,
                                              CL1, ln_g + 1*DIM, ln_b + 1*DIM,
                                              wq_w + 1*(size_t)DIM*DIM, wq_b + 1*DIM,
                                              wk_w + 1*(size_t)DIM*DIM, wk_b + 1*DIM,
                                              wv_w + 1*(size_t)DIM*DIM, wv_b + 1*DIM,
                                              Q1, K1, V1, nullptr, nullptr, nullptr);
  // ---- layer 1 ----
  k_conv2d_mfma<<<dim3(3, 48, 16), 256, 0, stream>>>(INB, WTB + 1*(size_t)16*9*2*256*8, RAW, STATALL + 1*2*C2);
  k_bn2_norm_gate<1><<<dim3(NP, BB), NP, 0, stream>>>(RAW, STATALL + 1*2*C2, bn2_g + 1*C2, bn2_b + 1*C2,
                                                      wd_w + 1*(size_t)HH*C2, CL2, INB, TG1);
  k_attnx<0><<<dim3(NP, BB), NP, 0, stream>>>(Q1, K1, V1, TG1, wd_b + 1*HH, mask, X,
                                              wl_w + 1*(size_t)DIM*DIM, wl_b + 1*DIM,
                                              CL2, ln_g + 2*DIM, ln_b + 2*DIM,
                                              wq_w + 2*(size_t)DIM*DIM, wq_b + 2*DIM,
                                              wk_w + 2*(size_t)DIM*DIM, wk_b + 2*DIM,
                                              wv_w + 2*(size_t)DIM*DIM, wv_b + 2*DIM,
                                              Q0, K0, V0, nullptr, nullptr, nullptr);
  // ---- layer 2 ----
  k_conv2d_mfma<<<dim3(3, 48, 16), 256, 0, stream>>>(INB, WTB + 2*(size_t)16*9*2*256*8, RAW, STATALL + 2*2*C2);
  k_bn2_norm_gate<0><<<dim3(NP, BB), NP, 0, stream>>>(RAW, STATALL + 2*2*C2, bn2_g + 2*C2, bn2_b + 2*C2,
                                                      wd_w + 2*(size_t)HH*C2, nullptr, nullptr, TG0);
  k_attnx<1><<<dim3(NP, BB), NP, 0, stream>>>(Q0, K0, V0, TG0, wd_b + 2*HH, mask, X,
                                              wl_w + 2*(size_t)DIM*DIM, wl_b + 2*DIM,
                                              nullptr, nullptr, nullptr,
                                              nullptr, nullptr, nullptr, nullptr, nullptr, nullptr,
                                              nullptr, nullptr, nullptr,
                                              fc_w, fc_b, out);
}

// Round 8
// 682.781 us; speedup vs baseline: 1.7626x; 1.0251x over previous
//
#include <hip/hip_runtime.h>
#include <math.h>

#define IN_DIM 20
#define DIM 128
#define HH 8
#define LL 3
#define BB 2
#define NP 192
#define DHH 16
#define C2 256
#define NN (NP*NP)
#define EPS 1e-5f

// padded conv-input geometry
#define PR 200
#define PC 224

typedef __bf16 bf16x8 __attribute__((ext_vector_type(8)));
typedef float  f32x16 __attribute__((ext_vector_type(16)));

union Pack8 { __bf16 h[8]; uint4 u; };

#define GLOAD16(gp, lp) \
  __builtin_amdgcn_global_load_lds((const __attribute__((address_space(1))) uint4*)(gp), \
                                   (__attribute__((address_space(3))) uint4*)(lp), 16, 0, 0)

// ---------------- init: conv1d over seq for both x and c ----------------
__global__ void k_conv_init(const float* __restrict__ seq, const float* __restrict__ w1,
                            const float* __restrict__ w2, float* __restrict__ X,
                            float* __restrict__ Cc) {
  int t = blockIdx.x, b = blockIdx.y, oc = threadIdx.x;
  __shared__ float ss[3][IN_DIM];
  if (threadIdx.x < 3*IN_DIM) {
    int k = threadIdx.x / IN_DIM, ic = threadIdx.x % IN_DIM;
    int tt = t + k - 1;
    ss[k][ic] = (tt >= 0 && tt < NP) ? seq[(b*NP + tt)*IN_DIM + ic] : 0.f;
  }
  __syncthreads();
  float a1 = 0.f, a2 = 0.f;
  #pragma unroll
  for (int ic = 0; ic < IN_DIM; ic++) {
    #pragma unroll
    for (int k = 0; k < 3; k++) {
      float sv = ss[k][ic];
      a1 = fmaf(w1[(oc*IN_DIM + ic)*3 + k], sv, a1);
      a2 = fmaf(w2[(oc*IN_DIM + ic)*3 + k], sv, a2);
    }
  }
  X[(b*NP + t)*DIM + oc] = a1;
  Cc[(b*DIM + oc)*NP + t] = a2;
}

// ---------------- conv1d + BN(train stats) + relu, fused ----------------
__global__ void k_conv1d_bn_relu(const float* __restrict__ cin, const float* __restrict__ w,
                                 const float* __restrict__ g, const float* __restrict__ bb,
                                 float* __restrict__ cout) {
  int oc = blockIdx.x;
  int t = threadIdx.x;
  float raw[BB];
  for (int b = 0; b < BB; b++) {
    float acc = 0.f;
    for (int ic = 0; ic < DIM; ic++) {
      const float* cr = cin + (b*DIM + ic)*NP;
      const float* wr = w + (oc*DIM + ic)*3;
      float lf = (t > 0)      ? cr[t-1] : 0.f;
      float mf = cr[t];
      float rf = (t < NP-1)   ? cr[t+1] : 0.f;
      acc = fmaf(lf, wr[0], acc);
      acc = fmaf(mf, wr[1], acc);
      acc = fmaf(rf, wr[2], acc);
    }
    raw[b] = acc;
  }
  __shared__ float sb[NP];
  sb[t] = raw[0] + raw[1];
  __syncthreads();
  for (int s = 128; s > 0; s >>= 1) {
    if (t < s && t + s < NP) sb[t] += sb[t + s];
    __syncthreads();
  }
  float mean = sb[0] / (float)(BB*NP);
  __syncthreads();
  sb[t] = raw[0]*raw[0] + raw[1]*raw[1];
  __syncthreads();
  for (int s = 128; s > 0; s >>= 1) {
    if (t < s && t + s < NP) sb[t] += sb[t + s];
    __syncthreads();
  }
  float var = sb[0] / (float)(BB*NP) - mean*mean;
  float rstd = rsqrtf(var + EPS);
  float gg = g[oc], bo = bb[oc];
  for (int b = 0; b < BB; b++)
    cout[(b*DIM + oc)*NP + t] = fmaxf((raw[b] - mean)*rstd*gg + bo, 0.f);
}

// ---------------- layer-0 only: x = LN(x + c^T), q,k,v ----------------
__global__ void k_lnqkv(float* __restrict__ X, const float* __restrict__ cc,
                        const float* __restrict__ g, const float* __restrict__ bb,
                        const float* __restrict__ wq, const float* __restrict__ bq,
                        const float* __restrict__ wk, const float* __restrict__ bk,
                        const float* __restrict__ wv, const float* __restrict__ bv,
                        float* __restrict__ Q, float* __restrict__ K, float* __restrict__ V) {
  int t = blockIdx.x, b = blockIdx.y, d = threadIdx.x;
  __shared__ float sb[DIM];
  __shared__ float sy[DIM];
  float v = X[(b*NP + t)*DIM + d] + cc[(b*DIM + d)*NP + t];
  sb[d] = v; __syncthreads();
  for (int s = 64; s > 0; s >>= 1) { if (d < s) sb[d] += sb[d+s]; __syncthreads(); }
  float mean = sb[0] / (float)DIM;
  __syncthreads();
  float dv = v - mean;
  sb[d] = dv*dv; __syncthreads();
  for (int s = 64; s > 0; s >>= 1) { if (d < s) sb[d] += sb[d+s]; __syncthreads(); }
  float var = sb[0] / (float)DIM;
  float rstd = rsqrtf(var + EPS);
  float xn = dv * rstd * g[d] + bb[d];
  X[(b*NP + t)*DIM + d] = xn;
  sy[d] = xn;
  __syncthreads();
  float aq = bq[d], ak = bk[d], av = bv[d];
  for (int e = 0; e < DIM; e++) {
    float xv = sy[e];
    aq = fmaf(wq[d*DIM + e], xv, aq);
    ak = fmaf(wk[d*DIM + e], xv, ak);
    av = fmaf(wv[d*DIM + e], xv, av);
  }
  int h = d >> 4, dh = d & 15;
  size_t o = ((size_t)(b*HH + h)*NP + t)*DHH + dh;
  Q[o] = fmaxf(aq, 0.f); K[o] = fmaxf(ak, 0.f); V[o] = fmaxf(av, 0.f);
}

// ---------------- conv2d weight prep (coalesced reads via LDS) ----------------
__global__ void k_wprep(const float* __restrict__ w, __bf16* __restrict__ wtb) {
  int l = blockIdx.x / C2, oc = blockIdx.x % C2;
  int tid = threadIdx.x;
  __shared__ float swt[C2*9];
  const float4* wsrc = (const float4*)(w + ((size_t)(l*C2 + oc))*C2*9);
  for (int idx = tid; idx < 576; idx += 256) ((float4*)swt)[idx] = wsrc[idx];
  __syncthreads();
  for (int v = tid; v < 288; v += 256) {
    int chunk = v / 18, rem = v % 18;
    int kk = rem >> 1, kh = rem & 1;
    Pack8 p;
    #pragma unroll
    for (int e = 0; e < 8; e++)
      p.h[e] = (__bf16)swt[(chunk*16 + kh*8 + e)*9 + kk];
    size_t unit = ((((size_t)(l*16 + chunk)*9 + kk)*2 + kh)*256 + oc);
    ((uint4*)wtb)[unit] = p.u;
  }
}

// ---------------- layer-0 conv input build (padded); zeroes 3x STAT2 ----------------
__global__ void k_make_convin(const float* __restrict__ Cc, const float* __restrict__ CL0,
                              __bf16* __restrict__ inb, float* __restrict__ STATALL) {
  int idx = blockIdx.x*256 + threadIdx.x;
  if (blockIdx.x == 0) {
    for (int z = threadIdx.x; z < 3*2*C2; z += 256) STATALL[z] = 0.f;
  }
  int kh = idx & 1;
  int t = idx >> 1;
  int gcol = t % PC; int t2 = t / PC;
  int grow = t2 % PR; int t3 = t2 / PR;
  int chunk = t3 & 15; int b = t3 >> 4;
  int i = grow - 1, j = gcol - 8;
  Pack8 p;
  if ((unsigned)i < 192u && (unsigned)j < 192u) {
    #pragma unroll
    for (int e = 0; e < 8; e++) {
      int c = chunk*16 + kh*8 + e;
      float v;
      if (c < DIM) v = Cc[(b*DIM + c)*NP + i] + CL0[(b*DIM + c)*NP + i];
      else { int cc = c - DIM; v = Cc[(b*DIM + cc)*NP + j] + CL0[(b*DIM + cc)*NP + j]; }
      p.h[e] = (__bf16)v;
    }
  } else {
    #pragma unroll
    for (int e = 0; e < 8; e++) p.h[e] = (__bf16)0.f;
  }
  ((uint4*)inb)[idx] = p.u;
}

// ---------------- heavy kernel: implicit-GEMM bf16 MFMA 3x3 conv ----------------
// grid (3 jt, 24 it, 16 = b*8+oct), block 256 (4 waves).
// Block tile: 32 oc x (8 rows x 64 cols); wave tile 32 oc x 2 rows x 64 cols.
// Reuse-optimized: per chunk per wave 33 ds_read_b128 for 36 MFMAs (0.92 reads/MFMA).
// Staging: W 576 u + I 1600 u (10 rows x 80 cols x 2kh) = 34.8 KB/buffer, dbuf -> 2 blocks/CU.
__global__ __launch_bounds__(256, 2)
void k_conv2d_mfma(const __bf16* __restrict__ inb,   // padded [b][16][PR][PC][2][8]
                   const __bf16* __restrict__ wtb,   // [16][9][2][256][8] (layer slice)
                   __bf16* __restrict__ rawb,        // [b][32][192][192][8]
                   float* __restrict__ STAT2) {
  __shared__ __align__(16) uint4 sbuf[2*2176];       // 69632 B
  int tid = threadIdx.x;
  int jt = blockIdx.x, it = blockIdx.y, zz = blockIdx.z;
  int b = zz >> 3, oct = zz & 7;
  int i0 = it*8, j0 = jt*64, oc0 = oct*32;
  int lane = tid & 63, wv = tid >> 6;
  int ln31 = lane & 31, khl = lane >> 5;

  const uint4* gW = (const uint4*)wtb;
  const uint4* gI = (const uint4*)inb;

  f32x16 acc[2][2];   // [row][ch]
  #pragma unroll
  for (int r = 0; r < 2; r++)
    #pragma unroll
    for (int n = 0; n < 2; n++)
      #pragma unroll
      for (int q = 0; q < 16; q++) acc[r][n][q] = 0.f;

  // staging: 34 wave-segments of 64 lanes; L = t*4 + wv (wave-uniform per slot).
  // L 0..8 = W (576 units exactly); L 9..33 = I (1600 units).
  const uint4* gp[9];
  int lofs[9];
  int gstride[9];
  bool gvalid[9];
  #pragma unroll
  for (int t = 0; t < 9; t++) {
    int L = t*4 + wv;
    gvalid[t] = (L < 34);
    if (L < 9) {                               // W segment
      int u = L*64 + lane;                     // 0..575
      int kkh = u >> 5;                        // 0..17
      int ocl = u & 31;
      gp[t] = gW + (size_t)kkh*256 + oc0 + ocl;
      lofs[t] = u;
      gstride[t] = 4608;
    } else {                                   // I segment
      int u = L*64 + lane - 576;               // 0..1599
      int r = u / 160;
      int rem = u % 160;
      int kh = rem / 80;
      int c = rem % 80;
      gp[t] = gI + (((size_t)(b*16)*PR) + i0 + r)*PC*2 + (size_t)(j0 + c)*2 + kh;
      lofs[t] = 576 + u;
      gstride[t] = PR*PC*2;
    }
  }

  auto issue = [&](int buf) {
    uint4* lbase = sbuf + buf*2176;
    #pragma unroll
    for (int t = 0; t < 9; t++) {
      if (gvalid[t]) {
        GLOAD16(gp[t], lbase + lofs[t]);
        gp[t] += gstride[t];
      }
    }
  };

  issue(0);

  for (int chunk = 0; chunk < 16; ++chunk) {
    int buf = chunk & 1;
    __syncthreads();                   // staged data visible; prev buf's ds_reads done
    if (chunk < 15) issue(buf ^ 1);
    const __bf16* Wl = (const __bf16*)(sbuf + buf*2176);
    const __bf16* Il = (const __bf16*)(sbuf + buf*2176 + 576);
    #pragma unroll
    for (int kj = 0; kj < 3; kj++) {
      // B fragments for input rows wv*2 + rr (rr=0..3), both col-halves
      bf16x8 bfr[4][2];
      #pragma unroll
      for (int rr = 0; rr < 4; rr++) {
        int r = wv*2 + rr;
        #pragma unroll
        for (int ch = 0; ch < 2; ch++) {
          int c = ch*32 + ln31 + kj + 7;
          bfr[rr][ch] = *(const bf16x8*)(Il + ((r*2 + khl)*80 + c)*8);
        }
      }
      #pragma unroll
      for (int ki = 0; ki < 3; ki++) {
        int kk = ki*3 + kj;
        bf16x8 a = *(const bf16x8*)(Wl + ((kk*2 + khl)*32 + ln31)*8);
        #pragma unroll
        for (int row = 0; row < 2; row++)
          #pragma unroll
          for (int ch = 0; ch < 2; ch++)
            acc[row][ch] = __builtin_amdgcn_mfma_f32_32x32x16_bf16(a, bfr[row + ki][ch], acc[row][ch], 0, 0, 0);
      }
    }
  }

  __syncthreads();                     // all ds_reads done; overlay LDS for epilogue
  float* trAll = (float*)sbuf;
  float* tr = trAll + wv*(32*33);
  float* sstat = trAll + 4*32*33;      // 64 floats: [32 sum][32 sumsq]
  if (tid < 64) sstat[tid] = 0.f;
  __syncthreads();

  // fused BN2 partial stats
  #pragma unroll
  for (int reg = 0; reg < 16; reg++) {
    float v00 = acc[0][0][reg], v01 = acc[0][1][reg];
    float v10 = acc[1][0][reg], v11 = acc[1][1][reg];
    float s = v00 + v01 + v10 + v11;
    float s2 = v00*v00 + v01*v01 + v10*v10 + v11*v11;
    #pragma unroll
    for (int msk = 1; msk <= 16; msk <<= 1) { s += __shfl_xor(s, msk); s2 += __shfl_xor(s2, msk); }
    if (ln31 == 0) {
      int oc_l = (reg & 3) + 8*(reg >> 2) + 4*khl;
      atomicAdd(&sstat[oc_l], s);
      atomicAdd(&sstat[32 + oc_l], s2);
    }
  }

  // packed bf16 output via wave-local LDS transpose
  int Gb = oc0 >> 3;
  uint4* RAWu = (uint4*)rawb;
  #pragma unroll
  for (int row = 0; row < 2; row++) {
    int i = i0 + wv*2 + row;
    #pragma unroll
    for (int ch = 0; ch < 2; ch++) {
      #pragma unroll
      for (int reg = 0; reg < 16; reg++) {
        int r = (reg & 3) + 8*(reg >> 2) + 4*khl;
        tr[r*33 + ln31] = acc[row][ch][reg];
      }
      __builtin_amdgcn_s_waitcnt(0);
      #pragma unroll
      for (int gs = 0; gs < 2; gs++) {
        int g = khl + gs*2;
        Pack8 p;
        #pragma unroll
        for (int e = 0; e < 8; e++) p.h[e] = (__bf16)tr[(g*8 + e)*33 + ln31];
        RAWu[((size_t)(b*32 + Gb + g)*192 + i)*192 + j0 + ch*32 + ln31] = p.u;
      }
      __builtin_amdgcn_s_waitcnt(0);
    }
  }

  __syncthreads();
  if (tid < 32) {
    atomicAdd(&STAT2[oc0 + tid], sstat[tid]);
    atomicAdd(&STAT2[C2 + oc0 + tid], sstat[32 + tid]);
  }
}

// ---------------- fused: BN2 norm+relu, gate projection, next conv input (padded) ----------------
template<int WRITE_NEXT>
__global__ void k_bn2_norm_gate(const __bf16* __restrict__ rawb, const float* __restrict__ STAT2,
                                const float* __restrict__ g, const float* __restrict__ bb,
                                const float* __restrict__ wd, const float* __restrict__ CLn,
                                __bf16* __restrict__ inb_next, float* __restrict__ tg) {
  int i = blockIdx.x, b = blockIdx.y, j = threadIdx.x;
  __shared__ float sscale[C2], sshift[C2], swd[HH*C2];
  const float inv = 1.f / (float)(BB*NN);
  for (int c = j; c < C2; c += 192) {
    float mean = STAT2[c] * inv;
    float var  = STAT2[C2 + c] * inv - mean*mean;
    float rstd = rsqrtf(var + EPS);
    float sc = rstd * g[c];
    sscale[c] = sc;
    sshift[c] = bb[c] - mean*sc;
  }
  for (int idx = j; idx < HH*C2; idx += 192) swd[idx] = wd[idx];
  __syncthreads();
  float gacc[HH] = {};
  const uint4* RAWu = (const uint4*)rawb;
  for (int cu = 0; cu < 32; cu++) {
    Pack8 pr; pr.u = RAWu[((size_t)(b*32 + cu)*NP + i)*NP + j];
    Pack8 p;
    #pragma unroll
    for (int e = 0; e < 8; e++) {
      int c = cu*8 + e;
      float v = (float)pr.h[e];
      v = fmaxf(fmaf(v, sscale[c], sshift[c]), 0.f);
      if (WRITE_NEXT) {
        float nv = v + ((c < DIM) ? CLn[(b*DIM + c)*NP + i] : CLn[(b*DIM + c - DIM)*NP + j]);
        p.h[e] = (__bf16)nv;
      }
      #pragma unroll
      for (int h = 0; h < HH; h++) gacc[h] = fmaf(v, swd[h*C2 + c], gacc[h]);
    }
    if (WRITE_NEXT) {
      size_t unit = ((((size_t)(b*16 + (cu>>1))*PR + (i+1))*PC + (j+8))*2 + (cu&1));
      ((uint4*)inb_next)[unit] = p.u;
    }
  }
  for (int h = 0; h < HH; h++)
    tg[((size_t)(b*HH + h)*NP + i)*NP + j] = gacc[h];
}

// ---------------- MEGA-fused: attention(all heads) + xup + [next LN/QKV | final FC] ----------------
template<int MODE>
__global__ __launch_bounds__(192)
void k_attnx(const float* __restrict__ Q, const float* __restrict__ K,
             const float* __restrict__ V, const float* __restrict__ tg,
             const float* __restrict__ wdb, const float* __restrict__ mask,
             float* __restrict__ X,
             const float* __restrict__ wl, const float* __restrict__ bl,
             const float* __restrict__ ccn,
             const float* __restrict__ lng, const float* __restrict__ lnb,
             const float* __restrict__ wq, const float* __restrict__ bq,
             const float* __restrict__ wk, const float* __restrict__ bk,
             const float* __restrict__ wv, const float* __restrict__ bv,
             float* __restrict__ Qn, float* __restrict__ Kn, float* __restrict__ Vn,
             const float* __restrict__ fc, const float* __restrict__ fb,
             float* __restrict__ out) {
  int i = blockIdx.x, b = blockIdx.y, j = threadIdx.x;
  int lane = j & 63, wvv = j >> 6;
  __shared__ float sattn[HH][NP];
  __shared__ float supd[DIM];
  __shared__ float sy[DIM];
  __shared__ float sred[3];
  float mk = mask[b*NP + j];

  for (int h = 0; h < HH; h++) {
    size_t bh = (size_t)(b*HH + h);
    const float4* qr = (const float4*)(Q + (bh*NP + i)*DHH);
    const float4* kr = (const float4*)(K + (bh*NP + j)*DHH);
    float a = 0.f;
    #pragma unroll
    for (int q4 = 0; q4 < 4; q4++) {
      float4 qv = qr[q4], kv = kr[q4];
      a = fmaf(qv.x, kv.x, a); a = fmaf(qv.y, kv.y, a);
      a = fmaf(qv.z, kv.z, a); a = fmaf(qv.w, kv.w, a);
    }
    a *= 0.25f;
    float gv = tg[(bh*NP + i)*NP + j] + tg[(bh*NP + j)*NP + i] + wdb[h];
    float gate = 1.f / (1.f + expf(-gv));
    float m = a;
    #pragma unroll
    for (int s = 32; s > 0; s >>= 1) m = fmaxf(m, __shfl_xor(m, s));
    if (lane == 0) sred[wvv] = m;
    __syncthreads();
    float amax = fmaxf(fmaxf(sred[0], sred[1]), sred[2]);
    float e = expf(a - amax) * mk;
    float ss = e;
    #pragma unroll
    for (int s = 32; s > 0; s >>= 1) ss += __shfl_xor(ss, s);
    __syncthreads();
    if (lane == 0) sred[wvv] = ss;
    __syncthreads();
    float denom = sred[0] + sred[1] + sred[2] + 1e-6f;
    sattn[h][j] = (e / denom) * gate;
    __syncthreads();
  }

  if (j < DIM) {
    int h = j >> 4, d = j & 15;
    size_t bh = (size_t)(b*HH + h);
    float acc = 0.f;
    for (int jj = 0; jj < NP; jj++)
      acc = fmaf(sattn[h][jj], V[(bh*NP + jj)*DHH + d], acc);
    supd[h*DHH + d] = acc;
  }
  __syncthreads();

  size_t o = (size_t)(b*NP + i)*DIM;
  if (j < DIM) sy[j] = X[o + j] + supd[j];
  __syncthreads();
  float xr = 0.f;
  if (j < DIM) {
    float acc = bl[j];
    for (int e = 0; e < DIM; e++) acc = fmaf(wl[j*DIM + e], sy[e], acc);
    xr = fmaxf(acc, 0.f);
  }
  __syncthreads();

  if (MODE == 0) {
    float v = 0.f;
    if (j < DIM) v = xr + ccn[(b*DIM + j)*NP + i];
    float s = (j < DIM) ? v : 0.f;
    #pragma unroll
    for (int m = 32; m > 0; m >>= 1) s += __shfl_xor(s, m);
    if (lane == 0 && wvv < 2) sred[wvv] = s;
    __syncthreads();
    float mean = (sred[0] + sred[1]) * (1.f/128.f);
    float dv = v - mean;
    float q = (j < DIM) ? dv*dv : 0.f;
    #pragma unroll
    for (int m = 32; m > 0; m >>= 1) q += __shfl_xor(q, m);
    __syncthreads();
    if (lane == 0 && wvv < 2) sred[wvv] = q;
    __syncthreads();
    float var = (sred[0] + sred[1]) * (1.f/128.f);
    float rstd = rsqrtf(var + EPS);
    if (j < DIM) {
      float xn = dv * rstd * lng[j] + lnb[j];
      X[o + j] = xn;
      sy[j] = xn;
    }
    __syncthreads();
    if (j < DIM) {
      float aq = bq[j], ak = bk[j], av = bv[j];
      for (int e = 0; e < DIM; e++) {
        float xv = sy[e];
        aq = fmaf(wq[j*DIM + e], xv, aq);
        ak = fmaf(wk[j*DIM + e], xv, ak);
        av = fmaf(wv[j*DIM + e], xv, av);
      }
      int h = j >> 4, dh = j & 15;
      size_t oo = ((size_t)(b*HH + h)*NP + i)*DHH + dh;
      Qn[oo] = fmaxf(aq, 0.f); Kn[oo] = fmaxf(ak, 0.f); Vn[oo] = fmaxf(av, 0.f);
    }
  } else {
    if (j < DIM) sy[j] = xr;
    __syncthreads();
    if (j < DIM) {
      float acc = fb[j];
      for (int e = 0; e < DIM; e++) acc = fmaf(fc[j*DIM + e], sy[e], acc);
      out[o + j] = fmaxf(acc, 0.f);
    }
  }
}

extern "C" void kernel_launch(void* const* d_in, const int* in_sizes, int n_in,
                              void* d_out, int out_size, void* d_ws, size_t ws_size,
                              hipStream_t stream) {
  const float* seq     = (const float*)d_in[0];
  const float* mask    = (const float*)d_in[1];
  const float* conv1_w = (const float*)d_in[2];
  const float* conv2_w = (const float*)d_in[3];
  const float* ln_g    = (const float*)d_in[4];
  const float* ln_b    = (const float*)d_in[5];
  const float* c1d_w   = (const float*)d_in[6];
  const float* bn1_g   = (const float*)d_in[7];
  const float* bn1_b   = (const float*)d_in[8];
  const float* c2d_w   = (const float*)d_in[9];
  const float* bn2_g   = (const float*)d_in[10];
  const float* bn2_b   = (const float*)d_in[11];
  const float* wq_w    = (const float*)d_in[12];
  const float* wq_b    = (const float*)d_in[13];
  const float* wk_w    = (const float*)d_in[14];
  const float* wk_b    = (const float*)d_in[15];
  const float* wv_w    = (const float*)d_in[16];
  const float* wv_b    = (const float*)d_in[17];
  const float* wd_w    = (const float*)d_in[18];
  const float* wd_b    = (const float*)d_in[19];
  const float* wl_w    = (const float*)d_in[20];
  const float* wl_b    = (const float*)d_in[21];
  const float* fc_w    = (const float*)d_in[22];
  const float* fc_b    = (const float*)d_in[23];
  float* out = (float*)d_out;

  float* ws = (float*)d_ws;
  float* X    = ws; ws += BB*NP*DIM;
  float* Cc   = ws; ws += BB*DIM*NP;
  float* CL0  = ws; ws += BB*DIM*NP;
  float* CL1  = ws; ws += BB*DIM*NP;
  float* CL2  = ws; ws += BB*DIM*NP;
  float* Q0   = ws; ws += BB*NP*DIM;
  float* K0   = ws; ws += BB*NP*DIM;
  float* V0   = ws; ws += BB*NP*DIM;
  float* Q1   = ws; ws += BB*NP*DIM;
  float* K1   = ws; ws += BB*NP*DIM;
  float* V1   = ws; ws += BB*NP*DIM;
  float* TG0  = ws; ws += (size_t)BB*HH*NN;
  float* TG1  = ws; ws += (size_t)BB*HH*NN;
  float* STATALL = ws; ws += 3*2*C2;
  __bf16* RAW = (__bf16*)ws; ws += (size_t)BB*C2*NN/2;
  __bf16* INB = (__bf16*)ws; ws += (size_t)BB*16*PR*PC*2*16/4;
  __bf16* WTB = (__bf16*)ws; ws += (size_t)LL*C2*C2*9/2;

  k_wprep<<<LL*C2, 256, 0, stream>>>(c2d_w, WTB);
  k_conv_init<<<dim3(NP, BB), DIM, 0, stream>>>(seq, conv1_w, conv2_w, X, Cc);
  k_conv1d_bn_relu<<<DIM, NP, 0, stream>>>(Cc,  c1d_w + 0*(size_t)DIM*DIM*3, bn1_g + 0*DIM, bn1_b + 0*DIM, CL0);
  k_conv1d_bn_relu<<<DIM, NP, 0, stream>>>(CL0, c1d_w + 1*(size_t)DIM*DIM*3, bn1_g + 1*DIM, bn1_b + 1*DIM, CL1);
  k_conv1d_bn_relu<<<DIM, NP, 0, stream>>>(CL1, c1d_w + 2*(size_t)DIM*DIM*3, bn1_g + 2*DIM, bn1_b + 2*DIM, CL2);
  k_make_convin<<<(BB*16*PR*PC*2)/256, 256, 0, stream>>>(Cc, CL0, INB, STATALL);
  k_lnqkv<<<dim3(NP, BB), DIM, 0, stream>>>(X, CL0, ln_g, ln_b,
                                            wq_w, wq_b, wk_w, wk_b, wv_w, wv_b, Q0, K0, V0);

  // ---- layer 0 ----
  k_conv2d_mfma<<<dim3(3, 24, 16), 256, 0, stream>>>(INB, WTB + 0*(size_t)16*9*2*256*8, RAW, STATALL + 0*2*C2);
  k_bn2_norm_gate<1><<<dim3(NP, BB), NP, 0, stream>>>(RAW, STATALL + 0*2*C2, bn2_g + 0*C2, bn2_b + 0*C2,
                                                      wd_w + 0*(size_t)HH*C2, CL1, INB, TG0);
  k_attnx<0><<<dim3(NP, BB), NP, 0, stream>>>(Q0, K0, V0, TG0, wd_b + 0*HH, mask, X,
                                              wl_w + 0*(size_t)DIM*DIM, wl_b + 0*DIM,
                                              CL1, ln_g + 1*DIM, ln_b + 1*DIM,
                                              wq_w + 1*(size_t)DIM*DIM, wq_b + 1*DIM,
                                              wk_w + 1*(size_t)DIM*DIM, wk_b + 1*DIM,
                                              wv_w + 1*(size_t)DIM*DIM, wv_b + 1*DIM,
                                              Q1, K1, V1, nullptr, nullptr, nullptr);
  // ---- layer 1 ----
  k_conv2d_mfma<<<dim3(3, 24, 16), 256, 0, stream>>>(INB, WTB + 1*(size_t)16*9*2*256*8, RAW, STATALL + 1*2*C2);
  k_bn2_norm_gate<1><<<dim3(NP, BB), NP, 0, stream>>>(RAW, STATALL + 1*2*C2, bn2_g + 1*C2, bn2_b + 1*C2,
                                                      wd_w + 1*(size_t)HH*C2, CL2, INB, TG1);
  k_attnx<0><<<dim3(NP, BB), NP, 0, stream>>>(Q1, K1, V1, TG1, wd_b + 1*HH, mask, X,
                                              wl_w + 1*(size_t)DIM*DIM, wl_b + 1*DIM,
                                              CL2, ln_g + 2*DIM, ln_b + 2*DIM,
                                              wq_w + 2*(size_t)DIM*DIM, wq_b + 2*DIM,
                                              wk_w + 2*(size_t)DIM*DIM, wk_b + 2*DIM,
                                              wv_w + 2*(size_t)DIM*DIM, wv_b + 2*DIM,
                                              Q0, K0, V0, nullptr, nullptr, nullptr);
  // ---- layer 2 ----
  k_conv2d_mfma<<<dim3(3, 24, 16), 256, 0, stream>>>(INB, WTB + 2*(size_t)16*9*2*256*8, RAW, STATALL + 2*2*C2);
  k_bn2_norm_gate<0><<<dim3(NP, BB), NP, 0, stream>>>(RAW, STATALL + 2*2*C2, bn2_g + 2*C2, bn2_b + 2*C2,
                                                      wd_w + 2*(size_t)HH*C2, nullptr, nullptr, TG0);
  k_attnx<1><<<dim3(NP, BB), NP, 0, stream>>>(Q0, K0, V0, TG0, wd_b + 2*HH, mask, X,
                                              wl_w + 2*(size_t)DIM*DIM, wl_b + 2*DIM,
                                              nullptr, nullptr, nullptr,
                                              nullptr, nullptr, nullptr, nullptr, nullptr, nullptr,
                                              nullptr, nullptr, nullptr,
                                              fc_w, fc_b, out);
}

// Round 9
// 680.109 us; speedup vs baseline: 1.7695x; 1.0039x over previous
//
#include <hip/hip_runtime.h>
#include <math.h>

#define IN_DIM 20
#define DIM 128
#define HH 8
#define LL 3
#define BB 2
#define NP 192
#define DHH 16
#define C2 256
#define NN (NP*NP)
#define EPS 1e-5f

// padded conv-input geometry
#define PR 200
#define PC 224

typedef __bf16 bf16x8 __attribute__((ext_vector_type(8)));
typedef float  f32x16 __attribute__((ext_vector_type(16)));

union Pack8 { __bf16 h[8]; uint4 u; };

#define GLOAD16(gp, lp) \
  __builtin_amdgcn_global_load_lds((const __attribute__((address_space(1))) uint4*)(gp), \
                                   (__attribute__((address_space(3))) uint4*)(lp), 16, 0, 0)

// ---------------- init: conv1d over seq for both x and c ----------------
__global__ void k_conv_init(const float* __restrict__ seq, const float* __restrict__ w1,
                            const float* __restrict__ w2, float* __restrict__ X,
                            float* __restrict__ Cc) {
  int t = blockIdx.x, b = blockIdx.y, oc = threadIdx.x;
  __shared__ float ss[3][IN_DIM];
  if (threadIdx.x < 3*IN_DIM) {
    int k = threadIdx.x / IN_DIM, ic = threadIdx.x % IN_DIM;
    int tt = t + k - 1;
    ss[k][ic] = (tt >= 0 && tt < NP) ? seq[(b*NP + tt)*IN_DIM + ic] : 0.f;
  }
  __syncthreads();
  float a1 = 0.f, a2 = 0.f;
  #pragma unroll
  for (int ic = 0; ic < IN_DIM; ic++) {
    #pragma unroll
    for (int k = 0; k < 3; k++) {
      float sv = ss[k][ic];
      a1 = fmaf(w1[(oc*IN_DIM + ic)*3 + k], sv, a1);
      a2 = fmaf(w2[(oc*IN_DIM + ic)*3 + k], sv, a2);
    }
  }
  X[(b*NP + t)*DIM + oc] = a1;
  Cc[(b*DIM + oc)*NP + t] = a2;
}

// ---------------- conv1d + BN(train stats) + relu, fused ----------------
__global__ void k_conv1d_bn_relu(const float* __restrict__ cin, const float* __restrict__ w,
                                 const float* __restrict__ g, const float* __restrict__ bb,
                                 float* __restrict__ cout) {
  int oc = blockIdx.x;
  int t = threadIdx.x;
  float raw[BB];
  for (int b = 0; b < BB; b++) {
    float acc = 0.f;
    for (int ic = 0; ic < DIM; ic++) {
      const float* cr = cin + (b*DIM + ic)*NP;
      const float* wr = w + (oc*DIM + ic)*3;
      float lf = (t > 0)      ? cr[t-1] : 0.f;
      float mf = cr[t];
      float rf = (t < NP-1)   ? cr[t+1] : 0.f;
      acc = fmaf(lf, wr[0], acc);
      acc = fmaf(mf, wr[1], acc);
      acc = fmaf(rf, wr[2], acc);
    }
    raw[b] = acc;
  }
  __shared__ float sb[NP];
  sb[t] = raw[0] + raw[1];
  __syncthreads();
  for (int s = 128; s > 0; s >>= 1) {
    if (t < s && t + s < NP) sb[t] += sb[t + s];
    __syncthreads();
  }
  float mean = sb[0] / (float)(BB*NP);
  __syncthreads();
  sb[t] = raw[0]*raw[0] + raw[1]*raw[1];
  __syncthreads();
  for (int s = 128; s > 0; s >>= 1) {
    if (t < s && t + s < NP) sb[t] += sb[t + s];
    __syncthreads();
  }
  float var = sb[0] / (float)(BB*NP) - mean*mean;
  float rstd = rsqrtf(var + EPS);
  float gg = g[oc], bo = bb[oc];
  for (int b = 0; b < BB; b++)
    cout[(b*DIM + oc)*NP + t] = fmaxf((raw[b] - mean)*rstd*gg + bo, 0.f);
}

// ---------------- small-weight transpose: wT[e][j] = w[j][e], 13 matrices ----------------
// grid (16 tiles, 13 matrices), 256 threads; 32x32 LDS tiles
__global__ void k_wtrans(const float* __restrict__ wq, const float* __restrict__ wk,
                         const float* __restrict__ wv, const float* __restrict__ wl,
                         const float* __restrict__ fcw,
                         float* __restrict__ wqt, float* __restrict__ wkt,
                         float* __restrict__ wvt, float* __restrict__ wlt,
                         float* __restrict__ fct) {
  int m = blockIdx.y;
  const float* src; float* dst;
  if (m < 3)       { src = wq + (size_t)m*DIM*DIM;     dst = wqt + (size_t)m*DIM*DIM; }
  else if (m < 6)  { src = wk + (size_t)(m-3)*DIM*DIM; dst = wkt + (size_t)(m-3)*DIM*DIM; }
  else if (m < 9)  { src = wv + (size_t)(m-6)*DIM*DIM; dst = wvt + (size_t)(m-6)*DIM*DIM; }
  else if (m < 12) { src = wl + (size_t)(m-9)*DIM*DIM; dst = wlt + (size_t)(m-9)*DIM*DIM; }
  else             { src = fcw;                        dst = fct; }
  int tile = blockIdx.x;
  int ti = tile >> 2, tj = tile & 3;
  int r = threadIdx.x >> 3, c4 = threadIdx.x & 7;
  __shared__ float t[32][33];
  float4 v = *(const float4*)(src + (ti*32 + r)*DIM + tj*32 + c4*4);
  t[r][c4*4+0] = v.x; t[r][c4*4+1] = v.y; t[r][c4*4+2] = v.z; t[r][c4*4+3] = v.w;
  __syncthreads();
  float4 o;
  o.x = t[c4*4+0][r]; o.y = t[c4*4+1][r]; o.z = t[c4*4+2][r]; o.w = t[c4*4+3][r];
  *(float4*)(dst + (tj*32 + r)*DIM + ti*32 + c4*4) = o;
}

// ---------------- layer-0 only: x = LN(x + c^T), q,k,v (transposed weights) ----------------
__global__ void k_lnqkv(float* __restrict__ X, const float* __restrict__ cc,
                        const float* __restrict__ g, const float* __restrict__ bb,
                        const float* __restrict__ wqt, const float* __restrict__ bq,
                        const float* __restrict__ wkt, const float* __restrict__ bk,
                        const float* __restrict__ wvt, const float* __restrict__ bv,
                        float* __restrict__ Q, float* __restrict__ K, float* __restrict__ V) {
  int t = blockIdx.x, b = blockIdx.y, d = threadIdx.x;
  __shared__ float sb[DIM];
  __shared__ float sy[DIM];
  float v = X[(b*NP + t)*DIM + d] + cc[(b*DIM + d)*NP + t];
  sb[d] = v; __syncthreads();
  for (int s = 64; s > 0; s >>= 1) { if (d < s) sb[d] += sb[d+s]; __syncthreads(); }
  float mean = sb[0] / (float)DIM;
  __syncthreads();
  float dv = v - mean;
  sb[d] = dv*dv; __syncthreads();
  for (int s = 64; s > 0; s >>= 1) { if (d < s) sb[d] += sb[d+s]; __syncthreads(); }
  float var = sb[0] / (float)DIM;
  float rstd = rsqrtf(var + EPS);
  float xn = dv * rstd * g[d] + bb[d];
  X[(b*NP + t)*DIM + d] = xn;
  sy[d] = xn;
  __syncthreads();
  float aq = bq[d], ak = bk[d], av = bv[d];
  for (int e = 0; e < DIM; e++) {
    float xv = sy[e];
    aq = fmaf(wqt[e*DIM + d], xv, aq);
    ak = fmaf(wkt[e*DIM + d], xv, ak);
    av = fmaf(wvt[e*DIM + d], xv, av);
  }
  int h = d >> 4, dh = d & 15;
  size_t o = ((size_t)(b*HH + h)*NP + t)*DHH + dh;
  Q[o] = fmaxf(aq, 0.f); K[o] = fmaxf(ak, 0.f); V[o] = fmaxf(av, 0.f);
}

// ---------------- conv2d weight prep (coalesced reads via LDS) ----------------
__global__ void k_wprep(const float* __restrict__ w, __bf16* __restrict__ wtb) {
  int l = blockIdx.x / C2, oc = blockIdx.x % C2;
  int tid = threadIdx.x;
  __shared__ float swt[C2*9];
  const float4* wsrc = (const float4*)(w + ((size_t)(l*C2 + oc))*C2*9);
  for (int idx = tid; idx < 576; idx += 256) ((float4*)swt)[idx] = wsrc[idx];
  __syncthreads();
  for (int v = tid; v < 288; v += 256) {
    int chunk = v / 18, rem = v % 18;
    int kk = rem >> 1, kh = rem & 1;
    Pack8 p;
    #pragma unroll
    for (int e = 0; e < 8; e++)
      p.h[e] = (__bf16)swt[(chunk*16 + kh*8 + e)*9 + kk];
    size_t unit = ((((size_t)(l*16 + chunk)*9 + kk)*2 + kh)*256 + oc);
    ((uint4*)wtb)[unit] = p.u;
  }
}

// ---------------- layer-0 conv input build (padded); zeroes 3x STAT2 ----------------
__global__ void k_make_convin(const float* __restrict__ Cc, const float* __restrict__ CL0,
                              __bf16* __restrict__ inb, float* __restrict__ STATALL) {
  int idx = blockIdx.x*256 + threadIdx.x;
  if (blockIdx.x == 0) {
    for (int z = threadIdx.x; z < 3*2*C2; z += 256) STATALL[z] = 0.f;
  }
  int kh = idx & 1;
  int t = idx >> 1;
  int gcol = t % PC; int t2 = t / PC;
  int grow = t2 % PR; int t3 = t2 / PR;
  int chunk = t3 & 15; int b = t3 >> 4;
  int i = grow - 1, j = gcol - 8;
  Pack8 p;
  if ((unsigned)i < 192u && (unsigned)j < 192u) {
    #pragma unroll
    for (int e = 0; e < 8; e++) {
      int c = chunk*16 + kh*8 + e;
      float v;
      if (c < DIM) v = Cc[(b*DIM + c)*NP + i] + CL0[(b*DIM + c)*NP + i];
      else { int cc = c - DIM; v = Cc[(b*DIM + cc)*NP + j] + CL0[(b*DIM + cc)*NP + j]; }
      p.h[e] = (__bf16)v;
    }
  } else {
    #pragma unroll
    for (int e = 0; e < 8; e++) p.h[e] = (__bf16)0.f;
  }
  ((uint4*)inb)[idx] = p.u;
}

// ---------------- heavy kernel: implicit-GEMM bf16 MFMA 3x3 conv (UNCHANGED from R8) ----------------
__global__ __launch_bounds__(256, 2)
void k_conv2d_mfma(const __bf16* __restrict__ inb,
                   const __bf16* __restrict__ wtb,
                   __bf16* __restrict__ rawb,
                   float* __restrict__ STAT2) {
  __shared__ __align__(16) uint4 sbuf[2*2176];
  int tid = threadIdx.x;
  int jt = blockIdx.x, it = blockIdx.y, zz = blockIdx.z;
  int b = zz >> 3, oct = zz & 7;
  int i0 = it*8, j0 = jt*64, oc0 = oct*32;
  int lane = tid & 63, wv = tid >> 6;
  int ln31 = lane & 31, khl = lane >> 5;

  const uint4* gW = (const uint4*)wtb;
  const uint4* gI = (const uint4*)inb;

  f32x16 acc[2][2];
  #pragma unroll
  for (int r = 0; r < 2; r++)
    #pragma unroll
    for (int n = 0; n < 2; n++)
      #pragma unroll
      for (int q = 0; q < 16; q++) acc[r][n][q] = 0.f;

  const uint4* gp[9];
  int lofs[9];
  int gstride[9];
  bool gvalid[9];
  #pragma unroll
  for (int t = 0; t < 9; t++) {
    int L = t*4 + wv;
    gvalid[t] = (L < 34);
    if (L < 9) {
      int u = L*64 + lane;
      int kkh = u >> 5;
      int ocl = u & 31;
      gp[t] = gW + (size_t)kkh*256 + oc0 + ocl;
      lofs[t] = u;
      gstride[t] = 4608;
    } else {
      int u = L*64 + lane - 576;
      int r = u / 160;
      int rem = u % 160;
      int kh = rem / 80;
      int c = rem % 80;
      gp[t] = gI + (((size_t)(b*16)*PR) + i0 + r)*PC*2 + (size_t)(j0 + c)*2 + kh;
      lofs[t] = 576 + u;
      gstride[t] = PR*PC*2;
    }
  }

  auto issue = [&](int buf) {
    uint4* lbase = sbuf + buf*2176;
    #pragma unroll
    for (int t = 0; t < 9; t++) {
      if (gvalid[t]) {
        GLOAD16(gp[t], lbase + lofs[t]);
        gp[t] += gstride[t];
      }
    }
  };

  issue(0);

  for (int chunk = 0; chunk < 16; ++chunk) {
    int buf = chunk & 1;
    __syncthreads();
    if (chunk < 15) issue(buf ^ 1);
    const __bf16* Wl = (const __bf16*)(sbuf + buf*2176);
    const __bf16* Il = (const __bf16*)(sbuf + buf*2176 + 576);
    #pragma unroll
    for (int kj = 0; kj < 3; kj++) {
      bf16x8 bfr[4][2];
      #pragma unroll
      for (int rr = 0; rr < 4; rr++) {
        int r = wv*2 + rr;
        #pragma unroll
        for (int ch = 0; ch < 2; ch++) {
          int c = ch*32 + ln31 + kj + 7;
          bfr[rr][ch] = *(const bf16x8*)(Il + ((r*2 + khl)*80 + c)*8);
        }
      }
      #pragma unroll
      for (int ki = 0; ki < 3; ki++) {
        int kk = ki*3 + kj;
        bf16x8 a = *(const bf16x8*)(Wl + ((kk*2 + khl)*32 + ln31)*8);
        #pragma unroll
        for (int row = 0; row < 2; row++)
          #pragma unroll
          for (int ch = 0; ch < 2; ch++)
            acc[row][ch] = __builtin_amdgcn_mfma_f32_32x32x16_bf16(a, bfr[row + ki][ch], acc[row][ch], 0, 0, 0);
      }
    }
  }

  __syncthreads();
  float* trAll = (float*)sbuf;
  float* tr = trAll + wv*(32*33);
  float* sstat = trAll + 4*32*33;
  if (tid < 64) sstat[tid] = 0.f;
  __syncthreads();

  #pragma unroll
  for (int reg = 0; reg < 16; reg++) {
    float v00 = acc[0][0][reg], v01 = acc[0][1][reg];
    float v10 = acc[1][0][reg], v11 = acc[1][1][reg];
    float s = v00 + v01 + v10 + v11;
    float s2 = v00*v00 + v01*v01 + v10*v10 + v11*v11;
    #pragma unroll
    for (int msk = 1; msk <= 16; msk <<= 1) { s += __shfl_xor(s, msk); s2 += __shfl_xor(s2, msk); }
    if (ln31 == 0) {
      int oc_l = (reg & 3) + 8*(reg >> 2) + 4*khl;
      atomicAdd(&sstat[oc_l], s);
      atomicAdd(&sstat[32 + oc_l], s2);
    }
  }

  int Gb = oc0 >> 3;
  uint4* RAWu = (uint4*)rawb;
  #pragma unroll
  for (int row = 0; row < 2; row++) {
    int i = i0 + wv*2 + row;
    #pragma unroll
    for (int ch = 0; ch < 2; ch++) {
      #pragma unroll
      for (int reg = 0; reg < 16; reg++) {
        int r = (reg & 3) + 8*(reg >> 2) + 4*khl;
        tr[r*33 + ln31] = acc[row][ch][reg];
      }
      __builtin_amdgcn_s_waitcnt(0);
      #pragma unroll
      for (int gs = 0; gs < 2; gs++) {
        int g = khl + gs*2;
        Pack8 p;
        #pragma unroll
        for (int e = 0; e < 8; e++) p.h[e] = (__bf16)tr[(g*8 + e)*33 + ln31];
        RAWu[((size_t)(b*32 + Gb + g)*192 + i)*192 + j0 + ch*32 + ln31] = p.u;
      }
      __builtin_amdgcn_s_waitcnt(0);
    }
  }

  __syncthreads();
  if (tid < 32) {
    atomicAdd(&STAT2[oc0 + tid], sstat[tid]);
    atomicAdd(&STAT2[C2 + oc0 + tid], sstat[32 + tid]);
  }
}

// ---------------- fused: BN2 norm+relu, gate projection, next conv input (padded) ----------------
template<int WRITE_NEXT>
__global__ void k_bn2_norm_gate(const __bf16* __restrict__ rawb, const float* __restrict__ STAT2,
                                const float* __restrict__ g, const float* __restrict__ bb,
                                const float* __restrict__ wd, const float* __restrict__ CLn,
                                __bf16* __restrict__ inb_next, float* __restrict__ tg) {
  int i = blockIdx.x, b = blockIdx.y, j = threadIdx.x;
  __shared__ float sscale[C2], sshift[C2], swd[HH*C2];
  const float inv = 1.f / (float)(BB*NN);
  for (int c = j; c < C2; c += 192) {
    float mean = STAT2[c] * inv;
    float var  = STAT2[C2 + c] * inv - mean*mean;
    float rstd = rsqrtf(var + EPS);
    float sc = rstd * g[c];
    sscale[c] = sc;
    sshift[c] = bb[c] - mean*sc;
  }
  for (int idx = j; idx < HH*C2; idx += 192) swd[idx] = wd[idx];
  __syncthreads();
  float gacc[HH] = {};
  const uint4* RAWu = (const uint4*)rawb;
  for (int cu = 0; cu < 32; cu++) {
    Pack8 pr; pr.u = RAWu[((size_t)(b*32 + cu)*NP + i)*NP + j];
    Pack8 p;
    #pragma unroll
    for (int e = 0; e < 8; e++) {
      int c = cu*8 + e;
      float v = (float)pr.h[e];
      v = fmaxf(fmaf(v, sscale[c], sshift[c]), 0.f);
      if (WRITE_NEXT) {
        float nv = v + ((c < DIM) ? CLn[(b*DIM + c)*NP + i] : CLn[(b*DIM + c - DIM)*NP + j]);
        p.h[e] = (__bf16)nv;
      }
      #pragma unroll
      for (int h = 0; h < HH; h++) gacc[h] = fmaf(v, swd[h*C2 + c], gacc[h]);
    }
    if (WRITE_NEXT) {
      size_t unit = ((((size_t)(b*16 + (cu>>1))*PR + (i+1))*PC + (j+8))*2 + (cu&1));
      ((uint4*)inb_next)[unit] = p.u;
    }
  }
  for (int h = 0; h < HH; h++)
    tg[((size_t)(b*HH + h)*NP + i)*NP + j] = gacc[h];
}

// ---------------- gate = sigmoid(t + t^T + bias), coalesced tiled transpose ----------------
// grid (36 = 6x6 tiles, 16 = b*8+h), 256 threads
__global__ void k_gate(const float* __restrict__ tg, const float* __restrict__ wdb,
                       float* __restrict__ gate) {
  int tile = blockIdx.x;
  int hb = blockIdx.y;
  int b = hb >> 3, h = hb & 7;
  size_t bh = (size_t)(b*HH + h);
  int ti = tile / 6, tj = tile % 6;
  int r = threadIdx.x >> 3, c4 = threadIdx.x & 7;
  __shared__ float tB[32][33];
  const float* base = tg + bh*NN;
  float4 vb = *(const float4*)(base + (tj*32 + r)*NP + ti*32 + c4*4);
  tB[r][c4*4+0] = vb.x; tB[r][c4*4+1] = vb.y; tB[r][c4*4+2] = vb.z; tB[r][c4*4+3] = vb.w;
  __syncthreads();
  float4 va = *(const float4*)(base + (ti*32 + r)*NP + tj*32 + c4*4);
  float bias = wdb[h];
  float4 o;
  o.x = 1.f / (1.f + expf(-(va.x + tB[c4*4+0][r] + bias)));
  o.y = 1.f / (1.f + expf(-(va.y + tB[c4*4+1][r] + bias)));
  o.z = 1.f / (1.f + expf(-(va.z + tB[c4*4+2][r] + bias)));
  o.w = 1.f / (1.f + expf(-(va.w + tB[c4*4+3][r] + bias)));
  *(float4*)(gate + bh*NN + (ti*32 + r)*NP + tj*32 + c4*4) = o;
}

// ---------------- MEGA-fused: attention(all heads) + xup + [next LN/QKV | final FC] ----------------
// All weight matvecs use TRANSPOSED weights (coalesced). Gate precomputed.
template<int MODE>
__global__ __launch_bounds__(192)
void k_attnx(const float* __restrict__ Q, const float* __restrict__ K,
             const float* __restrict__ V, const float* __restrict__ gate,
             const float* __restrict__ mask,
             float* __restrict__ X,
             const float* __restrict__ wlt, const float* __restrict__ bl,
             const float* __restrict__ ccn,
             const float* __restrict__ lng, const float* __restrict__ lnb,
             const float* __restrict__ wqt, const float* __restrict__ bq,
             const float* __restrict__ wkt, const float* __restrict__ bk,
             const float* __restrict__ wvt, const float* __restrict__ bv,
             float* __restrict__ Qn, float* __restrict__ Kn, float* __restrict__ Vn,
             const float* __restrict__ fct, const float* __restrict__ fb,
             float* __restrict__ out) {
  int i = blockIdx.x, b = blockIdx.y, j = threadIdx.x;
  int lane = j & 63, wvv = j >> 6;
  __shared__ float sq[DIM];
  __shared__ float sattn[HH][NP];
  __shared__ float supd[DIM];
  __shared__ float sy[DIM];
  __shared__ float sredm[HH][3];
  __shared__ float sreds[HH][3];
  __shared__ float sred[3];
  float mk = mask[b*NP + j];

  if (j < DIM) {
    int h = j >> 4, d = j & 15;
    sq[j] = Q[(((size_t)(b*HH + h))*NP + i)*DHH + d];
  }
  __syncthreads();

  float a[HH], gt[HH];
  #pragma unroll
  for (int h = 0; h < HH; h++) {
    size_t bh = (size_t)(b*HH + h);
    const float4* kr = (const float4*)(K + (bh*NP + j)*DHH);
    const float4* qr = (const float4*)(sq + h*DHH);
    float acc = 0.f;
    #pragma unroll
    for (int q4 = 0; q4 < 4; q4++) {
      float4 qv = qr[q4], kv = kr[q4];
      acc = fmaf(qv.x, kv.x, acc); acc = fmaf(qv.y, kv.y, acc);
      acc = fmaf(qv.z, kv.z, acc); acc = fmaf(qv.w, kv.w, acc);
    }
    a[h] = acc * 0.25f;
    gt[h] = gate[(bh*NP + i)*NP + j];
  }
  #pragma unroll
  for (int h = 0; h < HH; h++) {
    float m = a[h];
    #pragma unroll
    for (int s = 32; s > 0; s >>= 1) m = fmaxf(m, __shfl_xor(m, s));
    if (lane == 0) sredm[h][wvv] = m;
  }
  __syncthreads();
  float e[HH];
  #pragma unroll
  for (int h = 0; h < HH; h++) {
    float amax = fmaxf(fmaxf(sredm[h][0], sredm[h][1]), sredm[h][2]);
    e[h] = expf(a[h] - amax) * mk;
    float ss = e[h];
    #pragma unroll
    for (int s = 32; s > 0; s >>= 1) ss += __shfl_xor(ss, s);
    if (lane == 0) sreds[h][wvv] = ss;
  }
  __syncthreads();
  #pragma unroll
  for (int h = 0; h < HH; h++) {
    float denom = sreds[h][0] + sreds[h][1] + sreds[h][2] + 1e-6f;
    sattn[h][j] = (e[h] / denom) * gt[h];
  }
  __syncthreads();

  if (j < DIM) {
    int h = j >> 4, d = j & 15;
    size_t bh = (size_t)(b*HH + h);
    float acc = 0.f;
    for (int jj = 0; jj < NP; jj++)
      acc = fmaf(sattn[h][jj], V[(bh*NP + jj)*DHH + d], acc);
    supd[h*DHH + d] = acc;
  }
  __syncthreads();

  size_t o = (size_t)(b*NP + i)*DIM;
  if (j < DIM) sy[j] = X[o + j] + supd[j];
  __syncthreads();
  float xr = 0.f;
  if (j < DIM) {
    float acc = bl[j];
    for (int ee = 0; ee < DIM; ee++) acc = fmaf(wlt[ee*DIM + j], sy[ee], acc);
    xr = fmaxf(acc, 0.f);
  }
  __syncthreads();

  if (MODE == 0) {
    float v = 0.f;
    if (j < DIM) v = xr + ccn[(b*DIM + j)*NP + i];
    float s = (j < DIM) ? v : 0.f;
    #pragma unroll
    for (int m = 32; m > 0; m >>= 1) s += __shfl_xor(s, m);
    if (lane == 0 && wvv < 2) sred[wvv] = s;
    __syncthreads();
    float mean = (sred[0] + sred[1]) * (1.f/128.f);
    float dv = v - mean;
    float q = (j < DIM) ? dv*dv : 0.f;
    #pragma unroll
    for (int m = 32; m > 0; m >>= 1) q += __shfl_xor(q, m);
    __syncthreads();
    if (lane == 0 && wvv < 2) sred[wvv] = q;
    __syncthreads();
    float var = (sred[0] + sred[1]) * (1.f/128.f);
    float rstd = rsqrtf(var + EPS);
    if (j < DIM) {
      float xn = dv * rstd * lng[j] + lnb[j];
      X[o + j] = xn;
      sy[j] = xn;
    }
    __syncthreads();
    if (j < DIM) {
      float aq = bq[j], ak = bk[j], av = bv[j];
      for (int ee = 0; ee < DIM; ee++) {
        float xv = sy[ee];
        aq = fmaf(wqt[ee*DIM + j], xv, aq);
        ak = fmaf(wkt[ee*DIM + j], xv, ak);
        av = fmaf(wvt[ee*DIM + j], xv, av);
      }
      int h = j >> 4, dh = j & 15;
      size_t oo = ((size_t)(b*HH + h)*NP + i)*DHH + dh;
      Qn[oo] = fmaxf(aq, 0.f); Kn[oo] = fmaxf(ak, 0.f); Vn[oo] = fmaxf(av, 0.f);
    }
  } else {
    if (j < DIM) sy[j] = xr;
    __syncthreads();
    if (j < DIM) {
      float acc = fb[j];
      for (int ee = 0; ee < DIM; ee++) acc = fmaf(fct[ee*DIM + j], sy[ee], acc);
      out[o + j] = fmaxf(acc, 0.f);
    }
  }
}

extern "C" void kernel_launch(void* const* d_in, const int* in_sizes, int n_in,
                              void* d_out, int out_size, void* d_ws, size_t ws_size,
                              hipStream_t stream) {
  const float* seq     = (const float*)d_in[0];
  const float* mask    = (const float*)d_in[1];
  const float* conv1_w = (const float*)d_in[2];
  const float* conv2_w = (const float*)d_in[3];
  const float* ln_g    = (const float*)d_in[4];
  const float* ln_b    = (const float*)d_in[5];
  const float* c1d_w   = (const float*)d_in[6];
  const float* bn1_g   = (const float*)d_in[7];
  const float* bn1_b   = (const float*)d_in[8];
  const float* c2d_w   = (const float*)d_in[9];
  const float* bn2_g   = (const float*)d_in[10];
  const float* bn2_b   = (const float*)d_in[11];
  const float* wq_w    = (const float*)d_in[12];
  const float* wq_b    = (const float*)d_in[13];
  const float* wk_w    = (const float*)d_in[14];
  const float* wk_b    = (const float*)d_in[15];
  const float* wv_w    = (const float*)d_in[16];
  const float* wv_b    = (const float*)d_in[17];
  const float* wd_w    = (const float*)d_in[18];
  const float* wd_b    = (const float*)d_in[19];
  const float* wl_w    = (const float*)d_in[20];
  const float* wl_b    = (const float*)d_in[21];
  const float* fc_w    = (const float*)d_in[22];
  const float* fc_b    = (const float*)d_in[23];
  float* out = (float*)d_out;

  float* ws = (float*)d_ws;
  float* X    = ws; ws += BB*NP*DIM;
  float* Cc   = ws; ws += BB*DIM*NP;
  float* CL0  = ws; ws += BB*DIM*NP;
  float* CL1  = ws; ws += BB*DIM*NP;
  float* CL2  = ws; ws += BB*DIM*NP;
  float* Q0   = ws; ws += BB*NP*DIM;
  float* K0   = ws; ws += BB*NP*DIM;
  float* V0   = ws; ws += BB*NP*DIM;
  float* Q1   = ws; ws += BB*NP*DIM;
  float* K1   = ws; ws += BB*NP*DIM;
  float* V1   = ws; ws += BB*NP*DIM;
  float* TG   = ws; ws += (size_t)BB*HH*NN;
  float* GATE = ws; ws += (size_t)BB*HH*NN;
  float* WQT  = ws; ws += (size_t)LL*DIM*DIM;
  float* WKT  = ws; ws += (size_t)LL*DIM*DIM;
  float* WVT  = ws; ws += (size_t)LL*DIM*DIM;
  float* WLT  = ws; ws += (size_t)LL*DIM*DIM;
  float* FCT  = ws; ws += (size_t)DIM*DIM;
  float* STATALL = ws; ws += 3*2*C2;
  __bf16* RAW = (__bf16*)ws; ws += (size_t)BB*C2*NN/2;
  __bf16* INB = (__bf16*)ws; ws += (size_t)BB*16*PR*PC*2*16/4;
  __bf16* WTB = (__bf16*)ws; ws += (size_t)LL*C2*C2*9/2;

  k_wtrans<<<dim3(16, 13), 256, 0, stream>>>(wq_w, wk_w, wv_w, wl_w, fc_w,
                                             WQT, WKT, WVT, WLT, FCT);
  k_wprep<<<LL*C2, 256, 0, stream>>>(c2d_w, WTB);
  k_conv_init<<<dim3(NP, BB), DIM, 0, stream>>>(seq, conv1_w, conv2_w, X, Cc);
  k_conv1d_bn_relu<<<DIM, NP, 0, stream>>>(Cc,  c1d_w + 0*(size_t)DIM*DIM*3, bn1_g + 0*DIM, bn1_b + 0*DIM, CL0);
  k_conv1d_bn_relu<<<DIM, NP, 0, stream>>>(CL0, c1d_w + 1*(size_t)DIM*DIM*3, bn1_g + 1*DIM, bn1_b + 1*DIM, CL1);
  k_conv1d_bn_relu<<<DIM, NP, 0, stream>>>(CL1, c1d_w + 2*(size_t)DIM*DIM*3, bn1_g + 2*DIM, bn1_b + 2*DIM, CL2);
  k_make_convin<<<(BB*16*PR*PC*2)/256, 256, 0, stream>>>(Cc, CL0, INB, STATALL);
  k_lnqkv<<<dim3(NP, BB), DIM, 0, stream>>>(X, CL0, ln_g, ln_b,
                                            WQT, wq_b, WKT, wk_b, WVT, wv_b, Q0, K0, V0);

  // ---- layer 0 ----
  k_conv2d_mfma<<<dim3(3, 24, 16), 256, 0, stream>>>(INB, WTB + 0*(size_t)16*9*2*256*8, RAW, STATALL + 0*2*C2);
  k_bn2_norm_gate<1><<<dim3(NP, BB), NP, 0, stream>>>(RAW, STATALL + 0*2*C2, bn2_g + 0*C2, bn2_b + 0*C2,
                                                      wd_w + 0*(size_t)HH*C2, CL1, INB, TG);
  k_gate<<<dim3(36, 16), 256, 0, stream>>>(TG, wd_b + 0*HH, GATE);
  k_attnx<0><<<dim3(NP, BB), NP, 0, stream>>>(Q0, K0, V0, GATE, mask, X,
                                              WLT + 0*(size_t)DIM*DIM, wl_b + 0*DIM,
                                              CL1, ln_g + 1*DIM, ln_b + 1*DIM,
                                              WQT + 1*(size_t)DIM*DIM, wq_b + 1*DIM,
                                              WKT + 1*(size_t)DIM*DIM, wk_b + 1*DIM,
                                              WVT + 1*(size_t)DIM*DIM, wv_b + 1*DIM,
                                              Q1, K1, V1, nullptr, nullptr, nullptr);
  // ---- layer 1 ----
  k_conv2d_mfma<<<dim3(3, 24, 16), 256, 0, stream>>>(INB, WTB + 1*(size_t)16*9*2*256*8, RAW, STATALL + 1*2*C2);
  k_bn2_norm_gate<1><<<dim3(NP, BB), NP, 0, stream>>>(RAW, STATALL + 1*2*C2, bn2_g + 1*C2, bn2_b + 1*C2,
                                                      wd_w + 1*(size_t)HH*C2, CL2, INB, TG);
  k_gate<<<dim3(36, 16), 256, 0, stream>>>(TG, wd_b + 1*HH, GATE);
  k_attnx<0><<<dim3(NP, BB), NP, 0, stream>>>(Q1, K1, V1, GATE, mask, X,
                                              WLT + 1*(size_t)DIM*DIM, wl_b + 1*DIM,
                                              CL2, ln_g + 2*DIM, ln_b + 2*DIM,
                                              WQT + 2*(size_t)DIM*DIM, wq_b + 2*DIM,
                                              WKT + 2*(size_t)DIM*DIM, wk_b + 2*DIM,
                                              WVT + 2*(size_t)DIM*DIM, wv_b + 2*DIM,
                                              Q0, K0, V0, nullptr, nullptr, nullptr);
  // ---- layer 2 ----
  k_conv2d_mfma<<<dim3(3, 24, 16), 256, 0, stream>>>(INB, WTB + 2*(size_t)16*9*2*256*8, RAW, STATALL + 2*2*C2);
  k_bn2_norm_gate<0><<<dim3(NP, BB), NP, 0, stream>>>(RAW, STATALL + 2*2*C2, bn2_g + 2*C2, bn2_b + 2*C2,
                                                      wd_w + 2*(size_t)HH*C2, nullptr, nullptr, TG);
  k_gate<<<dim3(36, 16), 256, 0, stream>>>(TG, wd_b + 2*HH, GATE);
  k_attnx<1><<<dim3(NP, BB), NP, 0, stream>>>(Q0, K0, V0, GATE, mask, X,
                                              WLT + 2*(size_t)DIM*DIM, wl_b + 2*DIM,
                                              nullptr, nullptr, nullptr,
                                              nullptr, nullptr, nullptr, nullptr, nullptr, nullptr,
                                              nullptr, nullptr, nullptr,
                                              FCT, fc_b, out);
}

// Round 10
// 591.536 us; speedup vs baseline: 2.0345x; 1.1497x over previous
//
#include <hip/hip_runtime.h>
#include <math.h>

#define IN_DIM 20
#define DIM 128
#define HH 8
#define LL 3
#define BB 2
#define NP 192
#define DHH 16
#define C2 256
#define NN (NP*NP)
#define EPS 1e-5f

// padded conv-input geometry
#define PR 200
#define PC 224

typedef __bf16 bf16x8 __attribute__((ext_vector_type(8)));
typedef float  f32x16 __attribute__((ext_vector_type(16)));

union Pack8 { __bf16 h[8]; uint4 u; };

#define GLOAD16(gp, lp) \
  __builtin_amdgcn_global_load_lds((const __attribute__((address_space(1))) uint4*)(gp), \
                                   (__attribute__((address_space(3))) uint4*)(lp), 16, 0, 0)

// ---------------- init: conv1d over seq for both x and c ----------------
__global__ void k_conv_init(const float* __restrict__ seq, const float* __restrict__ w1,
                            const float* __restrict__ w2, float* __restrict__ X,
                            float* __restrict__ Cc) {
  int t = blockIdx.x, b = blockIdx.y, oc = threadIdx.x;
  __shared__ float ss[3][IN_DIM];
  if (threadIdx.x < 3*IN_DIM) {
    int k = threadIdx.x / IN_DIM, ic = threadIdx.x % IN_DIM;
    int tt = t + k - 1;
    ss[k][ic] = (tt >= 0 && tt < NP) ? seq[(b*NP + tt)*IN_DIM + ic] : 0.f;
  }
  __syncthreads();
  float a1 = 0.f, a2 = 0.f;
  #pragma unroll
  for (int ic = 0; ic < IN_DIM; ic++) {
    #pragma unroll
    for (int k = 0; k < 3; k++) {
      float sv = ss[k][ic];
      a1 = fmaf(w1[(oc*IN_DIM + ic)*3 + k], sv, a1);
      a2 = fmaf(w2[(oc*IN_DIM + ic)*3 + k], sv, a2);
    }
  }
  X[(b*NP + t)*DIM + oc] = a1;
  Cc[(b*DIM + oc)*NP + t] = a2;
}

// ---------------- conv1d + BN(train stats) + relu: WIDE (768 thr, 64-iter chain) ----------------
// threads: t (192) x sub(4) where sub = ih*2 + b... mapping: b = sub&1, ih = sub>>1
__global__ __launch_bounds__(768)
void k_conv1d_bn_relu(const float* __restrict__ cin, const float* __restrict__ w,
                      const float* __restrict__ g, const float* __restrict__ bb,
                      float* __restrict__ cout) {
  int oc = blockIdx.x;
  int tid = threadIdx.x;
  int t = tid % NP;
  int sub = tid / NP;            // 0..3
  int b = sub & 1, ih = sub >> 1;
  float acc = 0.f;
  for (int ic = ih*64; ic < ih*64 + 64; ic++) {
    const float* cr = cin + (b*DIM + ic)*NP;
    const float* wr = w + (oc*DIM + ic)*3;
    float lf = (t > 0)      ? cr[t-1] : 0.f;
    float mf = cr[t];
    float rf = (t < NP-1)   ? cr[t+1] : 0.f;
    acc = fmaf(lf, wr[0], acc);
    acc = fmaf(mf, wr[1], acc);
    acc = fmaf(rf, wr[2], acc);
  }
  __shared__ float sp[4][NP];
  __shared__ float sb[768];
  sp[sub][t] = acc;
  __syncthreads();
  float raw = sp[b][t] + sp[2 + b][t];     // subs 0,1 distinct (b=0,1); 2,3 duplicates
  sb[tid] = (sub < 2) ? raw : raw * raw;   // [0,384)=sums, [384,768)=squares
  __syncthreads();
  for (int s = 192; s >= 3; s >>= 1) {     // 192,96,48,24,12,6,3 -> 3 elems left each half
    if (tid < s) sb[tid] += sb[tid + s];
    int u = tid - 384;
    if (u >= 0 && u < s) sb[tid] += sb[tid + s];
    __syncthreads();
  }
  float mean = (sb[0] + sb[1] + sb[2]) / 384.f;
  float var  = (sb[384] + sb[385] + sb[386]) / 384.f - mean*mean;
  float rstd = rsqrtf(var + EPS);
  if (sub < 2)
    cout[(b*DIM + oc)*NP + t] = fmaxf((raw - mean)*rstd*g[oc] + bb[oc], 0.f);
}

// ---------------- small-weight transpose: wT[e][j] = w[j][e], 13 matrices ----------------
__global__ void k_wtrans(const float* __restrict__ wq, const float* __restrict__ wk,
                         const float* __restrict__ wv, const float* __restrict__ wl,
                         const float* __restrict__ fcw,
                         float* __restrict__ wqt, float* __restrict__ wkt,
                         float* __restrict__ wvt, float* __restrict__ wlt,
                         float* __restrict__ fct) {
  int m = blockIdx.y;
  const float* src; float* dst;
  if (m < 3)       { src = wq + (size_t)m*DIM*DIM;     dst = wqt + (size_t)m*DIM*DIM; }
  else if (m < 6)  { src = wk + (size_t)(m-3)*DIM*DIM; dst = wkt + (size_t)(m-3)*DIM*DIM; }
  else if (m < 9)  { src = wv + (size_t)(m-6)*DIM*DIM; dst = wvt + (size_t)(m-6)*DIM*DIM; }
  else if (m < 12) { src = wl + (size_t)(m-9)*DIM*DIM; dst = wlt + (size_t)(m-9)*DIM*DIM; }
  else             { src = fcw;                        dst = fct; }
  int tile = blockIdx.x;
  int ti = tile >> 2, tj = tile & 3;
  int r = threadIdx.x >> 3, c4 = threadIdx.x & 7;
  __shared__ float t[32][33];
  float4 v = *(const float4*)(src + (ti*32 + r)*DIM + tj*32 + c4*4);
  t[r][c4*4+0] = v.x; t[r][c4*4+1] = v.y; t[r][c4*4+2] = v.z; t[r][c4*4+3] = v.w;
  __syncthreads();
  float4 o;
  o.x = t[c4*4+0][r]; o.y = t[c4*4+1][r]; o.z = t[c4*4+2][r]; o.w = t[c4*4+3][r];
  *(float4*)(dst + (tj*32 + r)*DIM + ti*32 + c4*4) = o;
}

// ---------------- layer-0 only: x = LN(x + c^T), q,k,v (transposed weights) ----------------
__global__ void k_lnqkv(float* __restrict__ X, const float* __restrict__ cc,
                        const float* __restrict__ g, const float* __restrict__ bb,
                        const float* __restrict__ wqt, const float* __restrict__ bq,
                        const float* __restrict__ wkt, const float* __restrict__ bk,
                        const float* __restrict__ wvt, const float* __restrict__ bv,
                        float* __restrict__ Q, float* __restrict__ K, float* __restrict__ V) {
  int t = blockIdx.x, b = blockIdx.y, d = threadIdx.x;
  __shared__ float sb[DIM];
  __shared__ float sy[DIM];
  float v = X[(b*NP + t)*DIM + d] + cc[(b*DIM + d)*NP + t];
  sb[d] = v; __syncthreads();
  for (int s = 64; s > 0; s >>= 1) { if (d < s) sb[d] += sb[d+s]; __syncthreads(); }
  float mean = sb[0] / (float)DIM;
  __syncthreads();
  float dv = v - mean;
  sb[d] = dv*dv; __syncthreads();
  for (int s = 64; s > 0; s >>= 1) { if (d < s) sb[d] += sb[d+s]; __syncthreads(); }
  float var = sb[0] / (float)DIM;
  float rstd = rsqrtf(var + EPS);
  float xn = dv * rstd * g[d] + bb[d];
  X[(b*NP + t)*DIM + d] = xn;
  sy[d] = xn;
  __syncthreads();
  float aq = bq[d], ak = bk[d], av = bv[d];
  for (int e = 0; e < DIM; e++) {
    float xv = sy[e];
    aq = fmaf(wqt[e*DIM + d], xv, aq);
    ak = fmaf(wkt[e*DIM + d], xv, ak);
    av = fmaf(wvt[e*DIM + d], xv, av);
  }
  int h = d >> 4, dh = d & 15;
  size_t o = ((size_t)(b*HH + h)*NP + t)*DHH + dh;
  Q[o] = fmaxf(aq, 0.f); K[o] = fmaxf(ak, 0.f); V[o] = fmaxf(av, 0.f);
}

// ---------------- conv2d weight prep (coalesced reads via LDS) ----------------
__global__ void k_wprep(const float* __restrict__ w, __bf16* __restrict__ wtb) {
  int l = blockIdx.x / C2, oc = blockIdx.x % C2;
  int tid = threadIdx.x;
  __shared__ float swt[C2*9];
  const float4* wsrc = (const float4*)(w + ((size_t)(l*C2 + oc))*C2*9);
  for (int idx = tid; idx < 576; idx += 256) ((float4*)swt)[idx] = wsrc[idx];
  __syncthreads();
  for (int v = tid; v < 288; v += 256) {
    int chunk = v / 18, rem = v % 18;
    int kk = rem >> 1, kh = rem & 1;
    Pack8 p;
    #pragma unroll
    for (int e = 0; e < 8; e++)
      p.h[e] = (__bf16)swt[(chunk*16 + kh*8 + e)*9 + kk];
    size_t unit = ((((size_t)(l*16 + chunk)*9 + kk)*2 + kh)*256 + oc);
    ((uint4*)wtb)[unit] = p.u;
  }
}

// ---------------- layer-0 conv input build (padded); zeroes 3x STAT2 ----------------
__global__ void k_make_convin(const float* __restrict__ Cc, const float* __restrict__ CL0,
                              __bf16* __restrict__ inb, float* __restrict__ STATALL) {
  int idx = blockIdx.x*256 + threadIdx.x;
  if (blockIdx.x == 0) {
    for (int z = threadIdx.x; z < 3*2*C2; z += 256) STATALL[z] = 0.f;
  }
  int kh = idx & 1;
  int t = idx >> 1;
  int gcol = t % PC; int t2 = t / PC;
  int grow = t2 % PR; int t3 = t2 / PR;
  int chunk = t3 & 15; int b = t3 >> 4;
  int i = grow - 1, j = gcol - 8;
  Pack8 p;
  if ((unsigned)i < 192u && (unsigned)j < 192u) {
    #pragma unroll
    for (int e = 0; e < 8; e++) {
      int c = chunk*16 + kh*8 + e;
      float v;
      if (c < DIM) v = Cc[(b*DIM + c)*NP + i] + CL0[(b*DIM + c)*NP + i];
      else { int cc = c - DIM; v = Cc[(b*DIM + cc)*NP + j] + CL0[(b*DIM + cc)*NP + j]; }
      p.h[e] = (__bf16)v;
    }
  } else {
    #pragma unroll
    for (int e = 0; e < 8; e++) p.h[e] = (__bf16)0.f;
  }
  ((uint4*)inb)[idx] = p.u;
}

// ---------------- heavy kernel: implicit-GEMM bf16 MFMA 3x3 conv (UNCHANGED from R8) ----------------
__global__ __launch_bounds__(256, 2)
void k_conv2d_mfma(const __bf16* __restrict__ inb,
                   const __bf16* __restrict__ wtb,
                   __bf16* __restrict__ rawb,
                   float* __restrict__ STAT2) {
  __shared__ __align__(16) uint4 sbuf[2*2176];
  int tid = threadIdx.x;
  int jt = blockIdx.x, it = blockIdx.y, zz = blockIdx.z;
  int b = zz >> 3, oct = zz & 7;
  int i0 = it*8, j0 = jt*64, oc0 = oct*32;
  int lane = tid & 63, wv = tid >> 6;
  int ln31 = lane & 31, khl = lane >> 5;

  const uint4* gW = (const uint4*)wtb;
  const uint4* gI = (const uint4*)inb;

  f32x16 acc[2][2];
  #pragma unroll
  for (int r = 0; r < 2; r++)
    #pragma unroll
    for (int n = 0; n < 2; n++)
      #pragma unroll
      for (int q = 0; q < 16; q++) acc[r][n][q] = 0.f;

  const uint4* gp[9];
  int lofs[9];
  int gstride[9];
  bool gvalid[9];
  #pragma unroll
  for (int t = 0; t < 9; t++) {
    int L = t*4 + wv;
    gvalid[t] = (L < 34);
    if (L < 9) {
      int u = L*64 + lane;
      int kkh = u >> 5;
      int ocl = u & 31;
      gp[t] = gW + (size_t)kkh*256 + oc0 + ocl;
      lofs[t] = u;
      gstride[t] = 4608;
    } else {
      int u = L*64 + lane - 576;
      int r = u / 160;
      int rem = u % 160;
      int kh = rem / 80;
      int c = rem % 80;
      gp[t] = gI + (((size_t)(b*16)*PR) + i0 + r)*PC*2 + (size_t)(j0 + c)*2 + kh;
      lofs[t] = 576 + u;
      gstride[t] = PR*PC*2;
    }
  }

  auto issue = [&](int buf) {
    uint4* lbase = sbuf + buf*2176;
    #pragma unroll
    for (int t = 0; t < 9; t++) {
      if (gvalid[t]) {
        GLOAD16(gp[t], lbase + lofs[t]);
        gp[t] += gstride[t];
      }
    }
  };

  issue(0);

  for (int chunk = 0; chunk < 16; ++chunk) {
    int buf = chunk & 1;
    __syncthreads();
    if (chunk < 15) issue(buf ^ 1);
    const __bf16* Wl = (const __bf16*)(sbuf + buf*2176);
    const __bf16* Il = (const __bf16*)(sbuf + buf*2176 + 576);
    #pragma unroll
    for (int kj = 0; kj < 3; kj++) {
      bf16x8 bfr[4][2];
      #pragma unroll
      for (int rr = 0; rr < 4; rr++) {
        int r = wv*2 + rr;
        #pragma unroll
        for (int ch = 0; ch < 2; ch++) {
          int c = ch*32 + ln31 + kj + 7;
          bfr[rr][ch] = *(const bf16x8*)(Il + ((r*2 + khl)*80 + c)*8);
        }
      }
      #pragma unroll
      for (int ki = 0; ki < 3; ki++) {
        int kk = ki*3 + kj;
        bf16x8 a = *(const bf16x8*)(Wl + ((kk*2 + khl)*32 + ln31)*8);
        #pragma unroll
        for (int row = 0; row < 2; row++)
          #pragma unroll
          for (int ch = 0; ch < 2; ch++)
            acc[row][ch] = __builtin_amdgcn_mfma_f32_32x32x16_bf16(a, bfr[row + ki][ch], acc[row][ch], 0, 0, 0);
      }
    }
  }

  __syncthreads();
  float* trAll = (float*)sbuf;
  float* tr = trAll + wv*(32*33);
  float* sstat = trAll + 4*32*33;
  if (tid < 64) sstat[tid] = 0.f;
  __syncthreads();

  #pragma unroll
  for (int reg = 0; reg < 16; reg++) {
    float v00 = acc[0][0][reg], v01 = acc[0][1][reg];
    float v10 = acc[1][0][reg], v11 = acc[1][1][reg];
    float s = v00 + v01 + v10 + v11;
    float s2 = v00*v00 + v01*v01 + v10*v10 + v11*v11;
    #pragma unroll
    for (int msk = 1; msk <= 16; msk <<= 1) { s += __shfl_xor(s, msk); s2 += __shfl_xor(s2, msk); }
    if (ln31 == 0) {
      int oc_l = (reg & 3) + 8*(reg >> 2) + 4*khl;
      atomicAdd(&sstat[oc_l], s);
      atomicAdd(&sstat[32 + oc_l], s2);
    }
  }

  int Gb = oc0 >> 3;
  uint4* RAWu = (uint4*)rawb;
  #pragma unroll
  for (int row = 0; row < 2; row++) {
    int i = i0 + wv*2 + row;
    #pragma unroll
    for (int ch = 0; ch < 2; ch++) {
      #pragma unroll
      for (int reg = 0; reg < 16; reg++) {
        int r = (reg & 3) + 8*(reg >> 2) + 4*khl;
        tr[r*33 + ln31] = acc[row][ch][reg];
      }
      __builtin_amdgcn_s_waitcnt(0);
      #pragma unroll
      for (int gs = 0; gs < 2; gs++) {
        int g = khl + gs*2;
        Pack8 p;
        #pragma unroll
        for (int e = 0; e < 8; e++) p.h[e] = (__bf16)tr[(g*8 + e)*33 + ln31];
        RAWu[((size_t)(b*32 + Gb + g)*192 + i)*192 + j0 + ch*32 + ln31] = p.u;
      }
      __builtin_amdgcn_s_waitcnt(0);
    }
  }

  __syncthreads();
  if (tid < 32) {
    atomicAdd(&STAT2[oc0 + tid], sstat[tid]);
    atomicAdd(&STAT2[C2 + oc0 + tid], sstat[32 + tid]);
  }
}

// ---------------- fused: BN2 norm+relu, gate proj, next conv input: WIDE (384 thr) ----------------
template<int WRITE_NEXT>
__global__ __launch_bounds__(384)
void k_bn2_norm_gate(const __bf16* __restrict__ rawb, const float* __restrict__ STAT2,
                     const float* __restrict__ g, const float* __restrict__ bb,
                     const float* __restrict__ wd, const float* __restrict__ CLn,
                     __bf16* __restrict__ inb_next, float* __restrict__ tg) {
  int i = blockIdx.x, b = blockIdx.y;
  int tid = threadIdx.x;
  int j = tid % 192, half = tid / 192;
  __shared__ float sscale[C2], sshift[C2], swd[HH*C2];
  __shared__ float sg[2][HH][192];
  const float inv = 1.f / (float)(BB*NN);
  for (int c = tid; c < C2; c += 384) {
    float mean = STAT2[c] * inv;
    float var  = STAT2[C2 + c] * inv - mean*mean;
    float rstd = rsqrtf(var + EPS);
    float sc = rstd * g[c];
    sscale[c] = sc;
    sshift[c] = bb[c] - mean*sc;
  }
  for (int idx = tid; idx < HH*C2; idx += 384) swd[idx] = wd[idx];
  __syncthreads();
  float gacc[HH] = {};
  const uint4* RAWu = (const uint4*)rawb;
  for (int cu = half*16; cu < half*16 + 16; cu++) {
    Pack8 pr; pr.u = RAWu[((size_t)(b*32 + cu)*NP + i)*NP + j];
    Pack8 p;
    #pragma unroll
    for (int e = 0; e < 8; e++) {
      int c = cu*8 + e;
      float v = (float)pr.h[e];
      v = fmaxf(fmaf(v, sscale[c], sshift[c]), 0.f);
      if (WRITE_NEXT) {
        float nv = v + ((c < DIM) ? CLn[(b*DIM + c)*NP + i] : CLn[(b*DIM + c - DIM)*NP + j]);
        p.h[e] = (__bf16)nv;
      }
      #pragma unroll
      for (int h = 0; h < HH; h++) gacc[h] = fmaf(v, swd[h*C2 + c], gacc[h]);
    }
    if (WRITE_NEXT) {
      size_t unit = ((((size_t)(b*16 + (cu>>1))*PR + (i+1))*PC + (j+8))*2 + (cu&1));
      ((uint4*)inb_next)[unit] = p.u;
    }
  }
  #pragma unroll
  for (int h = 0; h < HH; h++) sg[half][h][j] = gacc[h];
  __syncthreads();
  if (half == 0) {
    #pragma unroll
    for (int h = 0; h < HH; h++)
      tg[((size_t)(b*HH + h)*NP + i)*NP + j] = sg[0][h][j] + sg[1][h][j];
  }
}

// ---------------- gate = sigmoid(t + t^T + bias), coalesced tiled transpose ----------------
__global__ void k_gate(const float* __restrict__ tg, const float* __restrict__ wdb,
                       float* __restrict__ gate) {
  int tile = blockIdx.x;
  int hb = blockIdx.y;
  int b = hb >> 3, h = hb & 7;
  size_t bh = (size_t)(b*HH + h);
  int ti = tile / 6, tj = tile % 6;
  int r = threadIdx.x >> 3, c4 = threadIdx.x & 7;
  __shared__ float tB[32][33];
  const float* base = tg + bh*NN;
  float4 vb = *(const float4*)(base + (tj*32 + r)*NP + ti*32 + c4*4);
  tB[r][c4*4+0] = vb.x; tB[r][c4*4+1] = vb.y; tB[r][c4*4+2] = vb.z; tB[r][c4*4+3] = vb.w;
  __syncthreads();
  float4 va = *(const float4*)(base + (ti*32 + r)*NP + tj*32 + c4*4);
  float bias = wdb[h];
  float4 o;
  o.x = 1.f / (1.f + expf(-(va.x + tB[c4*4+0][r] + bias)));
  o.y = 1.f / (1.f + expf(-(va.y + tB[c4*4+1][r] + bias)));
  o.z = 1.f / (1.f + expf(-(va.z + tB[c4*4+2][r] + bias)));
  o.w = 1.f / (1.f + expf(-(va.w + tB[c4*4+3][r] + bias)));
  *(float4*)(gate + bh*NN + (ti*32 + r)*NP + tj*32 + c4*4) = o;
}

// ---------------- MEGA-fused attnx: WIDE (384 thr) ----------------
// half-split heads for scores; 3-way jj split for PV; 3-way ee split for xup; one matvec
// per thread-third for QKV.
template<int MODE>
__global__ __launch_bounds__(384)
void k_attnx(const float* __restrict__ Q, const float* __restrict__ K,
             const float* __restrict__ V, const float* __restrict__ gate,
             const float* __restrict__ mask,
             float* __restrict__ X,
             const float* __restrict__ wlt, const float* __restrict__ bl,
             const float* __restrict__ ccn,
             const float* __restrict__ lng, const float* __restrict__ lnb,
             const float* __restrict__ wqt, const float* __restrict__ bq,
             const float* __restrict__ wkt, const float* __restrict__ bk,
             const float* __restrict__ wvt, const float* __restrict__ bv,
             float* __restrict__ Qn, float* __restrict__ Kn, float* __restrict__ Vn,
             const float* __restrict__ fct, const float* __restrict__ fb,
             float* __restrict__ out) {
  int i = blockIdx.x, b = blockIdx.y;
  int tid = threadIdx.x;
  int j = tid % 192, half = tid / 192;
  int lane = tid & 63, wave = tid >> 6;
  __shared__ float sq[DIM];
  __shared__ float sattn[HH][NP];
  __shared__ float spv[3][DIM];
  __shared__ float supd[DIM];
  __shared__ float sy[DIM];
  __shared__ float sxp[3][DIM];
  __shared__ float sredm[HH][3];
  __shared__ float sreds[HH][3];
  __shared__ float sred[2];
  float mk = mask[b*NP + j];

  if (tid < DIM) {
    int h = tid >> 4, d = tid & 15;
    sq[tid] = Q[(((size_t)(b*HH + h))*NP + i)*DHH + d];
  }
  __syncthreads();

  // scores: this half handles heads half*4 .. half*4+3
  float a[4], gt[4];
  #pragma unroll
  for (int hh = 0; hh < 4; hh++) {
    int h = half*4 + hh;
    size_t bh = (size_t)(b*HH + h);
    const float4* kr = (const float4*)(K + (bh*NP + j)*DHH);
    const float4* qr = (const float4*)(sq + h*DHH);
    float acc = 0.f;
    #pragma unroll
    for (int q4 = 0; q4 < 4; q4++) {
      float4 qv = qr[q4], kv = kr[q4];
      acc = fmaf(qv.x, kv.x, acc); acc = fmaf(qv.y, kv.y, acc);
      acc = fmaf(qv.z, kv.z, acc); acc = fmaf(qv.w, kv.w, acc);
    }
    a[hh] = acc * 0.25f;
    gt[hh] = gate[(bh*NP + i)*NP + j];
  }
  #pragma unroll
  for (int hh = 0; hh < 4; hh++) {
    int h = half*4 + hh;
    float m = a[hh];
    #pragma unroll
    for (int s = 32; s > 0; s >>= 1) m = fmaxf(m, __shfl_xor(m, s));
    if (lane == 0) sredm[h][wave % 3] = m;
  }
  __syncthreads();
  float e[4];
  #pragma unroll
  for (int hh = 0; hh < 4; hh++) {
    int h = half*4 + hh;
    float amax = fmaxf(fmaxf(sredm[h][0], sredm[h][1]), sredm[h][2]);
    e[hh] = expf(a[hh] - amax) * mk;
    float ss = e[hh];
    #pragma unroll
    for (int s = 32; s > 0; s >>= 1) ss += __shfl_xor(ss, s);
    if (lane == 0) sreds[h][wave % 3] = ss;
  }
  __syncthreads();
  #pragma unroll
  for (int hh = 0; hh < 4; hh++) {
    int h = half*4 + hh;
    float denom = sreds[h][0] + sreds[h][1] + sreds[h][2] + 1e-6f;
    sattn[h][j] = (e[hh] / denom) * gt[hh];
  }
  __syncthreads();

  // PV: threads (h2, d, jseg): 8*16*3 = 384; each sums 64 jj
  {
    int d = tid & 15, h2 = (tid >> 4) & 7, jseg = tid >> 7;
    size_t bh = (size_t)(b*HH + h2);
    float acc = 0.f;
    for (int jj = jseg*64; jj < jseg*64 + 64; jj++)
      acc = fmaf(sattn[h2][jj], V[(bh*NP + jj)*DHH + d], acc);
    spv[jseg][h2*DHH + d] = acc;
  }
  __syncthreads();
  if (tid < DIM) supd[tid] = spv[0][tid] + spv[1][tid] + spv[2][tid];
  __syncthreads();

  // xup: sy = X + upd; matvec split 3-way over ee
  size_t o = (size_t)(b*NP + i)*DIM;
  if (tid < DIM) sy[tid] = X[o + tid] + supd[tid];
  __syncthreads();
  {
    int d2 = tid & 127, ks = tid >> 7;          // ks 0..2
    int e0 = ks*43, e1 = (ks == 2) ? 128 : e0 + 43;
    float acc = (ks == 0) ? bl[d2] : 0.f;
    for (int ee = e0; ee < e1; ee++) acc = fmaf(wlt[ee*DIM + d2], sy[ee], acc);
    sxp[ks][d2] = acc;
  }
  __syncthreads();
  float xr = 0.f;
  if (tid < DIM) xr = fmaxf(sxp[0][tid] + sxp[1][tid] + sxp[2][tid], 0.f);
  __syncthreads();

  if (MODE == 0) {
    // LN(xr + ccn^T) over 128 dims: active waves 0,1
    float v = 0.f;
    if (tid < DIM) v = xr + ccn[(b*DIM + tid)*NP + i];
    if (tid < DIM) {
      float s = v;
      #pragma unroll
      for (int m = 32; m > 0; m >>= 1) s += __shfl_xor(s, m);
      if (lane == 0) sred[wave] = s;
    }
    __syncthreads();
    float mean = (sred[0] + sred[1]) * (1.f/128.f);
    float dv = v - mean;
    if (tid < DIM) {
      float q = dv*dv;
      #pragma unroll
      for (int m = 32; m > 0; m >>= 1) q += __shfl_xor(q, m);
      if (lane == 0) sred[wave] = q;
    }
    __syncthreads();
    float var = (sred[0] + sred[1]) * (1.f/128.f);
    float rstd = rsqrtf(var + EPS);
    if (tid < DIM) {
      float xn = dv * rstd * lng[tid] + lnb[tid];
      X[o + tid] = xn;
      sy[tid] = xn;
    }
    __syncthreads();
    // QKV: thread-third m does matvec m fully
    {
      int d2 = tid & 127, m = tid >> 7;         // m 0..2
      const float* wt_m = (m == 0) ? wqt : (m == 1) ? wkt : wvt;
      const float* b_m  = (m == 0) ? bq  : (m == 1) ? bk  : bv;
      float* out_m      = (m == 0) ? Qn  : (m == 1) ? Kn  : Vn;
      float acc = b_m[d2];
      for (int ee = 0; ee < DIM; ee++) acc = fmaf(wt_m[ee*DIM + d2], sy[ee], acc);
      int h = d2 >> 4, dh = d2 & 15;
      out_m[((size_t)(b*HH + h)*NP + i)*DHH + dh] = fmaxf(acc, 0.f);
    }
  } else {
    if (tid < DIM) sy[tid] = xr;
    __syncthreads();
    {
      int d2 = tid & 127, ks = tid >> 7;
      int e0 = ks*43, e1 = (ks == 2) ? 128 : e0 + 43;
      float acc = (ks == 0) ? fb[d2] : 0.f;
      for (int ee = e0; ee < e1; ee++) acc = fmaf(fct[ee*DIM + d2], sy[ee], acc);
      sxp[ks][d2] = acc;
    }
    __syncthreads();
    if (tid < DIM)
      out[o + tid] = fmaxf(sxp[0][tid] + sxp[1][tid] + sxp[2][tid], 0.f);
  }
}

extern "C" void kernel_launch(void* const* d_in, const int* in_sizes, int n_in,
                              void* d_out, int out_size, void* d_ws, size_t ws_size,
                              hipStream_t stream) {
  const float* seq     = (const float*)d_in[0];
  const float* mask    = (const float*)d_in[1];
  const float* conv1_w = (const float*)d_in[2];
  const float* conv2_w = (const float*)d_in[3];
  const float* ln_g    = (const float*)d_in[4];
  const float* ln_b    = (const float*)d_in[5];
  const float* c1d_w   = (const float*)d_in[6];
  const float* bn1_g   = (const float*)d_in[7];
  const float* bn1_b   = (const float*)d_in[8];
  const float* c2d_w   = (const float*)d_in[9];
  const float* bn2_g   = (const float*)d_in[10];
  const float* bn2_b   = (const float*)d_in[11];
  const float* wq_w    = (const float*)d_in[12];
  const float* wq_b    = (const float*)d_in[13];
  const float* wk_w    = (const float*)d_in[14];
  const float* wk_b    = (const float*)d_in[15];
  const float* wv_w    = (const float*)d_in[16];
  const float* wv_b    = (const float*)d_in[17];
  const float* wd_w    = (const float*)d_in[18];
  const float* wd_b    = (const float*)d_in[19];
  const float* wl_w    = (const float*)d_in[20];
  const float* wl_b    = (const float*)d_in[21];
  const float* fc_w    = (const float*)d_in[22];
  const float* fc_b    = (const float*)d_in[23];
  float* out = (float*)d_out;

  float* ws = (float*)d_ws;
  float* X    = ws; ws += BB*NP*DIM;
  float* Cc   = ws; ws += BB*DIM*NP;
  float* CL0  = ws; ws += BB*DIM*NP;
  float* CL1  = ws; ws += BB*DIM*NP;
  float* CL2  = ws; ws += BB*DIM*NP;
  float* Q0   = ws; ws += BB*NP*DIM;
  float* K0   = ws; ws += BB*NP*DIM;
  float* V0   = ws; ws += BB*NP*DIM;
  float* Q1   = ws; ws += BB*NP*DIM;
  float* K1   = ws; ws += BB*NP*DIM;
  float* V1   = ws; ws += BB*NP*DIM;
  float* TG   = ws; ws += (size_t)BB*HH*NN;
  float* GATE = ws; ws += (size_t)BB*HH*NN;
  float* WQT  = ws; ws += (size_t)LL*DIM*DIM;
  float* WKT  = ws; ws += (size_t)LL*DIM*DIM;
  float* WVT  = ws; ws += (size_t)LL*DIM*DIM;
  float* WLT  = ws; ws += (size_t)LL*DIM*DIM;
  float* FCT  = ws; ws += (size_t)DIM*DIM;
  float* STATALL = ws; ws += 3*2*C2;
  __bf16* RAW = (__bf16*)ws; ws += (size_t)BB*C2*NN/2;
  __bf16* INB = (__bf16*)ws; ws += (size_t)BB*16*PR*PC*2*16/4;
  __bf16* WTB = (__bf16*)ws; ws += (size_t)LL*C2*C2*9/2;

  k_wtrans<<<dim3(16, 13), 256, 0, stream>>>(wq_w, wk_w, wv_w, wl_w, fc_w,
                                             WQT, WKT, WVT, WLT, FCT);
  k_wprep<<<LL*C2, 256, 0, stream>>>(c2d_w, WTB);
  k_conv_init<<<dim3(NP, BB), DIM, 0, stream>>>(seq, conv1_w, conv2_w, X, Cc);
  k_conv1d_bn_relu<<<DIM, 768, 0, stream>>>(Cc,  c1d_w + 0*(size_t)DIM*DIM*3, bn1_g + 0*DIM, bn1_b + 0*DIM, CL0);
  k_conv1d_bn_relu<<<DIM, 768, 0, stream>>>(CL0, c1d_w + 1*(size_t)DIM*DIM*3, bn1_g + 1*DIM, bn1_b + 1*DIM, CL1);
  k_conv1d_bn_relu<<<DIM, 768, 0, stream>>>(CL1, c1d_w + 2*(size_t)DIM*DIM*3, bn1_g + 2*DIM, bn1_b + 2*DIM, CL2);
  k_make_convin<<<(BB*16*PR*PC*2)/256, 256, 0, stream>>>(Cc, CL0, INB, STATALL);
  k_lnqkv<<<dim3(NP, BB), DIM, 0, stream>>>(X, CL0, ln_g, ln_b,
                                            WQT, wq_b, WKT, wk_b, WVT, wv_b, Q0, K0, V0);

  // ---- layer 0 ----
  k_conv2d_mfma<<<dim3(3, 24, 16), 256, 0, stream>>>(INB, WTB + 0*(size_t)16*9*2*256*8, RAW, STATALL + 0*2*C2);
  k_bn2_norm_gate<1><<<dim3(NP, BB), 384, 0, stream>>>(RAW, STATALL + 0*2*C2, bn2_g + 0*C2, bn2_b + 0*C2,
                                                       wd_w + 0*(size_t)HH*C2, CL1, INB, TG);
  k_gate<<<dim3(36, 16), 256, 0, stream>>>(TG, wd_b + 0*HH, GATE);
  k_attnx<0><<<dim3(NP, BB), 384, 0, stream>>>(Q0, K0, V0, GATE, mask, X,
                                               WLT + 0*(size_t)DIM*DIM, wl_b + 0*DIM,
                                               CL1, ln_g + 1*DIM, ln_b + 1*DIM,
                                               WQT + 1*(size_t)DIM*DIM, wq_b + 1*DIM,
                                               WKT + 1*(size_t)DIM*DIM, wk_b + 1*DIM,
                                               WVT + 1*(size_t)DIM*DIM, wv_b + 1*DIM,
                                               Q1, K1, V1, nullptr, nullptr, nullptr);
  // ---- layer 1 ----
  k_conv2d_mfma<<<dim3(3, 24, 16), 256, 0, stream>>>(INB, WTB + 1*(size_t)16*9*2*256*8, RAW, STATALL + 1*2*C2);
  k_bn2_norm_gate<1><<<dim3(NP, BB), 384, 0, stream>>>(RAW, STATALL + 1*2*C2, bn2_g + 1*C2, bn2_b + 1*C2,
                                                       wd_w + 1*(size_t)HH*C2, CL2, INB, TG);
  k_gate<<<dim3(36, 16), 256, 0, stream>>>(TG, wd_b + 1*HH, GATE);
  k_attnx<0><<<dim3(NP, BB), 384, 0, stream>>>(Q1, K1, V1, GATE, mask, X,
                                               WLT + 1*(size_t)DIM*DIM, wl_b + 1*DIM,
                                               CL2, ln_g + 2*DIM, ln_b + 2*DIM,
                                               WQT + 2*(size_t)DIM*DIM, wq_b + 2*DIM,
                                               WKT + 2*(size_t)DIM*DIM, wk_b + 2*DIM,
                                               WVT + 2*(size_t)DIM*DIM, wv_b + 2*DIM,
                                               Q0, K0, V0, nullptr, nullptr, nullptr);
  // ---- layer 2 ----
  k_conv2d_mfma<<<dim3(3, 24, 16), 256, 0, stream>>>(INB, WTB + 2*(size_t)16*9*2*256*8, RAW, STATALL + 2*2*C2);
  k_bn2_norm_gate<0><<<dim3(NP, BB), 384, 0, stream>>>(RAW, STATALL + 2*2*C2, bn2_g + 2*C2, bn2_b + 2*C2,
                                                       wd_w + 2*(size_t)HH*C2, nullptr, nullptr, TG);
  k_gate<<<dim3(36, 16), 256, 0, stream>>>(TG, wd_b + 2*HH, GATE);
  k_attnx<1><<<dim3(NP, BB), 384, 0, stream>>>(Q0, K0, V0, GATE, mask, X,
                                               WLT + 2*(size_t)DIM*DIM, wl_b + 2*DIM,
                                               nullptr, nullptr, nullptr,
                                               nullptr, nullptr, nullptr, nullptr, nullptr, nullptr,
                                               nullptr, nullptr, nullptr,
                                               FCT, fc_b, out);
}

// Round 11
// 571.954 us; speedup vs baseline: 2.1041x; 1.0342x over previous
//
#include <hip/hip_runtime.h>
#include <math.h>

#define IN_DIM 20
#define DIM 128
#define HH 8
#define LL 3
#define BB 2
#define NP 192
#define DHH 16
#define C2 256
#define NN (NP*NP)
#define EPS 1e-5f

// padded conv-input geometry
#define PR 200
#define PC 224

typedef __bf16 bf16x8 __attribute__((ext_vector_type(8)));
typedef float  f32x16 __attribute__((ext_vector_type(16)));

union Pack8 { __bf16 h[8]; uint4 u; };

#define GLOAD16(gp, lp) \
  __builtin_amdgcn_global_load_lds((const __attribute__((address_space(1))) uint4*)(gp), \
                                   (__attribute__((address_space(3))) uint4*)(lp), 16, 0, 0)

// ---------------- init: conv1d over seq for both x and c (+ t-major CcT) ----------------
__global__ void k_conv_init(const float* __restrict__ seq, const float* __restrict__ w1,
                            const float* __restrict__ w2, float* __restrict__ X,
                            float* __restrict__ Cc, float* __restrict__ CcT) {
  int t = blockIdx.x, b = blockIdx.y, oc = threadIdx.x;
  __shared__ float ss[3][IN_DIM];
  if (threadIdx.x < 3*IN_DIM) {
    int k = threadIdx.x / IN_DIM, ic = threadIdx.x % IN_DIM;
    int tt = t + k - 1;
    ss[k][ic] = (tt >= 0 && tt < NP) ? seq[(b*NP + tt)*IN_DIM + ic] : 0.f;
  }
  __syncthreads();
  float a1 = 0.f, a2 = 0.f;
  #pragma unroll
  for (int ic = 0; ic < IN_DIM; ic++) {
    #pragma unroll
    for (int k = 0; k < 3; k++) {
      float sv = ss[k][ic];
      a1 = fmaf(w1[(oc*IN_DIM + ic)*3 + k], sv, a1);
      a2 = fmaf(w2[(oc*IN_DIM + ic)*3 + k], sv, a2);
    }
  }
  X[(b*NP + t)*DIM + oc] = a1;
  Cc[(b*DIM + oc)*NP + t] = a2;
  CcT[(size_t)(b*NP + t)*DIM + oc] = a2;
}

// ---------------- conv1d + BN + relu: WIDE (768 thr); writes c-major AND t-major ----------------
__global__ __launch_bounds__(768)
void k_conv1d_bn_relu(const float* __restrict__ cin, const float* __restrict__ w,
                      const float* __restrict__ g, const float* __restrict__ bb,
                      float* __restrict__ cout, float* __restrict__ coutT) {
  int oc = blockIdx.x;
  int tid = threadIdx.x;
  int t = tid % NP;
  int sub = tid / NP;            // 0..3
  int b = sub & 1, ih = sub >> 1;
  float acc = 0.f;
  for (int ic = ih*64; ic < ih*64 + 64; ic++) {
    const float* cr = cin + (b*DIM + ic)*NP;
    const float* wr = w + (oc*DIM + ic)*3;
    float lf = (t > 0)      ? cr[t-1] : 0.f;
    float mf = cr[t];
    float rf = (t < NP-1)   ? cr[t+1] : 0.f;
    acc = fmaf(lf, wr[0], acc);
    acc = fmaf(mf, wr[1], acc);
    acc = fmaf(rf, wr[2], acc);
  }
  __shared__ float sp[4][NP];
  __shared__ float sb[768];
  sp[sub][t] = acc;
  __syncthreads();
  float raw = sp[b][t] + sp[2 + b][t];
  sb[tid] = (sub < 2) ? raw : raw * raw;
  __syncthreads();
  for (int s = 192; s >= 3; s >>= 1) {
    if (tid < s) sb[tid] += sb[tid + s];
    int u = tid - 384;
    if (u >= 0 && u < s) sb[tid] += sb[tid + s];
    __syncthreads();
  }
  float mean = (sb[0] + sb[1] + sb[2]) / 384.f;
  float var  = (sb[384] + sb[385] + sb[386]) / 384.f - mean*mean;
  float rstd = rsqrtf(var + EPS);
  if (sub < 2) {
    float v = fmaxf((raw - mean)*rstd*g[oc] + bb[oc], 0.f);
    cout[(b*DIM + oc)*NP + t] = v;
    coutT[(size_t)(b*NP + t)*DIM + oc] = v;
  }
}

// ---------------- small-weight transpose: wT[e][j] = w[j][e], 13 matrices ----------------
__global__ void k_wtrans(const float* __restrict__ wq, const float* __restrict__ wk,
                         const float* __restrict__ wv, const float* __restrict__ wl,
                         const float* __restrict__ fcw,
                         float* __restrict__ wqt, float* __restrict__ wkt,
                         float* __restrict__ wvt, float* __restrict__ wlt,
                         float* __restrict__ fct) {
  int m = blockIdx.y;
  const float* src; float* dst;
  if (m < 3)       { src = wq + (size_t)m*DIM*DIM;     dst = wqt + (size_t)m*DIM*DIM; }
  else if (m < 6)  { src = wk + (size_t)(m-3)*DIM*DIM; dst = wkt + (size_t)(m-3)*DIM*DIM; }
  else if (m < 9)  { src = wv + (size_t)(m-6)*DIM*DIM; dst = wvt + (size_t)(m-6)*DIM*DIM; }
  else if (m < 12) { src = wl + (size_t)(m-9)*DIM*DIM; dst = wlt + (size_t)(m-9)*DIM*DIM; }
  else             { src = fcw;                        dst = fct; }
  int tile = blockIdx.x;
  int ti = tile >> 2, tj = tile & 3;
  int r = threadIdx.x >> 3, c4 = threadIdx.x & 7;
  __shared__ float t[32][33];
  float4 v = *(const float4*)(src + (ti*32 + r)*DIM + tj*32 + c4*4);
  t[r][c4*4+0] = v.x; t[r][c4*4+1] = v.y; t[r][c4*4+2] = v.z; t[r][c4*4+3] = v.w;
  __syncthreads();
  float4 o;
  o.x = t[c4*4+0][r]; o.y = t[c4*4+1][r]; o.z = t[c4*4+2][r]; o.w = t[c4*4+3][r];
  *(float4*)(dst + (tj*32 + r)*DIM + ti*32 + c4*4) = o;
}

// ---------------- layer-0: x = LN(x + ccT), q,k,v — WIDE (384 thr) ----------------
__global__ __launch_bounds__(384)
void k_lnqkv(float* __restrict__ X, const float* __restrict__ ccT,
             const float* __restrict__ g, const float* __restrict__ bb,
             const float* __restrict__ wqt, const float* __restrict__ bq,
             const float* __restrict__ wkt, const float* __restrict__ bk,
             const float* __restrict__ wvt, const float* __restrict__ bv,
             float* __restrict__ Q, float* __restrict__ K, float* __restrict__ V) {
  int t = blockIdx.x, b = blockIdx.y;
  int tid = threadIdx.x;
  int lane = tid & 63, wave = tid >> 6;
  __shared__ float sy[DIM];
  __shared__ float sred[2];
  size_t o = (size_t)(b*NP + t)*DIM;
  float v = 0.f;
  if (tid < DIM) v = X[o + tid] + ccT[o + tid];
  if (tid < DIM) {
    float s = v;
    #pragma unroll
    for (int m = 32; m > 0; m >>= 1) s += __shfl_xor(s, m);
    if (lane == 0) sred[wave] = s;
  }
  __syncthreads();
  float mean = (sred[0] + sred[1]) * (1.f/128.f);
  float dv = v - mean;
  __syncthreads();                     // all mean reads done before sred reuse
  if (tid < DIM) {
    float q = dv*dv;
    #pragma unroll
    for (int m = 32; m > 0; m >>= 1) q += __shfl_xor(q, m);
    if (lane == 0) sred[wave] = q;
  }
  __syncthreads();
  float var = (sred[0] + sred[1]) * (1.f/128.f);
  float rstd = rsqrtf(var + EPS);
  if (tid < DIM) {
    float xn = dv * rstd * g[tid] + bb[tid];
    X[o + tid] = xn;
    sy[tid] = xn;
  }
  __syncthreads();
  {
    int d2 = tid & 127, m = tid >> 7;
    const float* wt_m = (m == 0) ? wqt : (m == 1) ? wkt : wvt;
    const float* b_m  = (m == 0) ? bq  : (m == 1) ? bk  : bv;
    float* out_m      = (m == 0) ? Q   : (m == 1) ? K   : V;
    float acc = b_m[d2];
    for (int ee = 0; ee < DIM; ee++) acc = fmaf(wt_m[ee*DIM + d2], sy[ee], acc);
    int h = d2 >> 4, dh = d2 & 15;
    out_m[((size_t)(b*HH + h)*NP + t)*DHH + dh] = fmaxf(acc, 0.f);
  }
}

// ---------------- conv2d weight prep (coalesced reads via LDS) ----------------
__global__ void k_wprep(const float* __restrict__ w, __bf16* __restrict__ wtb) {
  int l = blockIdx.x / C2, oc = blockIdx.x % C2;
  int tid = threadIdx.x;
  __shared__ float swt[C2*9];
  const float4* wsrc = (const float4*)(w + ((size_t)(l*C2 + oc))*C2*9);
  for (int idx = tid; idx < 576; idx += 256) ((float4*)swt)[idx] = wsrc[idx];
  __syncthreads();
  for (int v = tid; v < 288; v += 256) {
    int chunk = v / 18, rem = v % 18;
    int kk = rem >> 1, kh = rem & 1;
    Pack8 p;
    #pragma unroll
    for (int e = 0; e < 8; e++)
      p.h[e] = (__bf16)swt[(chunk*16 + kh*8 + e)*9 + kk];
    size_t unit = ((((size_t)(l*16 + chunk)*9 + kk)*2 + kh)*256 + oc);
    ((uint4*)wtb)[unit] = p.u;
  }
}

// ---------------- layer-0 conv input build from t-major sources; zeroes 3x STAT2 ----------------
__global__ void k_make_convin(const float* __restrict__ CcT, const float* __restrict__ CLT0,
                              __bf16* __restrict__ inb, float* __restrict__ STATALL) {
  int idx = blockIdx.x*256 + threadIdx.x;
  if (blockIdx.x == 0) {
    for (int z = threadIdx.x; z < 3*2*C2; z += 256) STATALL[z] = 0.f;
  }
  int kh = idx & 1;
  int t = idx >> 1;
  int gcol = t % PC; int t2 = t / PC;
  int grow = t2 % PR; int t3 = t2 / PR;
  int chunk = t3 & 15; int b = t3 >> 4;
  int i = grow - 1, j = gcol - 8;
  Pack8 p;
  if ((unsigned)i < 192u && (unsigned)j < 192u) {
    int cbase = chunk*16 + kh*8;
    const float* pa;
    const float* pb;
    if (cbase < DIM) {
      pa = CcT  + (size_t)(b*NP + i)*DIM + cbase;
      pb = CLT0 + (size_t)(b*NP + i)*DIM + cbase;
    } else {
      pa = CcT  + (size_t)(b*NP + j)*DIM + (cbase - DIM);
      pb = CLT0 + (size_t)(b*NP + j)*DIM + (cbase - DIM);
    }
    #pragma unroll
    for (int e = 0; e < 8; e++) p.h[e] = (__bf16)(pa[e] + pb[e]);
  } else {
    #pragma unroll
    for (int e = 0; e < 8; e++) p.h[e] = (__bf16)0.f;
  }
  ((uint4*)inb)[idx] = p.u;
}

// ---------------- heavy kernel: implicit-GEMM bf16 MFMA 3x3 conv (UNCHANGED from R8) ----------------
__global__ __launch_bounds__(256, 2)
void k_conv2d_mfma(const __bf16* __restrict__ inb,
                   const __bf16* __restrict__ wtb,
                   __bf16* __restrict__ rawb,
                   float* __restrict__ STAT2) {
  __shared__ __align__(16) uint4 sbuf[2*2176];
  int tid = threadIdx.x;
  int jt = blockIdx.x, it = blockIdx.y, zz = blockIdx.z;
  int b = zz >> 3, oct = zz & 7;
  int i0 = it*8, j0 = jt*64, oc0 = oct*32;
  int lane = tid & 63, wv = tid >> 6;
  int ln31 = lane & 31, khl = lane >> 5;

  const uint4* gW = (const uint4*)wtb;
  const uint4* gI = (const uint4*)inb;

  f32x16 acc[2][2];
  #pragma unroll
  for (int r = 0; r < 2; r++)
    #pragma unroll
    for (int n = 0; n < 2; n++)
      #pragma unroll
      for (int q = 0; q < 16; q++) acc[r][n][q] = 0.f;

  const uint4* gp[9];
  int lofs[9];
  int gstride[9];
  bool gvalid[9];
  #pragma unroll
  for (int t = 0; t < 9; t++) {
    int L = t*4 + wv;
    gvalid[t] = (L < 34);
    if (L < 9) {
      int u = L*64 + lane;
      int kkh = u >> 5;
      int ocl = u & 31;
      gp[t] = gW + (size_t)kkh*256 + oc0 + ocl;
      lofs[t] = u;
      gstride[t] = 4608;
    } else {
      int u = L*64 + lane - 576;
      int r = u / 160;
      int rem = u % 160;
      int kh = rem / 80;
      int c = rem % 80;
      gp[t] = gI + (((size_t)(b*16)*PR) + i0 + r)*PC*2 + (size_t)(j0 + c)*2 + kh;
      lofs[t] = 576 + u;
      gstride[t] = PR*PC*2;
    }
  }

  auto issue = [&](int buf) {
    uint4* lbase = sbuf + buf*2176;
    #pragma unroll
    for (int t = 0; t < 9; t++) {
      if (gvalid[t]) {
        GLOAD16(gp[t], lbase + lofs[t]);
        gp[t] += gstride[t];
      }
    }
  };

  issue(0);

  for (int chunk = 0; chunk < 16; ++chunk) {
    int buf = chunk & 1;
    __syncthreads();
    if (chunk < 15) issue(buf ^ 1);
    const __bf16* Wl = (const __bf16*)(sbuf + buf*2176);
    const __bf16* Il = (const __bf16*)(sbuf + buf*2176 + 576);
    #pragma unroll
    for (int kj = 0; kj < 3; kj++) {
      bf16x8 bfr[4][2];
      #pragma unroll
      for (int rr = 0; rr < 4; rr++) {
        int r = wv*2 + rr;
        #pragma unroll
        for (int ch = 0; ch < 2; ch++) {
          int c = ch*32 + ln31 + kj + 7;
          bfr[rr][ch] = *(const bf16x8*)(Il + ((r*2 + khl)*80 + c)*8);
        }
      }
      #pragma unroll
      for (int ki = 0; ki < 3; ki++) {
        int kk = ki*3 + kj;
        bf16x8 a = *(const bf16x8*)(Wl + ((kk*2 + khl)*32 + ln31)*8);
        #pragma unroll
        for (int row = 0; row < 2; row++)
          #pragma unroll
          for (int ch = 0; ch < 2; ch++)
            acc[row][ch] = __builtin_amdgcn_mfma_f32_32x32x16_bf16(a, bfr[row + ki][ch], acc[row][ch], 0, 0, 0);
      }
    }
  }

  __syncthreads();
  float* trAll = (float*)sbuf;
  float* tr = trAll + wv*(32*33);
  float* sstat = trAll + 4*32*33;
  if (tid < 64) sstat[tid] = 0.f;
  __syncthreads();

  #pragma unroll
  for (int reg = 0; reg < 16; reg++) {
    float v00 = acc[0][0][reg], v01 = acc[0][1][reg];
    float v10 = acc[1][0][reg], v11 = acc[1][1][reg];
    float s = v00 + v01 + v10 + v11;
    float s2 = v00*v00 + v01*v01 + v10*v10 + v11*v11;
    #pragma unroll
    for (int msk = 1; msk <= 16; msk <<= 1) { s += __shfl_xor(s, msk); s2 += __shfl_xor(s2, msk); }
    if (ln31 == 0) {
      int oc_l = (reg & 3) + 8*(reg >> 2) + 4*khl;
      atomicAdd(&sstat[oc_l], s);
      atomicAdd(&sstat[32 + oc_l], s2);
    }
  }

  int Gb = oc0 >> 3;
  uint4* RAWu = (uint4*)rawb;
  #pragma unroll
  for (int row = 0; row < 2; row++) {
    int i = i0 + wv*2 + row;
    #pragma unroll
    for (int ch = 0; ch < 2; ch++) {
      #pragma unroll
      for (int reg = 0; reg < 16; reg++) {
        int r = (reg & 3) + 8*(reg >> 2) + 4*khl;
        tr[r*33 + ln31] = acc[row][ch][reg];
      }
      __builtin_amdgcn_s_waitcnt(0);
      #pragma unroll
      for (int gs = 0; gs < 2; gs++) {
        int g = khl + gs*2;
        Pack8 p;
        #pragma unroll
        for (int e = 0; e < 8; e++) p.h[e] = (__bf16)tr[(g*8 + e)*33 + ln31];
        RAWu[((size_t)(b*32 + Gb + g)*192 + i)*192 + j0 + ch*32 + ln31] = p.u;
      }
      __builtin_amdgcn_s_waitcnt(0);
    }
  }

  __syncthreads();
  if (tid < 32) {
    atomicAdd(&STAT2[oc0 + tid], sstat[tid]);
    atomicAdd(&STAT2[C2 + oc0 + tid], sstat[32 + tid]);
  }
}

// ---------------- fused: BN2 norm+relu, gate proj, next conv input: WIDER (768 thr) ----------------
template<int WRITE_NEXT>
__global__ __launch_bounds__(768)
void k_bn2_norm_gate(const __bf16* __restrict__ rawb, const float* __restrict__ STAT2,
                     const float* __restrict__ g, const float* __restrict__ bb,
                     const float* __restrict__ wd, const float* __restrict__ CLnT,
                     __bf16* __restrict__ inb_next, float* __restrict__ tg) {
  int i = blockIdx.x, b = blockIdx.y;
  int tid = threadIdx.x;
  int j = tid % 192, qt = tid / 192;       // quarter 0..3
  __shared__ float sscale[C2], sshift[C2], swd[HH*C2];
  __shared__ float sg[4][HH][192];
  const float inv = 1.f / (float)(BB*NN);
  for (int c = tid; c < C2; c += 768) {
    float mean = STAT2[c] * inv;
    float var  = STAT2[C2 + c] * inv - mean*mean;
    float rstd = rsqrtf(var + EPS);
    float sc = rstd * g[c];
    sscale[c] = sc;
    sshift[c] = bb[c] - mean*sc;
  }
  for (int idx = tid; idx < HH*C2; idx += 768) swd[idx] = wd[idx];
  __syncthreads();
  float gacc[HH] = {};
  const uint4* RAWu = (const uint4*)rawb;
  const float* clrow_i = CLnT ? CLnT + (size_t)(b*NP + i)*DIM : nullptr;
  const float* clrow_j = CLnT ? CLnT + (size_t)(b*NP + j)*DIM : nullptr;
  for (int cu = qt*8; cu < qt*8 + 8; cu++) {
    Pack8 pr; pr.u = RAWu[((size_t)(b*32 + cu)*NP + i)*NP + j];
    Pack8 p;
    int cbase = cu*8;
    const float* clp = (WRITE_NEXT && cbase < DIM) ? clrow_i + cbase
                     : (WRITE_NEXT ? clrow_j + (cbase - DIM) : nullptr);
    #pragma unroll
    for (int e = 0; e < 8; e++) {
      int c = cbase + e;
      float v = (float)pr.h[e];
      v = fmaxf(fmaf(v, sscale[c], sshift[c]), 0.f);
      if (WRITE_NEXT) p.h[e] = (__bf16)(v + clp[e]);
      #pragma unroll
      for (int h = 0; h < HH; h++) gacc[h] = fmaf(v, swd[h*C2 + c], gacc[h]);
    }
    if (WRITE_NEXT) {
      size_t unit = ((((size_t)(b*16 + (cu>>1))*PR + (i+1))*PC + (j+8))*2 + (cu&1));
      ((uint4*)inb_next)[unit] = p.u;
    }
  }
  #pragma unroll
  for (int h = 0; h < HH; h++) sg[qt][h][j] = gacc[h];
  __syncthreads();
  if (qt == 0) {
    #pragma unroll
    for (int h = 0; h < HH; h++)
      tg[((size_t)(b*HH + h)*NP + i)*NP + j] = sg[0][h][j] + sg[1][h][j] + sg[2][h][j] + sg[3][h][j];
  }
}

// ---------------- gate = sigmoid(t + t^T + bias), coalesced tiled transpose ----------------
__global__ void k_gate(const float* __restrict__ tg, const float* __restrict__ wdb,
                       float* __restrict__ gate) {
  int tile = blockIdx.x;
  int hb = blockIdx.y;
  int b = hb >> 3, h = hb & 7;
  size_t bh = (size_t)(b*HH + h);
  int ti = tile / 6, tj = tile % 6;
  int r = threadIdx.x >> 3, c4 = threadIdx.x & 7;
  __shared__ float tB[32][33];
  const float* base = tg + bh*NN;
  float4 vb = *(const float4*)(base + (tj*32 + r)*NP + ti*32 + c4*4);
  tB[r][c4*4+0] = vb.x; tB[r][c4*4+1] = vb.y; tB[r][c4*4+2] = vb.z; tB[r][c4*4+3] = vb.w;
  __syncthreads();
  float4 va = *(const float4*)(base + (ti*32 + r)*NP + tj*32 + c4*4);
  float bias = wdb[h];
  float4 o;
  o.x = 1.f / (1.f + expf(-(va.x + tB[c4*4+0][r] + bias)));
  o.y = 1.f / (1.f + expf(-(va.y + tB[c4*4+1][r] + bias)));
  o.z = 1.f / (1.f + expf(-(va.z + tB[c4*4+2][r] + bias)));
  o.w = 1.f / (1.f + expf(-(va.w + tB[c4*4+3][r] + bias)));
  *(float4*)(gate + bh*NN + (ti*32 + r)*NP + tj*32 + c4*4) = o;
}

// ---------------- MEGA-fused attnx: WIDE (384 thr), t-major ccn ----------------
template<int MODE>
__global__ __launch_bounds__(384)
void k_attnx(const float* __restrict__ Q, const float* __restrict__ K,
             const float* __restrict__ V, const float* __restrict__ gate,
             const float* __restrict__ mask,
             float* __restrict__ X,
             const float* __restrict__ wlt, const float* __restrict__ bl,
             const float* __restrict__ ccnT,
             const float* __restrict__ lng, const float* __restrict__ lnb,
             const float* __restrict__ wqt, const float* __restrict__ bq,
             const float* __restrict__ wkt, const float* __restrict__ bk,
             const float* __restrict__ wvt, const float* __restrict__ bv,
             float* __restrict__ Qn, float* __restrict__ Kn, float* __restrict__ Vn,
             const float* __restrict__ fct, const float* __restrict__ fb,
             float* __restrict__ out) {
  int i = blockIdx.x, b = blockIdx.y;
  int tid = threadIdx.x;
  int j = tid % 192, half = tid / 192;
  int lane = tid & 63, wave = tid >> 6;
  __shared__ float sq[DIM];
  __shared__ float sattn[HH][NP];
  __shared__ float spv[3][DIM];
  __shared__ float supd[DIM];
  __shared__ float sy[DIM];
  __shared__ float sxp[3][DIM];
  __shared__ float sredm[HH][3];
  __shared__ float sreds[HH][3];
  __shared__ float sred[2];
  float mk = mask[b*NP + j];

  if (tid < DIM) {
    int h = tid >> 4, d = tid & 15;
    sq[tid] = Q[(((size_t)(b*HH + h))*NP + i)*DHH + d];
  }
  __syncthreads();

  float a[4], gt[4];
  #pragma unroll
  for (int hh = 0; hh < 4; hh++) {
    int h = half*4 + hh;
    size_t bh = (size_t)(b*HH + h);
    const float4* kr = (const float4*)(K + (bh*NP + j)*DHH);
    const float4* qr = (const float4*)(sq + h*DHH);
    float acc = 0.f;
    #pragma unroll
    for (int q4 = 0; q4 < 4; q4++) {
      float4 qv = qr[q4], kv = kr[q4];
      acc = fmaf(qv.x, kv.x, acc); acc = fmaf(qv.y, kv.y, acc);
      acc = fmaf(qv.z, kv.z, acc); acc = fmaf(qv.w, kv.w, acc);
    }
    a[hh] = acc * 0.25f;
    gt[hh] = gate[(bh*NP + i)*NP + j];
  }
  #pragma unroll
  for (int hh = 0; hh < 4; hh++) {
    int h = half*4 + hh;
    float m = a[hh];
    #pragma unroll
    for (int s = 32; s > 0; s >>= 1) m = fmaxf(m, __shfl_xor(m, s));
    if (lane == 0) sredm[h][wave % 3] = m;
  }
  __syncthreads();
  float e[4];
  #pragma unroll
  for (int hh = 0; hh < 4; hh++) {
    int h = half*4 + hh;
    float amax = fmaxf(fmaxf(sredm[h][0], sredm[h][1]), sredm[h][2]);
    e[hh] = expf(a[hh] - amax) * mk;
    float ss = e[hh];
    #pragma unroll
    for (int s = 32; s > 0; s >>= 1) ss += __shfl_xor(ss, s);
    if (lane == 0) sreds[h][wave % 3] = ss;
  }
  __syncthreads();
  #pragma unroll
  for (int hh = 0; hh < 4; hh++) {
    int h = half*4 + hh;
    float denom = sreds[h][0] + sreds[h][1] + sreds[h][2] + 1e-6f;
    sattn[h][j] = (e[hh] / denom) * gt[hh];
  }
  __syncthreads();

  {
    int d = tid & 15, h2 = (tid >> 4) & 7, jseg = tid >> 7;
    size_t bh = (size_t)(b*HH + h2);
    float acc = 0.f;
    for (int jj = jseg*64; jj < jseg*64 + 64; jj++)
      acc = fmaf(sattn[h2][jj], V[(bh*NP + jj)*DHH + d], acc);
    spv[jseg][h2*DHH + d] = acc;
  }
  __syncthreads();
  if (tid < DIM) supd[tid] = spv[0][tid] + spv[1][tid] + spv[2][tid];
  __syncthreads();

  size_t o = (size_t)(b*NP + i)*DIM;
  if (tid < DIM) sy[tid] = X[o + tid] + supd[tid];
  __syncthreads();
  {
    int d2 = tid & 127, ks = tid >> 7;
    int e0 = ks*43, e1 = (ks == 2) ? 128 : e0 + 43;
    float acc = (ks == 0) ? bl[d2] : 0.f;
    for (int ee = e0; ee < e1; ee++) acc = fmaf(wlt[ee*DIM + d2], sy[ee], acc);
    sxp[ks][d2] = acc;
  }
  __syncthreads();
  float xr = 0.f;
  if (tid < DIM) xr = fmaxf(sxp[0][tid] + sxp[1][tid] + sxp[2][tid], 0.f);
  __syncthreads();

  if (MODE == 0) {
    float v = 0.f;
    if (tid < DIM) v = xr + ccnT[o + tid];
    if (tid < DIM) {
      float s = v;
      #pragma unroll
      for (int m = 32; m > 0; m >>= 1) s += __shfl_xor(s, m);
      if (lane == 0) sred[wave] = s;
    }
    __syncthreads();
    float mean = (sred[0] + sred[1]) * (1.f/128.f);
    float dv = v - mean;
    __syncthreads();                   // all mean reads done before sred reuse
    if (tid < DIM) {
      float q = dv*dv;
      #pragma unroll
      for (int m = 32; m > 0; m >>= 1) q += __shfl_xor(q, m);
      if (lane == 0) sred[wave] = q;
    }
    __syncthreads();
    float var = (sred[0] + sred[1]) * (1.f/128.f);
    float rstd = rsqrtf(var + EPS);
    if (tid < DIM) {
      float xn = dv * rstd * lng[tid] + lnb[tid];
      X[o + tid] = xn;
      sy[tid] = xn;
    }
    __syncthreads();
    {
      int d2 = tid & 127, m = tid >> 7;
      const float* wt_m = (m == 0) ? wqt : (m == 1) ? wkt : wvt;
      const float* b_m  = (m == 0) ? bq  : (m == 1) ? bk  : bv;
      float* out_m      = (m == 0) ? Qn  : (m == 1) ? Kn  : Vn;
      float acc = b_m[d2];
      for (int ee = 0; ee < DIM; ee++) acc = fmaf(wt_m[ee*DIM + d2], sy[ee], acc);
      int h = d2 >> 4, dh = d2 & 15;
      out_m[((size_t)(b*HH + h)*NP + i)*DHH + dh] = fmaxf(acc, 0.f);
    }
  } else {
    if (tid < DIM) sy[tid] = xr;
    __syncthreads();
    {
      int d2 = tid & 127, ks = tid >> 7;
      int e0 = ks*43, e1 = (ks == 2) ? 128 : e0 + 43;
      float acc = (ks == 0) ? fb[d2] : 0.f;
      for (int ee = e0; ee < e1; ee++) acc = fmaf(fct[ee*DIM + d2], sy[ee], acc);
      sxp[ks][d2] = acc;
    }
    __syncthreads();
    if (tid < DIM)
      out[o + tid] = fmaxf(sxp[0][tid] + sxp[1][tid] + sxp[2][tid], 0.f);
  }
}

extern "C" void kernel_launch(void* const* d_in, const int* in_sizes, int n_in,
                              void* d_out, int out_size, void* d_ws, size_t ws_size,
                              hipStream_t stream) {
  const float* seq     = (const float*)d_in[0];
  const float* mask    = (const float*)d_in[1];
  const float* conv1_w = (const float*)d_in[2];
  const float* conv2_w = (const float*)d_in[3];
  const float* ln_g    = (const float*)d_in[4];
  const float* ln_b    = (const float*)d_in[5];
  const float* c1d_w   = (const float*)d_in[6];
  const float* bn1_g   = (const float*)d_in[7];
  const float* bn1_b   = (const float*)d_in[8];
  const float* c2d_w   = (const float*)d_in[9];
  const float* bn2_g   = (const float*)d_in[10];
  const float* bn2_b   = (const float*)d_in[11];
  const float* wq_w    = (const float*)d_in[12];
  const float* wq_b    = (const float*)d_in[13];
  const float* wk_w    = (const float*)d_in[14];
  const float* wk_b    = (const float*)d_in[15];
  const float* wv_w    = (const float*)d_in[16];
  const float* wv_b    = (const float*)d_in[17];
  const float* wd_w    = (const float*)d_in[18];
  const float* wd_b    = (const float*)d_in[19];
  const float* wl_w    = (const float*)d_in[20];
  const float* wl_b    = (const float*)d_in[21];
  const float* fc_w    = (const float*)d_in[22];
  const float* fc_b    = (const float*)d_in[23];
  float* out = (float*)d_out;

  float* ws = (float*)d_ws;
  float* X    = ws; ws += BB*NP*DIM;
  float* Cc   = ws; ws += BB*DIM*NP;
  float* CcT  = ws; ws += BB*DIM*NP;
  float* CL0  = ws; ws += BB*DIM*NP;
  float* CL1  = ws; ws += BB*DIM*NP;
  float* CL2  = ws; ws += BB*DIM*NP;
  float* CLT0 = ws; ws += BB*DIM*NP;
  float* CLT1 = ws; ws += BB*DIM*NP;
  float* CLT2 = ws; ws += BB*DIM*NP;
  float* Q0   = ws; ws += BB*NP*DIM;
  float* K0   = ws; ws += BB*NP*DIM;
  float* V0   = ws; ws += BB*NP*DIM;
  float* Q1   = ws; ws += BB*NP*DIM;
  float* K1   = ws; ws += BB*NP*DIM;
  float* V1   = ws; ws += BB*NP*DIM;
  float* TG   = ws; ws += (size_t)BB*HH*NN;
  float* GATE = ws; ws += (size_t)BB*HH*NN;
  float* WQT  = ws; ws += (size_t)LL*DIM*DIM;
  float* WKT  = ws; ws += (size_t)LL*DIM*DIM;
  float* WVT  = ws; ws += (size_t)LL*DIM*DIM;
  float* WLT  = ws; ws += (size_t)LL*DIM*DIM;
  float* FCT  = ws; ws += (size_t)DIM*DIM;
  float* STATALL = ws; ws += 3*2*C2;
  __bf16* RAW = (__bf16*)ws; ws += (size_t)BB*C2*NN/2;
  __bf16* INB = (__bf16*)ws; ws += (size_t)BB*16*PR*PC*2*16/4;
  __bf16* WTB = (__bf16*)ws; ws += (size_t)LL*C2*C2*9/2;

  k_wtrans<<<dim3(16, 13), 256, 0, stream>>>(wq_w, wk_w, wv_w, wl_w, fc_w,
                                             WQT, WKT, WVT, WLT, FCT);
  k_wprep<<<LL*C2, 256, 0, stream>>>(c2d_w, WTB);
  k_conv_init<<<dim3(NP, BB), DIM, 0, stream>>>(seq, conv1_w, conv2_w, X, Cc, CcT);
  k_conv1d_bn_relu<<<DIM, 768, 0, stream>>>(Cc,  c1d_w + 0*(size_t)DIM*DIM*3, bn1_g + 0*DIM, bn1_b + 0*DIM, CL0, CLT0);
  k_conv1d_bn_relu<<<DIM, 768, 0, stream>>>(CL0, c1d_w + 1*(size_t)DIM*DIM*3, bn1_g + 1*DIM, bn1_b + 1*DIM, CL1, CLT1);
  k_conv1d_bn_relu<<<DIM, 768, 0, stream>>>(CL1, c1d_w + 2*(size_t)DIM*DIM*3, bn1_g + 2*DIM, bn1_b + 2*DIM, CL2, CLT2);
  k_make_convin<<<(BB*16*PR*PC*2)/256, 256, 0, stream>>>(CcT, CLT0, INB, STATALL);
  k_lnqkv<<<dim3(NP, BB), 384, 0, stream>>>(X, CLT0, ln_g, ln_b,
                                            WQT, wq_b, WKT, wk_b, WVT, wv_b, Q0, K0, V0);

  // ---- layer 0 ----
  k_conv2d_mfma<<<dim3(3, 24, 16), 256, 0, stream>>>(INB, WTB + 0*(size_t)16*9*2*256*8, RAW, STATALL + 0*2*C2);
  k_bn2_norm_gate<1><<<dim3(NP, BB), 768, 0, stream>>>(RAW, STATALL + 0*2*C2, bn2_g + 0*C2, bn2_b + 0*C2,
                                                       wd_w + 0*(size_t)HH*C2, CLT1, INB, TG);
  k_gate<<<dim3(36, 16), 256, 0, stream>>>(TG, wd_b + 0*HH, GATE);
  k_attnx<0><<<dim3(NP, BB), 384, 0, stream>>>(Q0, K0, V0, GATE, mask, X,
                                               WLT + 0*(size_t)DIM*DIM, wl_b + 0*DIM,
                                               CLT1, ln_g + 1*DIM, ln_b + 1*DIM,
                                               WQT + 1*(size_t)DIM*DIM, wq_b + 1*DIM,
                                               WKT + 1*(size_t)DIM*DIM, wk_b + 1*DIM,
                                               WVT + 1*(size_t)DIM*DIM, wv_b + 1*DIM,
                                               Q1, K1, V1, nullptr, nullptr, nullptr);
  // ---- layer 1 ----
  k_conv2d_mfma<<<dim3(3, 24, 16), 256, 0, stream>>>(INB, WTB + 1*(size_t)16*9*2*256*8, RAW, STATALL + 1*2*C2);
  k_bn2_norm_gate<1><<<dim3(NP, BB), 768, 0, stream>>>(RAW, STATALL + 1*2*C2, bn2_g + 1*C2, bn2_b + 1*C2,
                                                       wd_w + 1*(size_t)HH*C2, CLT2, INB, TG);
  k_gate<<<dim3(36, 16), 256, 0, stream>>>(TG, wd_b + 1*HH, GATE);
  k_attnx<0><<<dim3(NP, BB), 384, 0, stream>>>(Q1, K1, V1, GATE, mask, X,
                                               WLT + 1*(size_t)DIM*DIM, wl_b + 1*DIM,
                                               CLT2, ln_g + 2*DIM, ln_b + 2*DIM,
                                               WQT + 2*(size_t)DIM*DIM, wq_b + 2*DIM,
                                               WKT + 2*(size_t)DIM*DIM, wk_b + 2*DIM,
                                               WVT + 2*(size_t)DIM*DIM, wv_b + 2*DIM,
                                               Q0, K0, V0, nullptr, nullptr, nullptr);
  // ---- layer 2 ----
  k_conv2d_mfma<<<dim3(3, 24, 16), 256, 0, stream>>>(INB, WTB + 2*(size_t)16*9*2*256*8, RAW, STATALL + 2*2*C2);
  k_bn2_norm_gate<0><<<dim3(NP, BB), 768, 0, stream>>>(RAW, STATALL + 2*2*C2, bn2_g + 2*C2, bn2_b + 2*C2,
                                                       wd_w + 2*(size_t)HH*C2, nullptr, nullptr, TG);
  k_gate<<<dim3(36, 16), 256, 0, stream>>>(TG, wd_b + 2*HH, GATE);
  k_attnx<1><<<dim3(NP, BB), 384, 0, stream>>>(Q0, K0, V0, GATE, mask, X,
                                               WLT + 2*(size_t)DIM*DIM, wl_b + 2*DIM,
                                               nullptr, nullptr, nullptr,
                                               nullptr, nullptr, nullptr, nullptr, nullptr, nullptr,
                                               nullptr, nullptr, nullptr,
                                               FCT, fc_b, out);
}